// Round 6
// baseline (582.010 us; speedup 1.0000x reference)
//
#include <hip/hip_runtime.h>
#include <stdint.h>

#define NDIM 1152
#define NEXP 4
#define NHID 768
#define NHEAD 8
#define HDIM 144
#define NB 2
#define NS 1024
#define NSC 128
#define NTOK 2048
#define NCAP 256

typedef _Float16 f16;
typedef _Float16 f16x4 __attribute__((ext_vector_type(4)));
typedef _Float16 f16x8 __attribute__((ext_vector_type(8)));
typedef float f32x4 __attribute__((ext_vector_type(4)));

#define MFMA16(a, b, c) __builtin_amdgcn_mfma_f32_16x16x32_f16(a, b, c, 0, 0, 0)

#define WSZ ((size_t)NEXP * NHID * NDIM)  // elems per weight tensor (3,538,944)
#define WCH ((size_t)(WSZ / 8))           // 8-elem chunks per tensor (442,368)

// ---------------- Threefry2x32 (exact JAX replication) ----------------
__device__ inline uint2 tfry(uint32_t k0, uint32_t k1, uint32_t x0, uint32_t x1) {
  uint32_t k2 = k0 ^ k1 ^ 0x1BD11BDAu;
#define RND(r) { x0 += x1; x1 = (x1 << r) | (x1 >> (32 - r)); x1 ^= x0; }
  x0 += k0; x1 += k1;
  RND(13) RND(15) RND(26) RND(6)
  x0 += k1; x1 += k2 + 1u;
  RND(17) RND(29) RND(16) RND(24)
  x0 += k2; x1 += k0 + 2u;
  RND(13) RND(15) RND(26) RND(6)
  x0 += k0; x1 += k1 + 3u;
  RND(17) RND(29) RND(16) RND(24)
  x0 += k1; x1 += k2 + 4u;
  RND(13) RND(15) RND(26) RND(6)
  x0 += k2; x1 += k0 + 5u;
#undef RND
  return make_uint2(x0, x1);
}

__device__ inline float b2g(uint32_t bits) {
  uint32_t fb = (bits >> 9) | 0x3f800000u;
  float f = __uint_as_float(fb) - 1.0f;
  const float tiny = 1.1754943508222875e-38f;
  float u = f * 1.0f + tiny;
  u = fmaxf(tiny, u);
  return -logf(-logf(u));
}

// ---------------- prep: keys, gumbels, time-logits ----------------
__global__ void k_prep(const float* __restrict__ timep, const float* __restrict__ hlw,
                       const float* __restrict__ hlb,
                       float* __restrict__ g1, float* __restrict__ g2, float* __restrict__ g3,
                       float* __restrict__ tl) {
  int t = threadIdx.x;  // 256
  uint2 k1 = tfry(0u, 42u, 0u, 0u);
  uint2 k2 = tfry(0u, 42u, 0u, 1u);
  uint2 k3 = tfry(0u, 42u, 0u, 2u);
  for (int p = t; p < 4096; p += 256) {
    uint2 o = tfry(k1.x, k1.y, 0u, (uint32_t)p);
    g1[p] = b2g(o.x ^ o.y);
  }
  for (int p = t; p < 8192; p += 256) {
    uint2 o2 = tfry(k2.x, k2.y, 0u, (uint32_t)p);
    g2[p] = b2g(o2.x ^ o2.y);
    uint2 o3 = tfry(k3.x, k3.y, 0u, (uint32_t)p);
    g3[p] = b2g(o3.x ^ o3.y);
  }
  int wv = t >> 6, lane = t & 63;
  {
    int b = wv >> 1, j = wv & 1;
    float s = 0.f;
    for (int k = lane; k < NDIM; k += 64) s += timep[b * NDIM + k] * hlw[j * NDIM + k];
    for (int m = 32; m; m >>= 1) s += __shfl_xor(s, m);
    if (lane == 0) tl[b * 2 + j] = s + hlb[j];
  }
}

// ---------------- fused gate weights: W'[e,k] = sum_d gw[e,d]*ow[d,k]; b' = gw·ob + gb -
__global__ void k_fuse_gate(const float* __restrict__ ow, const float* __restrict__ ob,
                            const float* __restrict__ gw, const float* __restrict__ gb,
                            float* __restrict__ wp, float* __restrict__ bp) {
  int t = threadIdx.x;
  if (blockIdx.x == 5) {
    int wv = t >> 6, lane = t & 63;  // wv = e
    float s = 0.f;
    for (int d = lane; d < NDIM; d += 64) s += ob[d] * gw[wv * NDIM + d];
    for (int m = 32; m; m >>= 1) s += __shfl_xor(s, m);
    if (lane == 0) bp[wv] = s + gb[wv];
    return;
  }
  __shared__ float gws[4 * NDIM];
  for (int i = t; i < 4 * NDIM; i += 256) gws[i] = gw[i];
  __syncthreads();
  int k = blockIdx.x * 256 + t;
  if (k >= NDIM) return;
  float a0 = 0.f, a1 = 0.f, a2 = 0.f, a3 = 0.f;
#pragma unroll 4
  for (int d = 0; d < NDIM; ++d) {
    float o = ow[(size_t)d * NDIM + k];
    a0 += gws[d] * o;
    a1 += gws[NDIM + d] * o;
    a2 += gws[2 * NDIM + d] * o;
    a3 += gws[3 * NDIM + d] * o;
  }
  wp[k] = a0; wp[NDIM + k] = a1; wp[2 * NDIM + k] = a2; wp[3 * NDIM + k] = a3;
}

// ---------------- generic 4-logit head: out[n,e] = in[n,:]·w[e,:] + b[e] ----------------
__global__ void k_ac_logits(const float* __restrict__ ac, const float* __restrict__ agw,
                            const float* __restrict__ agb, float* __restrict__ al) {
  int wv = threadIdx.x >> 6, lane = threadIdx.x & 63;
  int n = blockIdx.x * 4 + wv;
  float s[NEXP] = {0.f, 0.f, 0.f, 0.f};
  for (int d = lane; d < NDIM; d += 64) {
    float a = ac[(size_t)n * NDIM + d];
#pragma unroll
    for (int e = 0; e < NEXP; ++e) s[e] += a * agw[e * NDIM + d];
  }
#pragma unroll
  for (int e = 0; e < NEXP; ++e)
    for (int m = 32; m; m >>= 1) s[e] += __shfl_xor(s[e], m);
  if (lane == 0) {
#pragma unroll
    for (int e = 0; e < NEXP; ++e) al[n * NEXP + e] = s[e] + agb[e];
  }
}

// ---------------- cap logits from split-f16 o: cl[n,e] = o[n,:]·W'[e,:] + b'[e] -------
__global__ void k_o_logits(const f16* __restrict__ ohi, const f16* __restrict__ olo,
                           const float* __restrict__ wp, const float* __restrict__ bp,
                           float* __restrict__ cl) {
  int wv = threadIdx.x >> 6, lane = threadIdx.x & 63;
  int n = blockIdx.x * 4 + wv;
  float s[NEXP] = {0.f, 0.f, 0.f, 0.f};
  for (int d = lane; d < NDIM; d += 64) {
    size_t gi = (size_t)n * NDIM + d;
    float a = (float)ohi[gi] + (float)olo[gi] * (1.f / 2048.f);
#pragma unroll
    for (int e = 0; e < NEXP; ++e) s[e] += a * wp[e * NDIM + d];
  }
#pragma unroll
  for (int e = 0; e < NEXP; ++e)
    for (int m = 32; m; m >>= 1) s[e] += __shfl_xor(s[e], m);
  if (lane == 0) {
#pragma unroll
    for (int e = 0; e < NEXP; ++e) cl[n * NEXP + e] = s[e] + bp[e];
  }
}

// ---------------- fp32 + fp32 -> fp16 convert (fused add) ----------------
__global__ void k_cvt_add(const float* __restrict__ srca, const float* __restrict__ srcb,
                          f16* __restrict__ dst, int n) {
  int i = (blockIdx.x * 256 + threadIdx.x) * 4;
  if (i + 3 < n) {
    float4 va = *(const float4*)(srca + i);
    float4 vb = *(const float4*)(srcb + i);
    f16x4 h;
    h[0] = (f16)(va.x + vb.x); h[1] = (f16)(va.y + vb.y);
    h[2] = (f16)(va.z + vb.z); h[3] = (f16)(va.w + vb.w);
    *(f16x4*)(dst + i) = h;
  }
}

// ---------------- fp32 -> fp16 hi/lo split convert (lo pre-scaled by 2048) ----------------
__global__ void k_cvt_split(const float* __restrict__ src, f16* __restrict__ hi,
                            f16* __restrict__ lo, int n) {
  int i = (blockIdx.x * 256 + threadIdx.x) * 4;
  if (i + 3 < n) {
    float4 v = *(const float4*)(src + i);
    f16x4 h, l;
    h[0] = (f16)v.x; l[0] = (f16)((v.x - (float)h[0]) * 2048.f);
    h[1] = (f16)v.y; l[1] = (f16)((v.y - (float)h[1]) * 2048.f);
    h[2] = (f16)v.z; l[2] = (f16)((v.z - (float)h[2]) * 2048.f);
    h[3] = (f16)v.w; l[3] = (f16)((v.w - (float)h[3]) * 2048.f);
    *(f16x4*)(hi + i) = h;
    *(f16x4*)(lo + i) = l;
  }
}

// ---------------- QKV projection + fused weight cvt (slots 0-3) ----------------
// z<3: split-fp16 QKV GEMM (2-phase prefetch). z==2 (V) emits transposed split-fp16.
// z in {3,4}: grid-stride f32->f16 conversion of cap_w1/cap_w3/ac_w1/ac_w3.
__global__ __launch_bounds__(256) void k_gemm_qkv(
    const f16* __restrict__ xhi, const f16* __restrict__ xlo,
    const f16* __restrict__ caphi, const f16* __restrict__ caplo,
    const float* __restrict__ inw, const float* __restrict__ inb,
    f16* __restrict__ qhi, f16* __restrict__ qlo,
    f16* __restrict__ khi, f16* __restrict__ klo,
    f16* __restrict__ vthi, f16* __restrict__ vtlo,
    const float* __restrict__ w0, const float* __restrict__ w1,
    const float* __restrict__ w2, const float* __restrict__ w3,
    f16* __restrict__ wf16) {
  int z = blockIdx.z;
  if (z >= 3) {
    // 4*WCH = 1,769,472 chunks over 1152 blocks -> 1536 chunks/block (1536 | WCH)
    int cvtid = (z - 3) * 576 + blockIdx.y * 18 + blockIdx.x;
    size_t c0 = (size_t)cvtid * 1536;
    int slot = (int)(c0 / WCH);               // block-uniform
    size_t base = (c0 % WCH) * 8;
    const float* s = ((slot == 0) ? w0 : (slot == 1) ? w1 : (slot == 2) ? w2 : w3) + base;
    f16* dst = wf16 + (size_t)slot * WSZ + base;
#pragma unroll
    for (int i = 0; i < 6; ++i) {
      size_t off = (size_t)(threadIdx.x + i * 256) * 8;
      float4 v0 = *(const float4*)(s + off);
      float4 v1 = *(const float4*)(s + off + 4);
      f16x8 h;
      h[0] = (f16)v0.x; h[1] = (f16)v0.y; h[2] = (f16)v0.z; h[3] = (f16)v0.w;
      h[4] = (f16)v1.x; h[5] = (f16)v1.y; h[6] = (f16)v1.z; h[7] = (f16)v1.w;
      *(f16x8*)(dst + off) = h;
    }
    return;
  }
  int M = (z == 0) ? NTOK : NCAP;
  int mt = blockIdx.y, nt = blockIdx.x;
  if (mt * 64 >= M) return;
  const f16* Ah_g = (z == 0) ? xhi : caphi;
  const f16* Al_g = (z == 0) ? xlo : caplo;
  __shared__ f16 Ash[64 * 72];
  __shared__ f16 Asl[64 * 72];
  __shared__ f16 Bsh[64 * 72];
  __shared__ f16 Bsl[64 * 72];
  int t = threadIdx.x;
  int wv = t >> 6, lane = t & 63, m16 = lane & 15, quad = lane >> 4;
  int r0 = t >> 3, ak = (t & 7) * 8;
  size_t a0o = (size_t)(mt * 64 + r0) * NDIM;
  size_t a1o = (size_t)(mt * 64 + r0 + 32) * NDIM;
  f32x4 zf = {0.f, 0.f, 0.f, 0.f};
  f32x4 ah[2][2] = {{zf, zf}, {zf, zf}};
  f32x4 am[2][2] = {{zf, zf}, {zf, zf}};
  uint4 rah0, rah1, ral0, ral1;
  float4 rbw[4];
  rah0 = *(const uint4*)(Ah_g + a0o + ak);
  rah1 = *(const uint4*)(Ah_g + a1o + ak);
  ral0 = *(const uint4*)(Al_g + a0o + ak);
  ral1 = *(const uint4*)(Al_g + a1o + ak);
#pragma unroll
  for (int uu = 0; uu < 4; ++uu) {
    int u = t + uu * 256;
    int rr = u >> 4, kp = (u & 15) * 4;
    rbw[uu] = *(const float4*)(inw + (size_t)(z * NDIM + nt * 64 + rr) * NDIM + kp);
  }
  for (int kc = 0; kc < NDIM; kc += 64) {
    __syncthreads();
    *(uint4*)&Ash[r0 * 72 + ak] = rah0;
    *(uint4*)&Ash[(r0 + 32) * 72 + ak] = rah1;
    *(uint4*)&Asl[r0 * 72 + ak] = ral0;
    *(uint4*)&Asl[(r0 + 32) * 72 + ak] = ral1;
#pragma unroll
    for (int uu = 0; uu < 4; ++uu) {
      int u = t + uu * 256;
      int rr = u >> 4, kp = (u & 15) * 4;
      f16x4 hb, lb;
      hb[0] = (f16)rbw[uu].x; lb[0] = (f16)((rbw[uu].x - (float)hb[0]) * 2048.f);
      hb[1] = (f16)rbw[uu].y; lb[1] = (f16)((rbw[uu].y - (float)hb[1]) * 2048.f);
      hb[2] = (f16)rbw[uu].z; lb[2] = (f16)((rbw[uu].z - (float)hb[2]) * 2048.f);
      hb[3] = (f16)rbw[uu].w; lb[3] = (f16)((rbw[uu].w - (float)hb[3]) * 2048.f);
      *(f16x4*)&Bsh[rr * 72 + kp] = hb;
      *(f16x4*)&Bsl[rr * 72 + kp] = lb;
    }
    __syncthreads();
    int kn = kc + 64;
    if (kn < NDIM) {
      rah0 = *(const uint4*)(Ah_g + a0o + kn + ak);
      rah1 = *(const uint4*)(Ah_g + a1o + kn + ak);
      ral0 = *(const uint4*)(Al_g + a0o + kn + ak);
      ral1 = *(const uint4*)(Al_g + a1o + kn + ak);
#pragma unroll
      for (int uu = 0; uu < 4; ++uu) {
        int u = t + uu * 256;
        int rr = u >> 4, kp = (u & 15) * 4;
        rbw[uu] = *(const float4*)(inw + (size_t)(z * NDIM + nt * 64 + rr) * NDIM + kn + kp);
      }
    }
#pragma unroll
    for (int ks = 0; ks < 2; ++ks) {
      int aoff = ((wv & 1) * 32 + m16) * 72 + ks * 32 + quad * 8;
      int boff = ((wv >> 1) * 32 + m16) * 72 + ks * 32 + quad * 8;
      f16x8 a0h = *(const f16x8*)&Ash[aoff];
      f16x8 a1h = *(const f16x8*)&Ash[aoff + 16 * 72];
      f16x8 a0l = *(const f16x8*)&Asl[aoff];
      f16x8 a1l = *(const f16x8*)&Asl[aoff + 16 * 72];
      f16x8 b0h = *(const f16x8*)&Bsh[boff];
      f16x8 b1h = *(const f16x8*)&Bsh[boff + 16 * 72];
      f16x8 b0l = *(const f16x8*)&Bsl[boff];
      f16x8 b1l = *(const f16x8*)&Bsl[boff + 16 * 72];
      ah[0][0] = MFMA16(a0h, b0h, ah[0][0]);
      ah[0][1] = MFMA16(a0h, b1h, ah[0][1]);
      ah[1][0] = MFMA16(a1h, b0h, ah[1][0]);
      ah[1][1] = MFMA16(a1h, b1h, ah[1][1]);
      am[0][0] = MFMA16(a0h, b0l, am[0][0]);
      am[0][1] = MFMA16(a0h, b1l, am[0][1]);
      am[1][0] = MFMA16(a1h, b0l, am[1][0]);
      am[1][1] = MFMA16(a1h, b1l, am[1][1]);
      am[0][0] = MFMA16(a0l, b0h, am[0][0]);
      am[0][1] = MFMA16(a0l, b1h, am[0][1]);
      am[1][0] = MFMA16(a1l, b0h, am[1][0]);
      am[1][1] = MFMA16(a1l, b1h, am[1][1]);
    }
  }
#pragma unroll
  for (int mi = 0; mi < 2; ++mi)
#pragma unroll
    for (int ni = 0; ni < 2; ++ni)
#pragma unroll
      for (int r = 0; r < 4; ++r) {
        int row = mt * 64 + (wv & 1) * 32 + mi * 16 + quad * 4 + r;
        int col = nt * 64 + (wv >> 1) * 32 + ni * 16 + m16;
        float v = ah[mi][ni][r] + am[mi][ni][r] * (1.f / 2048.f) + inb[z * NDIM + col];
        size_t idx = (size_t)row * NDIM + col;
        if (z == 0) {
          f16 hq = (f16)v;
          qhi[idx] = hq;
          qlo[idx] = (f16)((v - (float)hq) * 2048.f);
        } else if (z == 1) {
          f16 hk = (f16)v;
          khi[idx] = hk;
          klo[idx] = (f16)((v - (float)hk) * 2048.f);
        } else {
          f16 hv = (f16)v;
          int bb = row >> 7, kv = row & 127;
          size_t ti = (size_t)(bb * NDIM + col) * NSC + kv;
          vthi[ti] = hv;
          vtlo[ti] = (f16)((v - (float)hv) * 2048.f);
        }
      }
}

// ---------------- fused attention: QK^T + softmax + PV, split-fp16, writes o hi/lo ----
__global__ __launch_bounds__(256) void k_attn(
    const f16* __restrict__ qhi, const f16* __restrict__ qlo,
    const f16* __restrict__ khi, const f16* __restrict__ klo,
    const f16* __restrict__ vthi, const f16* __restrict__ vtlo,
    f16* __restrict__ ohi, f16* __restrict__ olo) {
  int mt = blockIdx.x, bh = blockIdx.y;
  int b = bh >> 3, h = bh & 7;
  __shared__ f16 Ah[64 * 160];
  __shared__ f16 Al[64 * 160];
  __shared__ f16 Bh[32 * 160];
  __shared__ f16 Bl[32 * 160];
  __shared__ f16 Ph[64 * 136];
  __shared__ f16 Pl[64 * 136];
  int t = threadIdx.x;
  int wv = t >> 6, lane = t & 63, m16 = lane & 15, quad = lane >> 4;
  for (int u = t; u < 64 * 20; u += 256) {
    int r = u / 20, kp = (u % 20) * 8;
    uint4 vh = make_uint4(0u, 0u, 0u, 0u), vl = vh;
    if (kp < HDIM) {
      size_t gi = (size_t)(b * NS + mt * 64 + r) * NDIM + h * HDIM + kp;
      vh = *(const uint4*)&qhi[gi];
      vl = *(const uint4*)&qlo[gi];
    }
    *(uint4*)&Ah[r * 160 + kp] = vh;
    *(uint4*)&Al[r * 160 + kp] = vl;
  }
  __syncthreads();
  f16x8 ahf[5], alf[5];
#pragma unroll
  for (int ks = 0; ks < 5; ++ks) {
    int ao = (wv * 16 + m16) * 160 + ks * 32 + quad * 8;
    ahf[ks] = *(const f16x8*)&Ah[ao];
    alf[ks] = *(const f16x8*)&Al[ao];
  }
  f32x4 zf = {0.f, 0.f, 0.f, 0.f};
  f32x4 sh_[4][2], sm_[4][2];
#pragma unroll
  for (int kt = 0; kt < 4; ++kt)
#pragma unroll
    for (int ni = 0; ni < 2; ++ni) { sh_[kt][ni] = zf; sm_[kt][ni] = zf; }
  for (int kt = 0; kt < 4; ++kt) {
    if (kt) __syncthreads();
    for (int u = t; u < 32 * 20; u += 256) {
      int r = u / 20, kp = (u % 20) * 8;
      uint4 vh = make_uint4(0u, 0u, 0u, 0u), vl = vh;
      if (kp < HDIM) {
        size_t gi = (size_t)(b * NSC + kt * 32 + r) * NDIM + h * HDIM + kp;
        vh = *(const uint4*)&khi[gi];
        vl = *(const uint4*)&klo[gi];
      }
      *(uint4*)&Bh[r * 160 + kp] = vh;
      *(uint4*)&Bl[r * 160 + kp] = vl;
    }
    __syncthreads();
#pragma unroll
    for (int ks = 0; ks < 5; ++ks) {
#pragma unroll
      for (int ni = 0; ni < 2; ++ni) {
        int bo = (ni * 16 + m16) * 160 + ks * 32 + quad * 8;
        f16x8 bhf = *(const f16x8*)&Bh[bo];
        f16x8 blf = *(const f16x8*)&Bl[bo];
        sh_[kt][ni] = MFMA16(ahf[ks], bhf, sh_[kt][ni]);
        sm_[kt][ni] = MFMA16(ahf[ks], blf, sm_[kt][ni]);
        sm_[kt][ni] = MFMA16(alf[ks], bhf, sm_[kt][ni]);
      }
    }
  }
  float sv[4][2][4];
  float mx[4] = {-1e30f, -1e30f, -1e30f, -1e30f};
#pragma unroll
  for (int kt = 0; kt < 4; ++kt)
#pragma unroll
    for (int ni = 0; ni < 2; ++ni)
#pragma unroll
      for (int r = 0; r < 4; ++r) {
        float s = (sh_[kt][ni][r] + sm_[kt][ni][r] * (1.f / 2048.f)) * (1.f / 12.f);
        sv[kt][ni][r] = s;
        mx[r] = fmaxf(mx[r], s);
      }
#pragma unroll
  for (int r = 0; r < 4; ++r) {
    mx[r] = fmaxf(mx[r], __shfl_xor(mx[r], 1));
    mx[r] = fmaxf(mx[r], __shfl_xor(mx[r], 2));
    mx[r] = fmaxf(mx[r], __shfl_xor(mx[r], 4));
    mx[r] = fmaxf(mx[r], __shfl_xor(mx[r], 8));
  }
  float sum[4] = {0.f, 0.f, 0.f, 0.f};
#pragma unroll
  for (int kt = 0; kt < 4; ++kt)
#pragma unroll
    for (int ni = 0; ni < 2; ++ni)
#pragma unroll
      for (int r = 0; r < 4; ++r) {
        float e = expf(sv[kt][ni][r] - mx[r]);
        sv[kt][ni][r] = e;
        sum[r] += e;
      }
  float inv[4];
#pragma unroll
  for (int r = 0; r < 4; ++r) {
    sum[r] += __shfl_xor(sum[r], 1);
    sum[r] += __shfl_xor(sum[r], 2);
    sum[r] += __shfl_xor(sum[r], 4);
    sum[r] += __shfl_xor(sum[r], 8);
    inv[r] = 1.0f / sum[r];
  }
#pragma unroll
  for (int kt = 0; kt < 4; ++kt)
#pragma unroll
    for (int ni = 0; ni < 2; ++ni)
#pragma unroll
      for (int r = 0; r < 4; ++r) {
        float p = sv[kt][ni][r] * inv[r];
        int row = wv * 16 + quad * 4 + r;
        int col = kt * 32 + ni * 16 + m16;
        f16 ph = (f16)p;
        Ph[row * 136 + col] = ph;
        Pl[row * 136 + col] = (f16)((p - (float)ph) * 2048.f);
      }
  const f16* vbh = vthi + (size_t)(b * NDIM + h * HDIM) * NSC;
  const f16* vbl = vtlo + (size_t)(b * NDIM + h * HDIM) * NSC;
  f32x4 oh_[9], om_[9];
#pragma unroll
  for (int nb = 0; nb < 9; ++nb) { oh_[nb] = zf; om_[nb] = zf; }
#pragma unroll
  for (int ks = 0; ks < 4; ++ks) {
    int po = (wv * 16 + m16) * 136 + ks * 32 + quad * 8;
    f16x8 pah = *(const f16x8*)&Ph[po];
    f16x8 pal = *(const f16x8*)&Pl[po];
#pragma unroll
    for (int nb = 0; nb < 9; ++nb) {
      size_t vo = (size_t)(nb * 16 + m16) * NSC + ks * 32 + quad * 8;
      f16x8 bvh = *(const f16x8*)&vbh[vo];
      f16x8 bvl = *(const f16x8*)&vbl[vo];
      oh_[nb] = MFMA16(pah, bvh, oh_[nb]);
      om_[nb] = MFMA16(pah, bvl, om_[nb]);
      om_[nb] = MFMA16(pal, bvh, om_[nb]);
    }
  }
#pragma unroll
  for (int nb = 0; nb < 9; ++nb)
#pragma unroll
    for (int r = 0; r < 4; ++r) {
      int row = mt * 64 + wv * 16 + quad * 4 + r;
      int col = h * HDIM + nb * 16 + m16;
      float v = oh_[nb][r] + om_[nb][r] * (1.f / 2048.f);
      size_t idx = (size_t)(b * NS + row) * NDIM + col;
      f16 hv = (f16)v;
      ohi[idx] = hv;
      olo[idx] = (f16)((v - (float)hv) * 2048.f);
    }
}

// ---------------- routing: argmax gates, cm/am, lists, loss ----------------
__global__ __launch_bounds__(1024) void k_route(
    const float* __restrict__ cl, const float* __restrict__ al,
    const float* __restrict__ g1, const float* __restrict__ g2,
    const float* __restrict__ g3, const float* __restrict__ tl,
    float* __restrict__ cmv, float* __restrict__ amv,
    int* __restrict__ lists, int* __restrict__ counts, float* __restrict__ out_loss) {
  __shared__ int lcnt[8];
  __shared__ float bins[8];
  __shared__ float ssum[2];
  int t = threadIdx.x;
  if (t < 8) { lcnt[t] = 0; bins[t] = 0.f; }
  if (t < 2) ssum[t] = 0.f;
  __syncthreads();
  for (int n = t; n < NTOK; n += 1024) {
    float lc[NEXP];
#pragma unroll
    for (int e = 0; e < NEXP; ++e) lc[e] = cl[n * NEXP + e] + g2[n * 4 + e];
    int ec = 0; float bv = lc[0];
#pragma unroll
    for (int e = 1; e < NEXP; ++e) if (lc[e] > bv) { bv = lc[e]; ec = e; }
    float la[NEXP];
#pragma unroll
    for (int e = 0; e < NEXP; ++e) la[e] = al[n * NEXP + e] + g3[n * 4 + e];
    int ea = 0; float bva = la[0];
#pragma unroll
    for (int e = 1; e < NEXP; ++e) if (la[e] > bva) { bva = la[e]; ea = e; }
    int b = n >> 10;
    float a0 = tl[b * 2 + 0] + g1[n * 2 + 0];
    float a1 = tl[b * 2 + 1] + g1[n * 2 + 1];
    float mx = fmaxf(a0, a1);
    float e0 = expf(a0 - mx), e1 = expf(a1 - mx);
    float cm = e0 / (e0 + e1), am = e1 / (e0 + e1);
    cmv[n] = cm; amv[n] = am;
    int p0 = atomicAdd(&lcnt[ec], 1);
    lists[ec * NTOK + p0] = n;
    int p1 = atomicAdd(&lcnt[4 + ea], 1);
    lists[(4 + ea) * NTOK + p1] = n;
    atomicAdd(&bins[ec], cm);
    atomicAdd(&bins[4 + ea], am);
    atomicAdd(&ssum[0], cm);
    atomicAdd(&ssum[1], am);
  }
  __syncthreads();
  if (t < 8) counts[t] = lcnt[t];
  if (t == 0) {
    float denom = 4.f * (ssum[0] + ssum[1]) + 1e-10f;
    float acc = 0.f;
    for (int j = 0; j < 8; ++j) {
      float u = bins[j] / denom;
      acc += u * logf(u + 1e-10f);
    }
    out_loss[0] = acc / 8.f;
  }
}

// ---------------- GEMM1: M64, f16 weights, XCD-grouped remap, 2-phase prefetch --------
// For gbase==0 launch, blocks beyond G*384 convert weight slots 4-8 (grid-stride cvt).
__global__ __launch_bounds__(256) void k_gemm1(
    const f16* __restrict__ x16, const f16* __restrict__ y16,
    f16* wf,
    const int* __restrict__ lists, const int* __restrict__ counts,
    f16* __restrict__ tbuf,
    const float* __restrict__ w4, const float* __restrict__ w5,
    const float* __restrict__ w6, const float* __restrict__ w7,
    const float* __restrict__ w8, int gbase, int G) {
  int bid = blockIdx.x;
  int nblk = G * 384;
  if (bid >= nblk) {
    // 5*WCH = 2,211,840 chunks over 1080 blocks -> 2048 chunks/block (2048 | WCH)
    int cvtid = bid - nblk;
    size_t c0 = (size_t)cvtid * 2048;
    int sg = (int)(c0 / WCH);                 // block-uniform
    size_t base = (c0 % WCH) * 8;
    const float* s = ((sg == 0) ? w4 : (sg == 1) ? w5 : (sg == 2) ? w6
                       : (sg == 3) ? w7 : w8) + base;
    f16* dst = wf + (size_t)(4 + sg) * WSZ + base;
#pragma unroll
    for (int i = 0; i < 8; ++i) {
      size_t off = (size_t)(threadIdx.x + i * 256) * 8;
      float4 v0 = *(const float4*)(s + off);
      float4 v1 = *(const float4*)(s + off + 4);
      f16x8 h;
      h[0] = (f16)v0.x; h[1] = (f16)v0.y; h[2] = (f16)v0.z; h[3] = (f16)v0.w;
      h[4] = (f16)v1.x; h[5] = (f16)v1.y; h[6] = (f16)v1.z; h[7] = (f16)v1.w;
      *(f16x8*)(dst + off) = h;
    }
    return;
  }
  int xcd = bid & 7;
  int local = bid >> 3;
  int ppx = (G * 12) >> 3;               // pairs per xcd (8->12, 4->6)
  int pair = xcd * ppx + (local >> 5);   // MT = 32
  int mt = local & 31;
  int g = gbase + pair / 12;
  int nt = pair % 12;
  const f16* A; const f16* B1; const f16* B3; f16* tout;
  const int* list = nullptr;
  int cnt, koff, K;
  if (g < 8) {
    int e = g & 3;
    cnt = counts[g];
    list = lists + g * NTOK;
    A = x16; koff = 0; K = NDIM;
    B1 = wf + (size_t)((g < 4) ? 0 : 2) * WSZ + (size_t)e * NHID * NDIM;
    B3 = wf + (size_t)((g < 4) ? 1 : 3) * WSZ + (size_t)e * NHID * NDIM;
    tout = tbuf + (size_t)g * NTOK * NHID;
  } else {
    int e = g - 8;
    cnt = NTOK;
    A = y16; koff = e * 288; K = 288;
    B1 = wf + (size_t)4 * WSZ + (size_t)e * NHID * NDIM + koff;
    B3 = wf + (size_t)5 * WSZ + (size_t)e * NHID * NDIM + koff;
    tout = tbuf + (size_t)e * NTOK * NHID;
  }
  if (mt * 64 >= cnt) return;
  int t = threadIdx.x;
  int wv = t >> 6, lane = t & 63, m16 = lane & 15, quad = lane >> 4;
  int r0 = t >> 3, ak = (t & 7) * 8;
  int m0 = mt * 64 + r0, m1 = m0 + 32;
  int tok0, tok1;
  if (list) { tok0 = list[min(m0, cnt - 1)]; tok1 = list[min(m1, cnt - 1)]; }
  else { tok0 = m0; tok1 = m1; }
  const f16* ar0 = A + (size_t)tok0 * NDIM + koff;
  const f16* ar1 = A + (size_t)tok1 * NDIM + koff;
  const f16* b1r0 = B1 + (size_t)(nt * 64 + r0) * NDIM;
  const f16* b1r1 = B1 + (size_t)(nt * 64 + r0 + 32) * NDIM;
  const f16* b3r0 = B3 + (size_t)(nt * 64 + r0) * NDIM;
  const f16* b3r1 = B3 + (size_t)(nt * 64 + r0 + 32) * NDIM;
  __shared__ f16 As[64 * 72];
  __shared__ f16 Bs1[64 * 72];
  __shared__ f16 Bs2[64 * 72];
  f32x4 zf = {0.f, 0.f, 0.f, 0.f};
  f32x4 ac1[2][2] = {{zf, zf}, {zf, zf}};
  f32x4 ac2[2][2] = {{zf, zf}, {zf, zf}};
  uint4 z4u = make_uint4(0u, 0u, 0u, 0u);
  uint4 ra0, ra1, rb10, rb11, rb30, rb31;
  {
    bool v = (ak < K);
    ra0  = v ? *(const uint4*)(ar0 + ak) : z4u;
    ra1  = v ? *(const uint4*)(ar1 + ak) : z4u;
    rb10 = v ? *(const uint4*)(b1r0 + ak) : z4u;
    rb11 = v ? *(const uint4*)(b1r1 + ak) : z4u;
    rb30 = v ? *(const uint4*)(b3r0 + ak) : z4u;
    rb31 = v ? *(const uint4*)(b3r1 + ak) : z4u;
  }
  for (int kc = 0; kc < K; kc += 64) {
    __syncthreads();
    *(uint4*)&As[r0 * 72 + ak] = ra0;
    *(uint4*)&As[(r0 + 32) * 72 + ak] = ra1;
    *(uint4*)&Bs1[r0 * 72 + ak] = rb10;
    *(uint4*)&Bs1[(r0 + 32) * 72 + ak] = rb11;
    *(uint4*)&Bs2[r0 * 72 + ak] = rb30;
    *(uint4*)&Bs2[(r0 + 32) * 72 + ak] = rb31;
    __syncthreads();
    int kn = kc + 64;
    if (kn < K) {
      bool v = (kn + ak < K);
      ra0  = v ? *(const uint4*)(ar0 + kn + ak) : z4u;
      ra1  = v ? *(const uint4*)(ar1 + kn + ak) : z4u;
      rb10 = v ? *(const uint4*)(b1r0 + kn + ak) : z4u;
      rb11 = v ? *(const uint4*)(b1r1 + kn + ak) : z4u;
      rb30 = v ? *(const uint4*)(b3r0 + kn + ak) : z4u;
      rb31 = v ? *(const uint4*)(b3r1 + kn + ak) : z4u;
    }
#pragma unroll
    for (int ks = 0; ks < 2; ++ks) {
      int aoff = ((wv & 1) * 32 + m16) * 72 + ks * 32 + quad * 8;
      int boff = ((wv >> 1) * 32 + m16) * 72 + ks * 32 + quad * 8;
      f16x8 a0 = *(const f16x8*)&As[aoff];
      f16x8 a1 = *(const f16x8*)&As[aoff + 16 * 72];
      f16x8 b10 = *(const f16x8*)&Bs1[boff];
      f16x8 b11 = *(const f16x8*)&Bs1[boff + 16 * 72];
      f16x8 b30 = *(const f16x8*)&Bs2[boff];
      f16x8 b31 = *(const f16x8*)&Bs2[boff + 16 * 72];
      ac1[0][0] = MFMA16(a0, b10, ac1[0][0]);
      ac1[0][1] = MFMA16(a0, b11, ac1[0][1]);
      ac1[1][0] = MFMA16(a1, b10, ac1[1][0]);
      ac1[1][1] = MFMA16(a1, b11, ac1[1][1]);
      ac2[0][0] = MFMA16(a0, b30, ac2[0][0]);
      ac2[0][1] = MFMA16(a0, b31, ac2[0][1]);
      ac2[1][0] = MFMA16(a1, b30, ac2[1][0]);
      ac2[1][1] = MFMA16(a1, b31, ac2[1][1]);
    }
  }
#pragma unroll
  for (int mi = 0; mi < 2; ++mi)
#pragma unroll
    for (int ni = 0; ni < 2; ++ni)
#pragma unroll
      for (int r = 0; r < 4; ++r) {
        int row = mt * 64 + (wv & 1) * 32 + mi * 16 + quad * 4 + r;
        int col = nt * 64 + (wv >> 1) * 32 + ni * 16 + m16;
        float h1 = ac1[mi][ni][r];
        float h3 = ac2[mi][ni][r];
        float sl = h1 / (1.0f + expf(-h1));
        tout[(size_t)row * NHID + col] = (f16)(sl * h3);
      }
}

// ---------------- GEMM2 (MoE): f16 weights, XCD-grouped remap, 2-phase ----------------
__global__ __launch_bounds__(256) void k_gemm2(
    const f16* __restrict__ tbuf, const f16* __restrict__ wf,
    const int* __restrict__ lists, const int* __restrict__ counts,
    const float* __restrict__ cmv, const float* __restrict__ amv,
    float* __restrict__ yc, float* __restrict__ ya) {
  int bid = blockIdx.x;
  int xcd = bid & 7;
  int local = bid >> 3;
  int pair = xcd * 18 + (local >> 5);
  int mt = local & 31;
  int g = pair / 18;
  int nt = pair % 18;
  int e = g & 3;
  int cnt = counts[g];
  if (mt * 64 >= cnt) return;
  const int* list = lists + g * NTOK;
  const f16* A = tbuf + (size_t)g * NTOK * NHID;
  const f16* Bw = wf + (size_t)((g < 4) ? 6 : 7) * WSZ + (size_t)e * NDIM * NHID;
  const float* sc = (g < 4) ? cmv : amv;
  float* y = (g < 4) ? yc : ya;
  int t = threadIdx.x;
  int wv = t >> 6, lane = t & 63, m16 = lane & 15, quad = lane >> 4;
  int r0 = t >> 3, ak = (t & 7) * 8;
  const f16* ar0 = A + (size_t)(mt * 64 + r0) * NHID;
  const f16* ar1 = A + (size_t)(mt * 64 + r0 + 32) * NHID;
  const f16* br0 = Bw + (size_t)(nt * 64 + r0) * NHID;
  const f16* br1 = Bw + (size_t)(nt * 64 + r0 + 32) * NHID;
  __shared__ f16 As[64 * 72];
  __shared__ f16 Bs[64 * 72];
  f32x4 zf = {0.f, 0.f, 0.f, 0.f};
  f32x4 acc[2][2] = {{zf, zf}, {zf, zf}};
  uint4 ra0, ra1, rb0, rb1;
  ra0 = *(const uint4*)(ar0 + ak);
  ra1 = *(const uint4*)(ar1 + ak);
  rb0 = *(const uint4*)(br0 + ak);
  rb1 = *(const uint4*)(br1 + ak);
  for (int kc = 0; kc < NHID; kc += 64) {
    __syncthreads();
    *(uint4*)&As[r0 * 72 + ak] = ra0;
    *(uint4*)&As[(r0 + 32) * 72 + ak] = ra1;
    *(uint4*)&Bs[r0 * 72 + ak] = rb0;
    *(uint4*)&Bs[(r0 + 32) * 72 + ak] = rb1;
    __syncthreads();
    int kn = kc + 64;
    if (kn < NHID) {
      ra0 = *(const uint4*)(ar0 + kn + ak);
      ra1 = *(const uint4*)(ar1 + kn + ak);
      rb0 = *(const uint4*)(br0 + kn + ak);
      rb1 = *(const uint4*)(br1 + kn + ak);
    }
#pragma unroll
    for (int ks = 0; ks < 2; ++ks) {
      int aoff = ((wv & 1) * 32 + m16) * 72 + ks * 32 + quad * 8;
      int boff = ((wv >> 1) * 32 + m16) * 72 + ks * 32 + quad * 8;
      f16x8 a0 = *(const f16x8*)&As[aoff];
      f16x8 a1 = *(const f16x8*)&As[aoff + 16 * 72];
      f16x8 b0 = *(const f16x8*)&Bs[boff];
      f16x8 b1 = *(const f16x8*)&Bs[boff + 16 * 72];
      acc[0][0] = MFMA16(a0, b0, acc[0][0]);
      acc[0][1] = MFMA16(a0, b1, acc[0][1]);
      acc[1][0] = MFMA16(a1, b0, acc[1][0]);
      acc[1][1] = MFMA16(a1, b1, acc[1][1]);
    }
  }
#pragma unroll
  for (int mi = 0; mi < 2; ++mi)
#pragma unroll
    for (int ni = 0; ni < 2; ++ni)
#pragma unroll
      for (int r = 0; r < 4; ++r) {
        int mg = mt * 64 + (wv & 1) * 32 + mi * 16 + quad * 4 + r;
        if (mg < cnt) {
          int tok = list[mg];
          int col = nt * 64 + (wv >> 1) * 32 + ni * 16 + m16;
          float v = acc[mi][ni][r] * sc[tok];
          y[(size_t)tok * NDIM + col] = v;
        }
      }
}

// ---------------- GEMM2 (fr): f16 weights, t16 @ fr_w2 slice -> z, 2-phase ------------
__global__ __launch_bounds__(256) void k_gemm2_fr(
    const f16* __restrict__ tbuf, const f16* __restrict__ wf, float* __restrict__ zz) {
  int e = blockIdx.z;
  int mt = blockIdx.y, nt = blockIdx.x;
  const f16* A = tbuf + (size_t)e * NTOK * NHID;
  const f16* Bw = wf + (size_t)8 * WSZ + (size_t)e * NDIM * NHID;
  int t = threadIdx.x;
  int wv = t >> 6, lane = t & 63, m16 = lane & 15, quad = lane >> 4;
  int r0 = t >> 3, ak = (t & 7) * 8;
  const f16* ar0 = A + (size_t)(mt * 64 + r0) * NHID;
  const f16* ar1 = A + (size_t)(mt * 64 + r0 + 32) * NHID;
  int ne0 = min(nt * 64 + r0, 287), ne1 = min(nt * 64 + r0 + 32, 287);
  const f16* br0 = Bw + (size_t)(e * 288 + ne0) * NHID;
  const f16* br1 = Bw + (size_t)(e * 288 + ne1) * NHID;
  __shared__ f16 As[64 * 72];
  __shared__ f16 Bs[64 * 72];
  f32x4 zf = {0.f, 0.f, 0.f, 0.f};
  f32x4 acc[2][2] = {{zf, zf}, {zf, zf}};
  uint4 ra0, ra1, rb0, rb1;
  ra0 = *(const uint4*)(ar0 + ak);
  ra1 = *(const uint4*)(ar1 + ak);
  rb0 = *(const uint4*)(br0 + ak);
  rb1 = *(const uint4*)(br1 + ak);
  for (int kc = 0; kc < NHID; kc += 64) {
    __syncthreads();
    *(uint4*)&As[r0 * 72 + ak] = ra0;
    *(uint4*)&As[(r0 + 32) * 72 + ak] = ra1;
    *(uint4*)&Bs[r0 * 72 + ak] = rb0;
    *(uint4*)&Bs[(r0 + 32) * 72 + ak] = rb1;
    __syncthreads();
    int kn = kc + 64;
    if (kn < NHID) {
      ra0 = *(const uint4*)(ar0 + kn + ak);
      ra1 = *(const uint4*)(ar1 + kn + ak);
      rb0 = *(const uint4*)(br0 + kn + ak);
      rb1 = *(const uint4*)(br1 + kn + ak);
    }
#pragma unroll
    for (int ks = 0; ks < 2; ++ks) {
      int aoff = ((wv & 1) * 32 + m16) * 72 + ks * 32 + quad * 8;
      int boff = ((wv >> 1) * 32 + m16) * 72 + ks * 32 + quad * 8;
      f16x8 a0 = *(const f16x8*)&As[aoff];
      f16x8 a1 = *(const f16x8*)&As[aoff + 16 * 72];
      f16x8 b0 = *(const f16x8*)&Bs[boff];
      f16x8 b1 = *(const f16x8*)&Bs[boff + 16 * 72];
      acc[0][0] = MFMA16(a0, b0, acc[0][0]);
      acc[0][1] = MFMA16(a0, b1, acc[0][1]);
      acc[1][0] = MFMA16(a1, b0, acc[1][0]);
      acc[1][1] = MFMA16(a1, b1, acc[1][1]);
    }
  }
#pragma unroll
  for (int mi = 0; mi < 2; ++mi)
#pragma unroll
    for (int ni = 0; ni < 2; ++ni)
#pragma unroll
      for (int r = 0; r < 4; ++r) {
        int cg = nt * 64 + (wv >> 1) * 32 + ni * 16 + m16;
        if (cg < 288) {
          int row = mt * 64 + (wv & 1) * 32 + mi * 16 + quad * 4 + r;
          zz[(size_t)row * NDIM + e * 288 + cg] = acc[mi][ni][r];
        }
      }
}

// ---------------- host ----------------
extern "C" void kernel_launch(void* const* d_in, const int* in_sizes, int n_in,
                              void* d_out, int out_size, void* d_ws, size_t ws_size,
                              hipStream_t stream) {
  const float* x          = (const float*)d_in[0];
  const float* timep      = (const float*)d_in[1];
  const float* caption    = (const float*)d_in[2];
  const float* acoustic   = (const float*)d_in[3];
  const float* attn_in_w  = (const float*)d_in[4];
  const float* attn_in_b  = (const float*)d_in[5];
  const float* attn_out_w = (const float*)d_in[6];
  const float* attn_out_b = (const float*)d_in[7];
  const float* hl_w       = (const float*)d_in[8];
  const float* hl_b       = (const float*)d_in[9];
  const float* cap_gate_w = (const float*)d_in[10];
  const float* cap_gate_b = (const float*)d_in[11];
  const float* ac_gate_w  = (const float*)d_in[12];
  const float* ac_gate_b  = (const float*)d_in[13];
  const float* cap_w1     = (const float*)d_in[14];
  const float* cap_w2     = (const float*)d_in[15];
  const float* cap_w3     = (const float*)d_in[16];
  const float* ac_w1      = (const float*)d_in[17];
  const float* ac_w2      = (const float*)d_in[18];
  const float* ac_w3      = (const float*)d_in[19];
  const float* fr_w1      = (const float*)d_in[20];
  const float* fr_w2      = (const float*)d_in[21];
  const float* fr_w3      = (const float*)d_in[22];
  (void)in_sizes; (void)n_in; (void)out_size; (void)ws_size;

  float* zout = (float*)d_out;
  float* loss = zout + (size_t)NTOK * NDIM;

  char* wsb = (char*)d_ws;
  size_t off = 0;
  auto alloc = [&](size_t bytes) -> void* {
    void* p = wsb + off;
    off = (off + bytes + 255) & ~(size_t)255;
    return p;
  };
  // persistent small + xhi + converted weights
  float* g1     = (float*)alloc(4096 * 4);
  float* g2     = (float*)alloc(8192 * 4);
  float* g3     = (float*)alloc(8192 * 4);
  float* tl     = (float*)alloc(4 * 4);
  float* al     = (float*)alloc((size_t)NTOK * NEXP * 4);
  float* cl     = (float*)alloc((size_t)NTOK * NEXP * 4);
  float* cmv    = (float*)alloc((size_t)NTOK * 4);
  float* amv    = (float*)alloc((size_t)NTOK * 4);
  int*   lists  = (int*)alloc((size_t)8 * NTOK * 4);
  int*   counts = (int*)alloc(8 * 4);
  float* wp     = (float*)alloc((size_t)NEXP * NDIM * 4);
  float* bp     = (float*)alloc(NEXP * 4);
  f16*   xhi    = (f16*)alloc((size_t)NTOK * NDIM * 2);
  f16*   wf16   = (f16*)alloc((size_t)9 * WSZ * 2);
  size_t region = off;
  // phase 1 (attention / routing inputs)
  f16*   xlo    = (f16*)alloc((size_t)NTOK * NDIM * 2);
  f16*   caphi  = (f16*)alloc((size_t)NCAP * NDIM * 2);
  f16*   caplo  = (f16*)alloc((size_t)NCAP * NDIM * 2);
  f16*   qhi    = (f16*)alloc((size_t)NTOK * NDIM * 2);
  f16*   qlo    = (f16*)alloc((size_t)NTOK * NDIM * 2);
  f16*   khi    = (f16*)alloc((size_t)NCAP * NDIM * 2);
  f16*   klo    = (f16*)alloc((size_t)NCAP * NDIM * 2);
  f16*   vthi   = (f16*)alloc((size_t)NB * NDIM * NSC * 2);
  f16*   vtlo   = (f16*)alloc((size_t)NB * NDIM * NSC * 2);
  f16*   ohi    = (f16*)alloc((size_t)NTOK * NDIM * 2);
  f16*   olo    = (f16*)alloc((size_t)NTOK * NDIM * 2);
  // phase 2 (MoE / fr) — reuses phase-1 region (all phase-1 buffers dead)
  off = region;
  f16*   tbuf   = (f16*)alloc((size_t)8 * NTOK * NHID * 2);
  float* ybc    = (float*)alloc((size_t)NTOK * NDIM * 4);
  float* yba    = (float*)alloc((size_t)NTOK * NDIM * 4);
  f16*   y16    = (f16*)alloc((size_t)NTOK * NDIM * 2);

  k_prep<<<dim3(1), dim3(256), 0, stream>>>(timep, hl_w, hl_b, g1, g2, g3, tl);
  k_fuse_gate<<<dim3(6), dim3(256), 0, stream>>>(attn_out_w, attn_out_b,
                                                 cap_gate_w, cap_gate_b, wp, bp);
  k_ac_logits<<<dim3(512), dim3(256), 0, stream>>>(acoustic, ac_gate_w, ac_gate_b, al);
  k_cvt_split<<<dim3(2304), dim3(256), 0, stream>>>(x, xhi, xlo, NTOK * NDIM);
  k_cvt_split<<<dim3(288), dim3(256), 0, stream>>>(caption, caphi, caplo, NCAP * NDIM);
  // fused: QKV projection (z<3) + grid-stride cvt of slots 0-3 (z=3,4)
  k_gemm_qkv<<<dim3(18, 32, 5), dim3(256), 0, stream>>>(
      xhi, xlo, caphi, caplo, attn_in_w, attn_in_b,
      qhi, qlo, khi, klo, vthi, vtlo,
      cap_w1, cap_w3, ac_w1, ac_w3, wf16);
  k_attn<<<dim3(16, 16), dim3(256), 0, stream>>>(qhi, qlo, khi, klo, vthi, vtlo, ohi, olo);
  // cap-gate logits directly from o via fused W' (k_ca eliminated)
  k_o_logits<<<dim3(512), dim3(256), 0, stream>>>(ohi, olo, wp, bp, cl);
  k_route<<<dim3(1), dim3(1024), 0, stream>>>(cl, al, g1, g2, g3, tl,
                                              cmv, amv, lists, counts, loss);
  // gemm1 pass-1 (8 groups) + tail cvt blocks for slots 4-8 (3072 + 1080)
  k_gemm1<<<dim3(4152), dim3(256), 0, stream>>>(xhi, y16, wf16, lists, counts, tbuf,
                                                fr_w1, fr_w3, cap_w2, ac_w2, fr_w2, 0, 8);
  k_gemm2<<<dim3(4608), dim3(256), 0, stream>>>(tbuf, wf16, lists, counts,
                                                cmv, amv, ybc, yba);
  k_cvt_add<<<dim3(2304), dim3(256), 0, stream>>>(ybc, yba, y16, NTOK * NDIM);
  k_gemm1<<<dim3(1536), dim3(256), 0, stream>>>(xhi, y16, wf16, lists, counts, tbuf,
                                                fr_w1, fr_w3, cap_w2, ac_w2, fr_w2, 8, 4);
  k_gemm2_fr<<<dim3(5, 32, 4), dim3(256), 0, stream>>>(tbuf, wf16, zout);
}

// Round 7
// 447.969 us; speedup vs baseline: 1.2992x; 1.2992x over previous
//
#include <hip/hip_runtime.h>
#include <stdint.h>

#define NDIM 1152
#define NEXP 4
#define NHID 768
#define NHEAD 8
#define HDIM 144
#define NB 2
#define NS 1024
#define NSC 128
#define NTOK 2048
#define NCAP 256

typedef _Float16 f16;
typedef _Float16 f16x4 __attribute__((ext_vector_type(4)));
typedef _Float16 f16x8 __attribute__((ext_vector_type(8)));
typedef float f32x4 __attribute__((ext_vector_type(4)));

#define MFMA16(a, b, c) __builtin_amdgcn_mfma_f32_16x16x32_f16(a, b, c, 0, 0, 0)

#define WSZ ((size_t)NEXP * NHID * NDIM)  // elems per weight tensor (3,538,944)
#define WCH ((size_t)(WSZ / 8))           // 8-elem chunks per tensor (442,368)

// ---------------- Threefry2x32 (exact JAX replication) ----------------
__device__ inline uint2 tfry(uint32_t k0, uint32_t k1, uint32_t x0, uint32_t x1) {
  uint32_t k2 = k0 ^ k1 ^ 0x1BD11BDAu;
#define RND(r) { x0 += x1; x1 = (x1 << r) | (x1 >> (32 - r)); x1 ^= x0; }
  x0 += k0; x1 += k1;
  RND(13) RND(15) RND(26) RND(6)
  x0 += k1; x1 += k2 + 1u;
  RND(17) RND(29) RND(16) RND(24)
  x0 += k2; x1 += k0 + 2u;
  RND(13) RND(15) RND(26) RND(6)
  x0 += k0; x1 += k1 + 3u;
  RND(17) RND(29) RND(16) RND(24)
  x0 += k1; x1 += k2 + 4u;
  RND(13) RND(15) RND(26) RND(6)
  x0 += k2; x1 += k0 + 5u;
#undef RND
  return make_uint2(x0, x1);
}

__device__ inline float b2g(uint32_t bits) {
  uint32_t fb = (bits >> 9) | 0x3f800000u;
  float f = __uint_as_float(fb) - 1.0f;
  const float tiny = 1.1754943508222875e-38f;
  float u = f * 1.0f + tiny;
  u = fmaxf(tiny, u);
  return -logf(-logf(u));
}

// ---------------- prep: keys, gumbels, time-logits ----------------
__global__ void k_prep(const float* __restrict__ timep, const float* __restrict__ hlw,
                       const float* __restrict__ hlb,
                       float* __restrict__ g1, float* __restrict__ g2, float* __restrict__ g3,
                       float* __restrict__ tl) {
  int t = threadIdx.x;  // 256
  uint2 k1 = tfry(0u, 42u, 0u, 0u);
  uint2 k2 = tfry(0u, 42u, 0u, 1u);
  uint2 k3 = tfry(0u, 42u, 0u, 2u);
  for (int p = t; p < 4096; p += 256) {
    uint2 o = tfry(k1.x, k1.y, 0u, (uint32_t)p);
    g1[p] = b2g(o.x ^ o.y);
  }
  for (int p = t; p < 8192; p += 256) {
    uint2 o2 = tfry(k2.x, k2.y, 0u, (uint32_t)p);
    g2[p] = b2g(o2.x ^ o2.y);
    uint2 o3 = tfry(k3.x, k3.y, 0u, (uint32_t)p);
    g3[p] = b2g(o3.x ^ o3.y);
  }
  int wv = t >> 6, lane = t & 63;
  {
    int b = wv >> 1, j = wv & 1;
    float s = 0.f;
    for (int k = lane; k < NDIM; k += 64) s += timep[b * NDIM + k] * hlw[j * NDIM + k];
    for (int m = 32; m; m >>= 1) s += __shfl_xor(s, m);
    if (lane == 0) tl[b * 2 + j] = s + hlb[j];
  }
}

// ---------------- fused gate stage 1: partials wpp[dc][e][k] over 64-d chunks ---------
// grid 90 = 5 k-tiles x 18 d-chunks; coalesced ow row reads, high ILP.
__global__ void k_fuse_gate1(const float* __restrict__ ow, const float* __restrict__ gw,
                             float* __restrict__ wpp) {
  int kt = blockIdx.x % 5;
  int dc = blockIdx.x / 5;
  int k = kt * 256 + threadIdx.x;
  if (k >= NDIM) return;
  float a0 = 0.f, a1 = 0.f, a2 = 0.f, a3 = 0.f;
#pragma unroll 8
  for (int j = 0; j < 64; ++j) {
    int d = dc * 64 + j;
    float o = ow[(size_t)d * NDIM + k];
    a0 += gw[d] * o;
    a1 += gw[NDIM + d] * o;
    a2 += gw[2 * NDIM + d] * o;
    a3 += gw[3 * NDIM + d] * o;
  }
  float* p = wpp + (size_t)dc * 4 * NDIM;
  p[k] = a0; p[NDIM + k] = a1; p[2 * NDIM + k] = a2; p[3 * NDIM + k] = a3;
}

// ---------------- fused gate stage 2: deterministic 18-way reduce + bias --------------
__global__ void k_fuse_gate2(const float* __restrict__ wpp,
                             const float* __restrict__ gw, const float* __restrict__ ob,
                             const float* __restrict__ gb,
                             float* __restrict__ wp, float* __restrict__ bp) {
  if (blockIdx.x == 18) {
    int wv = threadIdx.x >> 6, lane = threadIdx.x & 63;  // wv = e
    float s = 0.f;
    for (int d = lane; d < NDIM; d += 64) s += ob[d] * gw[wv * NDIM + d];
    for (int m = 32; m; m >>= 1) s += __shfl_xor(s, m);
    if (lane == 0) bp[wv] = s + gb[wv];
    return;
  }
  int i = blockIdx.x * 256 + threadIdx.x;  // 0 .. 4607
  float s = 0.f;
#pragma unroll
  for (int c = 0; c < 18; ++c) s += wpp[(size_t)c * 4 * NDIM + i];
  wp[i] = s;
}

// ---------------- generic 4-logit head: out[n,e] = in[n,:]·w[e,:] + b[e] ----------------
__global__ void k_ac_logits(const float* __restrict__ ac, const float* __restrict__ agw,
                            const float* __restrict__ agb, float* __restrict__ al) {
  int wv = threadIdx.x >> 6, lane = threadIdx.x & 63;
  int n = blockIdx.x * 4 + wv;
  float s[NEXP] = {0.f, 0.f, 0.f, 0.f};
  for (int d = lane; d < NDIM; d += 64) {
    float a = ac[(size_t)n * NDIM + d];
#pragma unroll
    for (int e = 0; e < NEXP; ++e) s[e] += a * agw[e * NDIM + d];
  }
#pragma unroll
  for (int e = 0; e < NEXP; ++e)
    for (int m = 32; m; m >>= 1) s[e] += __shfl_xor(s[e], m);
  if (lane == 0) {
#pragma unroll
    for (int e = 0; e < NEXP; ++e) al[n * NEXP + e] = s[e] + agb[e];
  }
}

// ---------------- cap logits from split-f16 o: cl[n,e] = o[n,:]·W'[e,:] + b'[e] -------
__global__ void k_o_logits(const f16* __restrict__ ohi, const f16* __restrict__ olo,
                           const float* __restrict__ wp, const float* __restrict__ bp,
                           float* __restrict__ cl) {
  int wv = threadIdx.x >> 6, lane = threadIdx.x & 63;
  int n = blockIdx.x * 4 + wv;
  float s[NEXP] = {0.f, 0.f, 0.f, 0.f};
  for (int d = lane; d < NDIM; d += 64) {
    size_t gi = (size_t)n * NDIM + d;
    float a = (float)ohi[gi] + (float)olo[gi] * (1.f / 2048.f);
#pragma unroll
    for (int e = 0; e < NEXP; ++e) s[e] += a * wp[e * NDIM + d];
  }
#pragma unroll
  for (int e = 0; e < NEXP; ++e)
    for (int m = 32; m; m >>= 1) s[e] += __shfl_xor(s[e], m);
  if (lane == 0) {
#pragma unroll
    for (int e = 0; e < NEXP; ++e) cl[n * NEXP + e] = s[e] + bp[e];
  }
}

// ---------------- fp32 + fp32 -> fp16 convert (fused add) ----------------
__global__ void k_cvt_add(const float* __restrict__ srca, const float* __restrict__ srcb,
                          f16* __restrict__ dst, int n) {
  int i = (blockIdx.x * 256 + threadIdx.x) * 4;
  if (i + 3 < n) {
    float4 va = *(const float4*)(srca + i);
    float4 vb = *(const float4*)(srcb + i);
    f16x4 h;
    h[0] = (f16)(va.x + vb.x); h[1] = (f16)(va.y + vb.y);
    h[2] = (f16)(va.z + vb.z); h[3] = (f16)(va.w + vb.w);
    *(f16x4*)(dst + i) = h;
  }
}

// ---------------- fp32 -> fp16 hi/lo split convert (lo pre-scaled by 2048) ----------------
__global__ void k_cvt_split(const float* __restrict__ src, f16* __restrict__ hi,
                            f16* __restrict__ lo, int n) {
  int i = (blockIdx.x * 256 + threadIdx.x) * 4;
  if (i + 3 < n) {
    float4 v = *(const float4*)(src + i);
    f16x4 h, l;
    h[0] = (f16)v.x; l[0] = (f16)((v.x - (float)h[0]) * 2048.f);
    h[1] = (f16)v.y; l[1] = (f16)((v.y - (float)h[1]) * 2048.f);
    h[2] = (f16)v.z; l[2] = (f16)((v.z - (float)h[2]) * 2048.f);
    h[3] = (f16)v.w; l[3] = (f16)((v.w - (float)h[3]) * 2048.f);
    *(f16x4*)(hi + i) = h;
    *(f16x4*)(lo + i) = l;
  }
}

// ---------------- QKV projection + fused weight cvt (slots 0-3) ----------------
// z<3: split-fp16 QKV GEMM (2-phase prefetch). z==2 (V) emits transposed split-fp16.
// z in {3,4}: grid-stride f32->f16 conversion of cap_w1/cap_w3/ac_w1/ac_w3.
__global__ __launch_bounds__(256) void k_gemm_qkv(
    const f16* __restrict__ xhi, const f16* __restrict__ xlo,
    const f16* __restrict__ caphi, const f16* __restrict__ caplo,
    const float* __restrict__ inw, const float* __restrict__ inb,
    f16* __restrict__ qhi, f16* __restrict__ qlo,
    f16* __restrict__ khi, f16* __restrict__ klo,
    f16* __restrict__ vthi, f16* __restrict__ vtlo,
    const float* __restrict__ w0, const float* __restrict__ w1,
    const float* __restrict__ w2, const float* __restrict__ w3,
    f16* __restrict__ wf16) {
  int z = blockIdx.z;
  if (z >= 3) {
    // 4*WCH = 1,769,472 chunks over 1152 blocks -> 1536 chunks/block (1536 | WCH)
    int cvtid = (z - 3) * 576 + blockIdx.y * 18 + blockIdx.x;
    size_t c0 = (size_t)cvtid * 1536;
    int slot = (int)(c0 / WCH);               // block-uniform
    size_t base = (c0 % WCH) * 8;
    const float* s = ((slot == 0) ? w0 : (slot == 1) ? w1 : (slot == 2) ? w2 : w3) + base;
    f16* dst = wf16 + (size_t)slot * WSZ + base;
#pragma unroll
    for (int i = 0; i < 6; ++i) {
      size_t off = (size_t)(threadIdx.x + i * 256) * 8;
      float4 v0 = *(const float4*)(s + off);
      float4 v1 = *(const float4*)(s + off + 4);
      f16x8 h;
      h[0] = (f16)v0.x; h[1] = (f16)v0.y; h[2] = (f16)v0.z; h[3] = (f16)v0.w;
      h[4] = (f16)v1.x; h[5] = (f16)v1.y; h[6] = (f16)v1.z; h[7] = (f16)v1.w;
      *(f16x8*)(dst + off) = h;
    }
    return;
  }
  int M = (z == 0) ? NTOK : NCAP;
  int mt = blockIdx.y, nt = blockIdx.x;
  if (mt * 64 >= M) return;
  const f16* Ah_g = (z == 0) ? xhi : caphi;
  const f16* Al_g = (z == 0) ? xlo : caplo;
  __shared__ f16 Ash[64 * 72];
  __shared__ f16 Asl[64 * 72];
  __shared__ f16 Bsh[64 * 72];
  __shared__ f16 Bsl[64 * 72];
  int t = threadIdx.x;
  int wv = t >> 6, lane = t & 63, m16 = lane & 15, quad = lane >> 4;
  int r0 = t >> 3, ak = (t & 7) * 8;
  size_t a0o = (size_t)(mt * 64 + r0) * NDIM;
  size_t a1o = (size_t)(mt * 64 + r0 + 32) * NDIM;
  f32x4 zf = {0.f, 0.f, 0.f, 0.f};
  f32x4 ah[2][2] = {{zf, zf}, {zf, zf}};
  f32x4 am[2][2] = {{zf, zf}, {zf, zf}};
  uint4 rah0, rah1, ral0, ral1;
  float4 rbw[4];
  rah0 = *(const uint4*)(Ah_g + a0o + ak);
  rah1 = *(const uint4*)(Ah_g + a1o + ak);
  ral0 = *(const uint4*)(Al_g + a0o + ak);
  ral1 = *(const uint4*)(Al_g + a1o + ak);
#pragma unroll
  for (int uu = 0; uu < 4; ++uu) {
    int u = t + uu * 256;
    int rr = u >> 4, kp = (u & 15) * 4;
    rbw[uu] = *(const float4*)(inw + (size_t)(z * NDIM + nt * 64 + rr) * NDIM + kp);
  }
  for (int kc = 0; kc < NDIM; kc += 64) {
    __syncthreads();
    *(uint4*)&Ash[r0 * 72 + ak] = rah0;
    *(uint4*)&Ash[(r0 + 32) * 72 + ak] = rah1;
    *(uint4*)&Asl[r0 * 72 + ak] = ral0;
    *(uint4*)&Asl[(r0 + 32) * 72 + ak] = ral1;
#pragma unroll
    for (int uu = 0; uu < 4; ++uu) {
      int u = t + uu * 256;
      int rr = u >> 4, kp = (u & 15) * 4;
      f16x4 hb, lb;
      hb[0] = (f16)rbw[uu].x; lb[0] = (f16)((rbw[uu].x - (float)hb[0]) * 2048.f);
      hb[1] = (f16)rbw[uu].y; lb[1] = (f16)((rbw[uu].y - (float)hb[1]) * 2048.f);
      hb[2] = (f16)rbw[uu].z; lb[2] = (f16)((rbw[uu].z - (float)hb[2]) * 2048.f);
      hb[3] = (f16)rbw[uu].w; lb[3] = (f16)((rbw[uu].w - (float)hb[3]) * 2048.f);
      *(f16x4*)&Bsh[rr * 72 + kp] = hb;
      *(f16x4*)&Bsl[rr * 72 + kp] = lb;
    }
    __syncthreads();
    int kn = kc + 64;
    if (kn < NDIM) {
      rah0 = *(const uint4*)(Ah_g + a0o + kn + ak);
      rah1 = *(const uint4*)(Ah_g + a1o + kn + ak);
      ral0 = *(const uint4*)(Al_g + a0o + kn + ak);
      ral1 = *(const uint4*)(Al_g + a1o + kn + ak);
#pragma unroll
      for (int uu = 0; uu < 4; ++uu) {
        int u = t + uu * 256;
        int rr = u >> 4, kp = (u & 15) * 4;
        rbw[uu] = *(const float4*)(inw + (size_t)(z * NDIM + nt * 64 + rr) * NDIM + kn + kp);
      }
    }
#pragma unroll
    for (int ks = 0; ks < 2; ++ks) {
      int aoff = ((wv & 1) * 32 + m16) * 72 + ks * 32 + quad * 8;
      int boff = ((wv >> 1) * 32 + m16) * 72 + ks * 32 + quad * 8;
      f16x8 a0h = *(const f16x8*)&Ash[aoff];
      f16x8 a1h = *(const f16x8*)&Ash[aoff + 16 * 72];
      f16x8 a0l = *(const f16x8*)&Asl[aoff];
      f16x8 a1l = *(const f16x8*)&Asl[aoff + 16 * 72];
      f16x8 b0h = *(const f16x8*)&Bsh[boff];
      f16x8 b1h = *(const f16x8*)&Bsh[boff + 16 * 72];
      f16x8 b0l = *(const f16x8*)&Bsl[boff];
      f16x8 b1l = *(const f16x8*)&Bsl[boff + 16 * 72];
      ah[0][0] = MFMA16(a0h, b0h, ah[0][0]);
      ah[0][1] = MFMA16(a0h, b1h, ah[0][1]);
      ah[1][0] = MFMA16(a1h, b0h, ah[1][0]);
      ah[1][1] = MFMA16(a1h, b1h, ah[1][1]);
      am[0][0] = MFMA16(a0h, b0l, am[0][0]);
      am[0][1] = MFMA16(a0h, b1l, am[0][1]);
      am[1][0] = MFMA16(a1h, b0l, am[1][0]);
      am[1][1] = MFMA16(a1h, b1l, am[1][1]);
      am[0][0] = MFMA16(a0l, b0h, am[0][0]);
      am[0][1] = MFMA16(a0l, b1h, am[0][1]);
      am[1][0] = MFMA16(a1l, b0h, am[1][0]);
      am[1][1] = MFMA16(a1l, b1h, am[1][1]);
    }
  }
#pragma unroll
  for (int mi = 0; mi < 2; ++mi)
#pragma unroll
    for (int ni = 0; ni < 2; ++ni)
#pragma unroll
      for (int r = 0; r < 4; ++r) {
        int row = mt * 64 + (wv & 1) * 32 + mi * 16 + quad * 4 + r;
        int col = nt * 64 + (wv >> 1) * 32 + ni * 16 + m16;
        float v = ah[mi][ni][r] + am[mi][ni][r] * (1.f / 2048.f) + inb[z * NDIM + col];
        size_t idx = (size_t)row * NDIM + col;
        if (z == 0) {
          f16 hq = (f16)v;
          qhi[idx] = hq;
          qlo[idx] = (f16)((v - (float)hq) * 2048.f);
        } else if (z == 1) {
          f16 hk = (f16)v;
          khi[idx] = hk;
          klo[idx] = (f16)((v - (float)hk) * 2048.f);
        } else {
          f16 hv = (f16)v;
          int bb = row >> 7, kv = row & 127;
          size_t ti = (size_t)(bb * NDIM + col) * NSC + kv;
          vthi[ti] = hv;
          vtlo[ti] = (f16)((v - (float)hv) * 2048.f);
        }
      }
}

// ---------------- fused attention: QK^T + softmax + PV, split-fp16, writes o hi/lo ----
__global__ __launch_bounds__(256) void k_attn(
    const f16* __restrict__ qhi, const f16* __restrict__ qlo,
    const f16* __restrict__ khi, const f16* __restrict__ klo,
    const f16* __restrict__ vthi, const f16* __restrict__ vtlo,
    f16* __restrict__ ohi, f16* __restrict__ olo) {
  int mt = blockIdx.x, bh = blockIdx.y;
  int b = bh >> 3, h = bh & 7;
  __shared__ f16 Ah[64 * 160];
  __shared__ f16 Al[64 * 160];
  __shared__ f16 Bh[32 * 160];
  __shared__ f16 Bl[32 * 160];
  __shared__ f16 Ph[64 * 136];
  __shared__ f16 Pl[64 * 136];
  int t = threadIdx.x;
  int wv = t >> 6, lane = t & 63, m16 = lane & 15, quad = lane >> 4;
  for (int u = t; u < 64 * 20; u += 256) {
    int r = u / 20, kp = (u % 20) * 8;
    uint4 vh = make_uint4(0u, 0u, 0u, 0u), vl = vh;
    if (kp < HDIM) {
      size_t gi = (size_t)(b * NS + mt * 64 + r) * NDIM + h * HDIM + kp;
      vh = *(const uint4*)&qhi[gi];
      vl = *(const uint4*)&qlo[gi];
    }
    *(uint4*)&Ah[r * 160 + kp] = vh;
    *(uint4*)&Al[r * 160 + kp] = vl;
  }
  __syncthreads();
  f16x8 ahf[5], alf[5];
#pragma unroll
  for (int ks = 0; ks < 5; ++ks) {
    int ao = (wv * 16 + m16) * 160 + ks * 32 + quad * 8;
    ahf[ks] = *(const f16x8*)&Ah[ao];
    alf[ks] = *(const f16x8*)&Al[ao];
  }
  f32x4 zf = {0.f, 0.f, 0.f, 0.f};
  f32x4 sh_[4][2], sm_[4][2];
#pragma unroll
  for (int kt = 0; kt < 4; ++kt)
#pragma unroll
    for (int ni = 0; ni < 2; ++ni) { sh_[kt][ni] = zf; sm_[kt][ni] = zf; }
  for (int kt = 0; kt < 4; ++kt) {
    if (kt) __syncthreads();
    for (int u = t; u < 32 * 20; u += 256) {
      int r = u / 20, kp = (u % 20) * 8;
      uint4 vh = make_uint4(0u, 0u, 0u, 0u), vl = vh;
      if (kp < HDIM) {
        size_t gi = (size_t)(b * NSC + kt * 32 + r) * NDIM + h * HDIM + kp;
        vh = *(const uint4*)&khi[gi];
        vl = *(const uint4*)&klo[gi];
      }
      *(uint4*)&Bh[r * 160 + kp] = vh;
      *(uint4*)&Bl[r * 160 + kp] = vl;
    }
    __syncthreads();
#pragma unroll
    for (int ks = 0; ks < 5; ++ks) {
#pragma unroll
      for (int ni = 0; ni < 2; ++ni) {
        int bo = (ni * 16 + m16) * 160 + ks * 32 + quad * 8;
        f16x8 bhf = *(const f16x8*)&Bh[bo];
        f16x8 blf = *(const f16x8*)&Bl[bo];
        sh_[kt][ni] = MFMA16(ahf[ks], bhf, sh_[kt][ni]);
        sm_[kt][ni] = MFMA16(ahf[ks], blf, sm_[kt][ni]);
        sm_[kt][ni] = MFMA16(alf[ks], bhf, sm_[kt][ni]);
      }
    }
  }
  float sv[4][2][4];
  float mx[4] = {-1e30f, -1e30f, -1e30f, -1e30f};
#pragma unroll
  for (int kt = 0; kt < 4; ++kt)
#pragma unroll
    for (int ni = 0; ni < 2; ++ni)
#pragma unroll
      for (int r = 0; r < 4; ++r) {
        float s = (sh_[kt][ni][r] + sm_[kt][ni][r] * (1.f / 2048.f)) * (1.f / 12.f);
        sv[kt][ni][r] = s;
        mx[r] = fmaxf(mx[r], s);
      }
#pragma unroll
  for (int r = 0; r < 4; ++r) {
    mx[r] = fmaxf(mx[r], __shfl_xor(mx[r], 1));
    mx[r] = fmaxf(mx[r], __shfl_xor(mx[r], 2));
    mx[r] = fmaxf(mx[r], __shfl_xor(mx[r], 4));
    mx[r] = fmaxf(mx[r], __shfl_xor(mx[r], 8));
  }
  float sum[4] = {0.f, 0.f, 0.f, 0.f};
#pragma unroll
  for (int kt = 0; kt < 4; ++kt)
#pragma unroll
    for (int ni = 0; ni < 2; ++ni)
#pragma unroll
      for (int r = 0; r < 4; ++r) {
        float e = expf(sv[kt][ni][r] - mx[r]);
        sv[kt][ni][r] = e;
        sum[r] += e;
      }
  float inv[4];
#pragma unroll
  for (int r = 0; r < 4; ++r) {
    sum[r] += __shfl_xor(sum[r], 1);
    sum[r] += __shfl_xor(sum[r], 2);
    sum[r] += __shfl_xor(sum[r], 4);
    sum[r] += __shfl_xor(sum[r], 8);
    inv[r] = 1.0f / sum[r];
  }
#pragma unroll
  for (int kt = 0; kt < 4; ++kt)
#pragma unroll
    for (int ni = 0; ni < 2; ++ni)
#pragma unroll
      for (int r = 0; r < 4; ++r) {
        float p = sv[kt][ni][r] * inv[r];
        int row = wv * 16 + quad * 4 + r;
        int col = kt * 32 + ni * 16 + m16;
        f16 ph = (f16)p;
        Ph[row * 136 + col] = ph;
        Pl[row * 136 + col] = (f16)((p - (float)ph) * 2048.f);
      }
  const f16* vbh = vthi + (size_t)(b * NDIM + h * HDIM) * NSC;
  const f16* vbl = vtlo + (size_t)(b * NDIM + h * HDIM) * NSC;
  f32x4 oh_[9], om_[9];
#pragma unroll
  for (int nb = 0; nb < 9; ++nb) { oh_[nb] = zf; om_[nb] = zf; }
#pragma unroll
  for (int ks = 0; ks < 4; ++ks) {
    int po = (wv * 16 + m16) * 136 + ks * 32 + quad * 8;
    f16x8 pah = *(const f16x8*)&Ph[po];
    f16x8 pal = *(const f16x8*)&Pl[po];
#pragma unroll
    for (int nb = 0; nb < 9; ++nb) {
      size_t vo = (size_t)(nb * 16 + m16) * NSC + ks * 32 + quad * 8;
      f16x8 bvh = *(const f16x8*)&vbh[vo];
      f16x8 bvl = *(const f16x8*)&vbl[vo];
      oh_[nb] = MFMA16(pah, bvh, oh_[nb]);
      om_[nb] = MFMA16(pah, bvl, om_[nb]);
      om_[nb] = MFMA16(pal, bvh, om_[nb]);
    }
  }
#pragma unroll
  for (int nb = 0; nb < 9; ++nb)
#pragma unroll
    for (int r = 0; r < 4; ++r) {
      int row = mt * 64 + wv * 16 + quad * 4 + r;
      int col = h * HDIM + nb * 16 + m16;
      float v = oh_[nb][r] + om_[nb][r] * (1.f / 2048.f);
      size_t idx = (size_t)(b * NS + row) * NDIM + col;
      f16 hv = (f16)v;
      ohi[idx] = hv;
      olo[idx] = (f16)((v - (float)hv) * 2048.f);
    }
}

// ---------------- routing: argmax gates, cm/am, lists, loss ----------------
__global__ __launch_bounds__(1024) void k_route(
    const float* __restrict__ cl, const float* __restrict__ al,
    const float* __restrict__ g1, const float* __restrict__ g2,
    const float* __restrict__ g3, const float* __restrict__ tl,
    float* __restrict__ cmv, float* __restrict__ amv,
    int* __restrict__ lists, int* __restrict__ counts, float* __restrict__ out_loss) {
  __shared__ int lcnt[8];
  __shared__ float bins[8];
  __shared__ float ssum[2];
  int t = threadIdx.x;
  if (t < 8) { lcnt[t] = 0; bins[t] = 0.f; }
  if (t < 2) ssum[t] = 0.f;
  __syncthreads();
  for (int n = t; n < NTOK; n += 1024) {
    float lc[NEXP];
#pragma unroll
    for (int e = 0; e < NEXP; ++e) lc[e] = cl[n * NEXP + e] + g2[n * 4 + e];
    int ec = 0; float bv = lc[0];
#pragma unroll
    for (int e = 1; e < NEXP; ++e) if (lc[e] > bv) { bv = lc[e]; ec = e; }
    float la[NEXP];
#pragma unroll
    for (int e = 0; e < NEXP; ++e) la[e] = al[n * NEXP + e] + g3[n * 4 + e];
    int ea = 0; float bva = la[0];
#pragma unroll
    for (int e = 1; e < NEXP; ++e) if (la[e] > bva) { bva = la[e]; ea = e; }
    int b = n >> 10;
    float a0 = tl[b * 2 + 0] + g1[n * 2 + 0];
    float a1 = tl[b * 2 + 1] + g1[n * 2 + 1];
    float mx = fmaxf(a0, a1);
    float e0 = expf(a0 - mx), e1 = expf(a1 - mx);
    float cm = e0 / (e0 + e1), am = e1 / (e0 + e1);
    cmv[n] = cm; amv[n] = am;
    int p0 = atomicAdd(&lcnt[ec], 1);
    lists[ec * NTOK + p0] = n;
    int p1 = atomicAdd(&lcnt[4 + ea], 1);
    lists[(4 + ea) * NTOK + p1] = n;
    atomicAdd(&bins[ec], cm);
    atomicAdd(&bins[4 + ea], am);
    atomicAdd(&ssum[0], cm);
    atomicAdd(&ssum[1], am);
  }
  __syncthreads();
  if (t < 8) counts[t] = lcnt[t];
  if (t == 0) {
    float denom = 4.f * (ssum[0] + ssum[1]) + 1e-10f;
    float acc = 0.f;
    for (int j = 0; j < 8; ++j) {
      float u = bins[j] / denom;
      acc += u * logf(u + 1e-10f);
    }
    out_loss[0] = acc / 8.f;
  }
}

// ---------------- GEMM1: M64, f16 weights, XCD-grouped remap, 2-phase prefetch --------
// For gbase==0 launch, blocks beyond G*384 convert weight slots 4-8 (grid-stride cvt).
__global__ __launch_bounds__(256) void k_gemm1(
    const f16* __restrict__ x16, const f16* __restrict__ y16,
    f16* wf,
    const int* __restrict__ lists, const int* __restrict__ counts,
    f16* __restrict__ tbuf,
    const float* __restrict__ w4, const float* __restrict__ w5,
    const float* __restrict__ w6, const float* __restrict__ w7,
    const float* __restrict__ w8, int gbase, int G) {
  int bid = blockIdx.x;
  int nblk = G * 384;
  if (bid >= nblk) {
    // 5*WCH = 2,211,840 chunks over 1080 blocks -> 2048 chunks/block (2048 | WCH)
    int cvtid = bid - nblk;
    size_t c0 = (size_t)cvtid * 2048;
    int sg = (int)(c0 / WCH);                 // block-uniform
    size_t base = (c0 % WCH) * 8;
    const float* s = ((sg == 0) ? w4 : (sg == 1) ? w5 : (sg == 2) ? w6
                       : (sg == 3) ? w7 : w8) + base;
    f16* dst = wf + (size_t)(4 + sg) * WSZ + base;
#pragma unroll
    for (int i = 0; i < 8; ++i) {
      size_t off = (size_t)(threadIdx.x + i * 256) * 8;
      float4 v0 = *(const float4*)(s + off);
      float4 v1 = *(const float4*)(s + off + 4);
      f16x8 h;
      h[0] = (f16)v0.x; h[1] = (f16)v0.y; h[2] = (f16)v0.z; h[3] = (f16)v0.w;
      h[4] = (f16)v1.x; h[5] = (f16)v1.y; h[6] = (f16)v1.z; h[7] = (f16)v1.w;
      *(f16x8*)(dst + off) = h;
    }
    return;
  }
  int xcd = bid & 7;
  int local = bid >> 3;
  int ppx = (G * 12) >> 3;               // pairs per xcd (8->12, 4->6)
  int pair = xcd * ppx + (local >> 5);   // MT = 32
  int mt = local & 31;
  int g = gbase + pair / 12;
  int nt = pair % 12;
  const f16* A; const f16* B1; const f16* B3; f16* tout;
  const int* list = nullptr;
  int cnt, koff, K;
  if (g < 8) {
    int e = g & 3;
    cnt = counts[g];
    list = lists + g * NTOK;
    A = x16; koff = 0; K = NDIM;
    B1 = wf + (size_t)((g < 4) ? 0 : 2) * WSZ + (size_t)e * NHID * NDIM;
    B3 = wf + (size_t)((g < 4) ? 1 : 3) * WSZ + (size_t)e * NHID * NDIM;
    tout = tbuf + (size_t)g * NTOK * NHID;
  } else {
    int e = g - 8;
    cnt = NTOK;
    A = y16; koff = e * 288; K = 288;
    B1 = wf + (size_t)4 * WSZ + (size_t)e * NHID * NDIM + koff;
    B3 = wf + (size_t)5 * WSZ + (size_t)e * NHID * NDIM + koff;
    tout = tbuf + (size_t)e * NTOK * NHID;
  }
  if (mt * 64 >= cnt) return;
  int t = threadIdx.x;
  int wv = t >> 6, lane = t & 63, m16 = lane & 15, quad = lane >> 4;
  int r0 = t >> 3, ak = (t & 7) * 8;
  int m0 = mt * 64 + r0, m1 = m0 + 32;
  int tok0, tok1;
  if (list) { tok0 = list[min(m0, cnt - 1)]; tok1 = list[min(m1, cnt - 1)]; }
  else { tok0 = m0; tok1 = m1; }
  const f16* ar0 = A + (size_t)tok0 * NDIM + koff;
  const f16* ar1 = A + (size_t)tok1 * NDIM + koff;
  const f16* b1r0 = B1 + (size_t)(nt * 64 + r0) * NDIM;
  const f16* b1r1 = B1 + (size_t)(nt * 64 + r0 + 32) * NDIM;
  const f16* b3r0 = B3 + (size_t)(nt * 64 + r0) * NDIM;
  const f16* b3r1 = B3 + (size_t)(nt * 64 + r0 + 32) * NDIM;
  __shared__ f16 As[64 * 72];
  __shared__ f16 Bs1[64 * 72];
  __shared__ f16 Bs2[64 * 72];
  f32x4 zf = {0.f, 0.f, 0.f, 0.f};
  f32x4 ac1[2][2] = {{zf, zf}, {zf, zf}};
  f32x4 ac2[2][2] = {{zf, zf}, {zf, zf}};
  uint4 z4u = make_uint4(0u, 0u, 0u, 0u);
  uint4 ra0, ra1, rb10, rb11, rb30, rb31;
  {
    bool v = (ak < K);
    ra0  = v ? *(const uint4*)(ar0 + ak) : z4u;
    ra1  = v ? *(const uint4*)(ar1 + ak) : z4u;
    rb10 = v ? *(const uint4*)(b1r0 + ak) : z4u;
    rb11 = v ? *(const uint4*)(b1r1 + ak) : z4u;
    rb30 = v ? *(const uint4*)(b3r0 + ak) : z4u;
    rb31 = v ? *(const uint4*)(b3r1 + ak) : z4u;
  }
  for (int kc = 0; kc < K; kc += 64) {
    __syncthreads();
    *(uint4*)&As[r0 * 72 + ak] = ra0;
    *(uint4*)&As[(r0 + 32) * 72 + ak] = ra1;
    *(uint4*)&Bs1[r0 * 72 + ak] = rb10;
    *(uint4*)&Bs1[(r0 + 32) * 72 + ak] = rb11;
    *(uint4*)&Bs2[r0 * 72 + ak] = rb30;
    *(uint4*)&Bs2[(r0 + 32) * 72 + ak] = rb31;
    __syncthreads();
    int kn = kc + 64;
    if (kn < K) {
      bool v = (kn + ak < K);
      ra0  = v ? *(const uint4*)(ar0 + kn + ak) : z4u;
      ra1  = v ? *(const uint4*)(ar1 + kn + ak) : z4u;
      rb10 = v ? *(const uint4*)(b1r0 + kn + ak) : z4u;
      rb11 = v ? *(const uint4*)(b1r1 + kn + ak) : z4u;
      rb30 = v ? *(const uint4*)(b3r0 + kn + ak) : z4u;
      rb31 = v ? *(const uint4*)(b3r1 + kn + ak) : z4u;
    }
#pragma unroll
    for (int ks = 0; ks < 2; ++ks) {
      int aoff = ((wv & 1) * 32 + m16) * 72 + ks * 32 + quad * 8;
      int boff = ((wv >> 1) * 32 + m16) * 72 + ks * 32 + quad * 8;
      f16x8 a0 = *(const f16x8*)&As[aoff];
      f16x8 a1 = *(const f16x8*)&As[aoff + 16 * 72];
      f16x8 b10 = *(const f16x8*)&Bs1[boff];
      f16x8 b11 = *(const f16x8*)&Bs1[boff + 16 * 72];
      f16x8 b30 = *(const f16x8*)&Bs2[boff];
      f16x8 b31 = *(const f16x8*)&Bs2[boff + 16 * 72];
      ac1[0][0] = MFMA16(a0, b10, ac1[0][0]);
      ac1[0][1] = MFMA16(a0, b11, ac1[0][1]);
      ac1[1][0] = MFMA16(a1, b10, ac1[1][0]);
      ac1[1][1] = MFMA16(a1, b11, ac1[1][1]);
      ac2[0][0] = MFMA16(a0, b30, ac2[0][0]);
      ac2[0][1] = MFMA16(a0, b31, ac2[0][1]);
      ac2[1][0] = MFMA16(a1, b30, ac2[1][0]);
      ac2[1][1] = MFMA16(a1, b31, ac2[1][1]);
    }
  }
#pragma unroll
  for (int mi = 0; mi < 2; ++mi)
#pragma unroll
    for (int ni = 0; ni < 2; ++ni)
#pragma unroll
      for (int r = 0; r < 4; ++r) {
        int row = mt * 64 + (wv & 1) * 32 + mi * 16 + quad * 4 + r;
        int col = nt * 64 + (wv >> 1) * 32 + ni * 16 + m16;
        float h1 = ac1[mi][ni][r];
        float h3 = ac2[mi][ni][r];
        float sl = h1 / (1.0f + expf(-h1));
        tout[(size_t)row * NHID + col] = (f16)(sl * h3);
      }
}

// ---------------- GEMM2 (MoE): f16 weights, XCD-grouped remap, 2-phase ----------------
__global__ __launch_bounds__(256) void k_gemm2(
    const f16* __restrict__ tbuf, const f16* __restrict__ wf,
    const int* __restrict__ lists, const int* __restrict__ counts,
    const float* __restrict__ cmv, const float* __restrict__ amv,
    float* __restrict__ yc, float* __restrict__ ya) {
  int bid = blockIdx.x;
  int xcd = bid & 7;
  int local = bid >> 3;
  int pair = xcd * 18 + (local >> 5);
  int mt = local & 31;
  int g = pair / 18;
  int nt = pair % 18;
  int e = g & 3;
  int cnt = counts[g];
  if (mt * 64 >= cnt) return;
  const int* list = lists + g * NTOK;
  const f16* A = tbuf + (size_t)g * NTOK * NHID;
  const f16* Bw = wf + (size_t)((g < 4) ? 6 : 7) * WSZ + (size_t)e * NDIM * NHID;
  const float* sc = (g < 4) ? cmv : amv;
  float* y = (g < 4) ? yc : ya;
  int t = threadIdx.x;
  int wv = t >> 6, lane = t & 63, m16 = lane & 15, quad = lane >> 4;
  int r0 = t >> 3, ak = (t & 7) * 8;
  const f16* ar0 = A + (size_t)(mt * 64 + r0) * NHID;
  const f16* ar1 = A + (size_t)(mt * 64 + r0 + 32) * NHID;
  const f16* br0 = Bw + (size_t)(nt * 64 + r0) * NHID;
  const f16* br1 = Bw + (size_t)(nt * 64 + r0 + 32) * NHID;
  __shared__ f16 As[64 * 72];
  __shared__ f16 Bs[64 * 72];
  f32x4 zf = {0.f, 0.f, 0.f, 0.f};
  f32x4 acc[2][2] = {{zf, zf}, {zf, zf}};
  uint4 ra0, ra1, rb0, rb1;
  ra0 = *(const uint4*)(ar0 + ak);
  ra1 = *(const uint4*)(ar1 + ak);
  rb0 = *(const uint4*)(br0 + ak);
  rb1 = *(const uint4*)(br1 + ak);
  for (int kc = 0; kc < NHID; kc += 64) {
    __syncthreads();
    *(uint4*)&As[r0 * 72 + ak] = ra0;
    *(uint4*)&As[(r0 + 32) * 72 + ak] = ra1;
    *(uint4*)&Bs[r0 * 72 + ak] = rb0;
    *(uint4*)&Bs[(r0 + 32) * 72 + ak] = rb1;
    __syncthreads();
    int kn = kc + 64;
    if (kn < NHID) {
      ra0 = *(const uint4*)(ar0 + kn + ak);
      ra1 = *(const uint4*)(ar1 + kn + ak);
      rb0 = *(const uint4*)(br0 + kn + ak);
      rb1 = *(const uint4*)(br1 + kn + ak);
    }
#pragma unroll
    for (int ks = 0; ks < 2; ++ks) {
      int aoff = ((wv & 1) * 32 + m16) * 72 + ks * 32 + quad * 8;
      int boff = ((wv >> 1) * 32 + m16) * 72 + ks * 32 + quad * 8;
      f16x8 a0 = *(const f16x8*)&As[aoff];
      f16x8 a1 = *(const f16x8*)&As[aoff + 16 * 72];
      f16x8 b0 = *(const f16x8*)&Bs[boff];
      f16x8 b1 = *(const f16x8*)&Bs[boff + 16 * 72];
      acc[0][0] = MFMA16(a0, b0, acc[0][0]);
      acc[0][1] = MFMA16(a0, b1, acc[0][1]);
      acc[1][0] = MFMA16(a1, b0, acc[1][0]);
      acc[1][1] = MFMA16(a1, b1, acc[1][1]);
    }
  }
#pragma unroll
  for (int mi = 0; mi < 2; ++mi)
#pragma unroll
    for (int ni = 0; ni < 2; ++ni)
#pragma unroll
      for (int r = 0; r < 4; ++r) {
        int mg = mt * 64 + (wv & 1) * 32 + mi * 16 + quad * 4 + r;
        if (mg < cnt) {
          int tok = list[mg];
          int col = nt * 64 + (wv >> 1) * 32 + ni * 16 + m16;
          float v = acc[mi][ni][r] * sc[tok];
          y[(size_t)tok * NDIM + col] = v;
        }
      }
}

// ---------------- GEMM2 (fr): f16 weights, t16 @ fr_w2 slice -> z, 2-phase ------------
__global__ __launch_bounds__(256) void k_gemm2_fr(
    const f16* __restrict__ tbuf, const f16* __restrict__ wf, float* __restrict__ zz) {
  int e = blockIdx.z;
  int mt = blockIdx.y, nt = blockIdx.x;
  const f16* A = tbuf + (size_t)e * NTOK * NHID;
  const f16* Bw = wf + (size_t)8 * WSZ + (size_t)e * NDIM * NHID;
  int t = threadIdx.x;
  int wv = t >> 6, lane = t & 63, m16 = lane & 15, quad = lane >> 4;
  int r0 = t >> 3, ak = (t & 7) * 8;
  const f16* ar0 = A + (size_t)(mt * 64 + r0) * NHID;
  const f16* ar1 = A + (size_t)(mt * 64 + r0 + 32) * NHID;
  int ne0 = min(nt * 64 + r0, 287), ne1 = min(nt * 64 + r0 + 32, 287);
  const f16* br0 = Bw + (size_t)(e * 288 + ne0) * NHID;
  const f16* br1 = Bw + (size_t)(e * 288 + ne1) * NHID;
  __shared__ f16 As[64 * 72];
  __shared__ f16 Bs[64 * 72];
  f32x4 zf = {0.f, 0.f, 0.f, 0.f};
  f32x4 acc[2][2] = {{zf, zf}, {zf, zf}};
  uint4 ra0, ra1, rb0, rb1;
  ra0 = *(const uint4*)(ar0 + ak);
  ra1 = *(const uint4*)(ar1 + ak);
  rb0 = *(const uint4*)(br0 + ak);
  rb1 = *(const uint4*)(br1 + ak);
  for (int kc = 0; kc < NHID; kc += 64) {
    __syncthreads();
    *(uint4*)&As[r0 * 72 + ak] = ra0;
    *(uint4*)&As[(r0 + 32) * 72 + ak] = ra1;
    *(uint4*)&Bs[r0 * 72 + ak] = rb0;
    *(uint4*)&Bs[(r0 + 32) * 72 + ak] = rb1;
    __syncthreads();
    int kn = kc + 64;
    if (kn < NHID) {
      ra0 = *(const uint4*)(ar0 + kn + ak);
      ra1 = *(const uint4*)(ar1 + kn + ak);
      rb0 = *(const uint4*)(br0 + kn + ak);
      rb1 = *(const uint4*)(br1 + kn + ak);
    }
#pragma unroll
    for (int ks = 0; ks < 2; ++ks) {
      int aoff = ((wv & 1) * 32 + m16) * 72 + ks * 32 + quad * 8;
      int boff = ((wv >> 1) * 32 + m16) * 72 + ks * 32 + quad * 8;
      f16x8 a0 = *(const f16x8*)&As[aoff];
      f16x8 a1 = *(const f16x8*)&As[aoff + 16 * 72];
      f16x8 b0 = *(const f16x8*)&Bs[boff];
      f16x8 b1 = *(const f16x8*)&Bs[boff + 16 * 72];
      acc[0][0] = MFMA16(a0, b0, acc[0][0]);
      acc[0][1] = MFMA16(a0, b1, acc[0][1]);
      acc[1][0] = MFMA16(a1, b0, acc[1][0]);
      acc[1][1] = MFMA16(a1, b1, acc[1][1]);
    }
  }
#pragma unroll
  for (int mi = 0; mi < 2; ++mi)
#pragma unroll
    for (int ni = 0; ni < 2; ++ni)
#pragma unroll
      for (int r = 0; r < 4; ++r) {
        int cg = nt * 64 + (wv >> 1) * 32 + ni * 16 + m16;
        if (cg < 288) {
          int row = mt * 64 + (wv & 1) * 32 + mi * 16 + quad * 4 + r;
          zz[(size_t)row * NDIM + e * 288 + cg] = acc[mi][ni][r];
        }
      }
}

// ---------------- host ----------------
extern "C" void kernel_launch(void* const* d_in, const int* in_sizes, int n_in,
                              void* d_out, int out_size, void* d_ws, size_t ws_size,
                              hipStream_t stream) {
  const float* x          = (const float*)d_in[0];
  const float* timep      = (const float*)d_in[1];
  const float* caption    = (const float*)d_in[2];
  const float* acoustic   = (const float*)d_in[3];
  const float* attn_in_w  = (const float*)d_in[4];
  const float* attn_in_b  = (const float*)d_in[5];
  const float* attn_out_w = (const float*)d_in[6];
  const float* attn_out_b = (const float*)d_in[7];
  const float* hl_w       = (const float*)d_in[8];
  const float* hl_b       = (const float*)d_in[9];
  const float* cap_gate_w = (const float*)d_in[10];
  const float* cap_gate_b = (const float*)d_in[11];
  const float* ac_gate_w  = (const float*)d_in[12];
  const float* ac_gate_b  = (const float*)d_in[13];
  const float* cap_w1     = (const float*)d_in[14];
  const float* cap_w2     = (const float*)d_in[15];
  const float* cap_w3     = (const float*)d_in[16];
  const float* ac_w1      = (const float*)d_in[17];
  const float* ac_w2      = (const float*)d_in[18];
  const float* ac_w3      = (const float*)d_in[19];
  const float* fr_w1      = (const float*)d_in[20];
  const float* fr_w2      = (const float*)d_in[21];
  const float* fr_w3      = (const float*)d_in[22];
  (void)in_sizes; (void)n_in; (void)out_size; (void)ws_size;

  float* zout = (float*)d_out;
  float* loss = zout + (size_t)NTOK * NDIM;

  char* wsb = (char*)d_ws;
  size_t off = 0;
  auto alloc = [&](size_t bytes) -> void* {
    void* p = wsb + off;
    off = (off + bytes + 255) & ~(size_t)255;
    return p;
  };
  // persistent small + xhi + converted weights
  float* g1     = (float*)alloc(4096 * 4);
  float* g2     = (float*)alloc(8192 * 4);
  float* g3     = (float*)alloc(8192 * 4);
  float* tl     = (float*)alloc(4 * 4);
  float* al     = (float*)alloc((size_t)NTOK * NEXP * 4);
  float* cl     = (float*)alloc((size_t)NTOK * NEXP * 4);
  float* cmv    = (float*)alloc((size_t)NTOK * 4);
  float* amv    = (float*)alloc((size_t)NTOK * 4);
  int*   lists  = (int*)alloc((size_t)8 * NTOK * 4);
  int*   counts = (int*)alloc(8 * 4);
  float* wp     = (float*)alloc((size_t)NEXP * NDIM * 4);
  float* bp     = (float*)alloc(NEXP * 4);
  float* wpp    = (float*)alloc((size_t)18 * NEXP * NDIM * 4);
  f16*   xhi    = (f16*)alloc((size_t)NTOK * NDIM * 2);
  f16*   wf16   = (f16*)alloc((size_t)9 * WSZ * 2);
  size_t region = off;
  // phase 1 (attention / routing inputs)
  f16*   xlo    = (f16*)alloc((size_t)NTOK * NDIM * 2);
  f16*   caphi  = (f16*)alloc((size_t)NCAP * NDIM * 2);
  f16*   caplo  = (f16*)alloc((size_t)NCAP * NDIM * 2);
  f16*   qhi    = (f16*)alloc((size_t)NTOK * NDIM * 2);
  f16*   qlo    = (f16*)alloc((size_t)NTOK * NDIM * 2);
  f16*   khi    = (f16*)alloc((size_t)NCAP * NDIM * 2);
  f16*   klo    = (f16*)alloc((size_t)NCAP * NDIM * 2);
  f16*   vthi   = (f16*)alloc((size_t)NB * NDIM * NSC * 2);
  f16*   vtlo   = (f16*)alloc((size_t)NB * NDIM * NSC * 2);
  f16*   ohi    = (f16*)alloc((size_t)NTOK * NDIM * 2);
  f16*   olo    = (f16*)alloc((size_t)NTOK * NDIM * 2);
  // phase 2 (MoE / fr) — reuses phase-1 region (all phase-1 buffers dead)
  off = region;
  f16*   tbuf   = (f16*)alloc((size_t)8 * NTOK * NHID * 2);
  float* ybc    = (float*)alloc((size_t)NTOK * NDIM * 4);
  float* yba    = (float*)alloc((size_t)NTOK * NDIM * 4);
  f16*   y16    = (f16*)alloc((size_t)NTOK * NDIM * 2);

  k_prep<<<dim3(1), dim3(256), 0, stream>>>(timep, hl_w, hl_b, g1, g2, g3, tl);
  k_fuse_gate1<<<dim3(90), dim3(256), 0, stream>>>(attn_out_w, cap_gate_w, wpp);
  k_fuse_gate2<<<dim3(19), dim3(256), 0, stream>>>(wpp, cap_gate_w, attn_out_b,
                                                   cap_gate_b, wp, bp);
  k_ac_logits<<<dim3(512), dim3(256), 0, stream>>>(acoustic, ac_gate_w, ac_gate_b, al);
  k_cvt_split<<<dim3(2304), dim3(256), 0, stream>>>(x, xhi, xlo, NTOK * NDIM);
  k_cvt_split<<<dim3(288), dim3(256), 0, stream>>>(caption, caphi, caplo, NCAP * NDIM);
  // fused: QKV projection (z<3) + grid-stride cvt of slots 0-3 (z=3,4)
  k_gemm_qkv<<<dim3(18, 32, 5), dim3(256), 0, stream>>>(
      xhi, xlo, caphi, caplo, attn_in_w, attn_in_b,
      qhi, qlo, khi, klo, vthi, vtlo,
      cap_w1, cap_w3, ac_w1, ac_w3, wf16);
  k_attn<<<dim3(16, 16), dim3(256), 0, stream>>>(qhi, qlo, khi, klo, vthi, vtlo, ohi, olo);
  // cap-gate logits directly from o via fused W' (k_ca eliminated)
  k_o_logits<<<dim3(512), dim3(256), 0, stream>>>(ohi, olo, wp, bp, cl);
  k_route<<<dim3(1), dim3(1024), 0, stream>>>(cl, al, g1, g2, g3, tl,
                                              cmv, amv, lists, counts, loss);
  // gemm1 pass-1 (8 groups) + tail cvt blocks for slots 4-8 (3072 + 1080)
  k_gemm1<<<dim3(4152), dim3(256), 0, stream>>>(xhi, y16, wf16, lists, counts, tbuf,
                                                fr_w1, fr_w3, cap_w2, ac_w2, fr_w2, 0, 8);
  k_gemm2<<<dim3(4608), dim3(256), 0, stream>>>(tbuf, wf16, lists, counts,
                                                cmv, amv, ybc, yba);
  k_cvt_add<<<dim3(2304), dim3(256), 0, stream>>>(ybc, yba, y16, NTOK * NDIM);
  k_gemm1<<<dim3(1536), dim3(256), 0, stream>>>(xhi, y16, wf16, lists, counts, tbuf,
                                                fr_w1, fr_w3, cap_w2, ac_w2, fr_w2, 8, 4);
  k_gemm2_fr<<<dim3(5, 32, 4), dim3(256), 0, stream>>>(tbuf, wf16, zout);
}

// Round 8
// 441.363 us; speedup vs baseline: 1.3187x; 1.0150x over previous
//
#include <hip/hip_runtime.h>
#include <stdint.h>

#define NDIM 1152
#define NEXP 4
#define NHID 768
#define NHEAD 8
#define HDIM 144
#define NB 2
#define NS 1024
#define NSC 128
#define NTOK 2048
#define NCAP 256

typedef _Float16 f16;
typedef _Float16 f16x4 __attribute__((ext_vector_type(4)));
typedef _Float16 f16x8 __attribute__((ext_vector_type(8)));
typedef float f32x4 __attribute__((ext_vector_type(4)));

#define MFMA16(a, b, c) __builtin_amdgcn_mfma_f32_16x16x32_f16(a, b, c, 0, 0, 0)

#define WSZ ((size_t)NEXP * NHID * NDIM)  // elems per full weight tensor (3,538,944)
#define WQ  ((size_t)(WSZ / 4))           // compact fr tensor elems (884,736)
#define OFF_CW2 ((size_t)4 * WSZ)
#define OFF_AW2 ((size_t)5 * WSZ)
#define OFF_FR1 ((size_t)6 * WSZ)
#define OFF_FR3 ((size_t)6 * WSZ + WQ)
#define OFF_FR2 ((size_t)6 * WSZ + 2 * WQ)

// ---------------- Threefry2x32 (exact JAX replication) ----------------
__device__ inline uint2 tfry(uint32_t k0, uint32_t k1, uint32_t x0, uint32_t x1) {
  uint32_t k2 = k0 ^ k1 ^ 0x1BD11BDAu;
#define RND(r) { x0 += x1; x1 = (x1 << r) | (x1 >> (32 - r)); x1 ^= x0; }
  x0 += k0; x1 += k1;
  RND(13) RND(15) RND(26) RND(6)
  x0 += k1; x1 += k2 + 1u;
  RND(17) RND(29) RND(16) RND(24)
  x0 += k2; x1 += k0 + 2u;
  RND(13) RND(15) RND(26) RND(6)
  x0 += k0; x1 += k1 + 3u;
  RND(17) RND(29) RND(16) RND(24)
  x0 += k1; x1 += k2 + 4u;
  RND(13) RND(15) RND(26) RND(6)
  x0 += k2; x1 += k0 + 5u;
#undef RND
  return make_uint2(x0, x1);
}

__device__ inline float b2g(uint32_t bits) {
  uint32_t fb = (bits >> 9) | 0x3f800000u;
  float f = __uint_as_float(fb) - 1.0f;
  const float tiny = 1.1754943508222875e-38f;
  float u = f * 1.0f + tiny;
  u = fmaxf(tiny, u);
  return -logf(-logf(u));
}

// ---------------- prep: keys, gumbels, time-logits ----------------
__global__ void k_prep(const float* __restrict__ timep, const float* __restrict__ hlw,
                       const float* __restrict__ hlb,
                       float* __restrict__ g1, float* __restrict__ g2, float* __restrict__ g3,
                       float* __restrict__ tl) {
  int t = threadIdx.x;  // 256
  uint2 k1 = tfry(0u, 42u, 0u, 0u);
  uint2 k2 = tfry(0u, 42u, 0u, 1u);
  uint2 k3 = tfry(0u, 42u, 0u, 2u);
  for (int p = t; p < 4096; p += 256) {
    uint2 o = tfry(k1.x, k1.y, 0u, (uint32_t)p);
    g1[p] = b2g(o.x ^ o.y);
  }
  for (int p = t; p < 8192; p += 256) {
    uint2 o2 = tfry(k2.x, k2.y, 0u, (uint32_t)p);
    g2[p] = b2g(o2.x ^ o2.y);
    uint2 o3 = tfry(k3.x, k3.y, 0u, (uint32_t)p);
    g3[p] = b2g(o3.x ^ o3.y);
  }
  int wv = t >> 6, lane = t & 63;
  {
    int b = wv >> 1, j = wv & 1;
    float s = 0.f;
    for (int k = lane; k < NDIM; k += 64) s += timep[b * NDIM + k] * hlw[j * NDIM + k];
    for (int m = 32; m; m >>= 1) s += __shfl_xor(s, m);
    if (lane == 0) tl[b * 2 + j] = s + hlb[j];
  }
}

// ---------------- fused gate stage 1: partials wpp[dc][e][k] over 64-d chunks ---------
__global__ void k_fuse_gate1(const float* __restrict__ ow, const float* __restrict__ gw,
                             float* __restrict__ wpp) {
  int kt = blockIdx.x % 5;
  int dc = blockIdx.x / 5;
  int k = kt * 256 + threadIdx.x;
  if (k >= NDIM) return;
  float a0 = 0.f, a1 = 0.f, a2 = 0.f, a3 = 0.f;
#pragma unroll 8
  for (int j = 0; j < 64; ++j) {
    int d = dc * 64 + j;
    float o = ow[(size_t)d * NDIM + k];
    a0 += gw[d] * o;
    a1 += gw[NDIM + d] * o;
    a2 += gw[2 * NDIM + d] * o;
    a3 += gw[3 * NDIM + d] * o;
  }
  float* p = wpp + (size_t)dc * 4 * NDIM;
  p[k] = a0; p[NDIM + k] = a1; p[2 * NDIM + k] = a2; p[3 * NDIM + k] = a3;
}

// ---------------- fused gate stage 2: deterministic 18-way reduce + bias --------------
__global__ void k_fuse_gate2(const float* __restrict__ wpp,
                             const float* __restrict__ gw, const float* __restrict__ ob,
                             const float* __restrict__ gb,
                             float* __restrict__ wp, float* __restrict__ bp) {
  if (blockIdx.x == 18) {
    int wv = threadIdx.x >> 6, lane = threadIdx.x & 63;  // wv = e
    float s = 0.f;
    for (int d = lane; d < NDIM; d += 64) s += ob[d] * gw[wv * NDIM + d];
    for (int m = 32; m; m >>= 1) s += __shfl_xor(s, m);
    if (lane == 0) bp[wv] = s + gb[wv];
    return;
  }
  int i = blockIdx.x * 256 + threadIdx.x;  // 0 .. 4607
  float s = 0.f;
#pragma unroll
  for (int c = 0; c < 18; ++c) s += wpp[(size_t)c * 4 * NDIM + i];
  wp[i] = s;
}

// ---------------- generic 4-logit head: out[n,e] = in[n,:]·w[e,:] + b[e] ----------------
__global__ void k_ac_logits(const float* __restrict__ ac, const float* __restrict__ agw,
                            const float* __restrict__ agb, float* __restrict__ al) {
  int wv = threadIdx.x >> 6, lane = threadIdx.x & 63;
  int n = blockIdx.x * 4 + wv;
  float s[NEXP] = {0.f, 0.f, 0.f, 0.f};
  for (int d = lane; d < NDIM; d += 64) {
    float a = ac[(size_t)n * NDIM + d];
#pragma unroll
    for (int e = 0; e < NEXP; ++e) s[e] += a * agw[e * NDIM + d];
  }
#pragma unroll
  for (int e = 0; e < NEXP; ++e)
    for (int m = 32; m; m >>= 1) s[e] += __shfl_xor(s[e], m);
  if (lane == 0) {
#pragma unroll
    for (int e = 0; e < NEXP; ++e) al[n * NEXP + e] = s[e] + agb[e];
  }
}

// ---------------- cap logits from split-f16 o: cl[n,e] = o[n,:]·W'[e,:] + b'[e] -------
__global__ void k_o_logits(const f16* __restrict__ ohi, const f16* __restrict__ olo,
                           const float* __restrict__ wp, const float* __restrict__ bp,
                           float* __restrict__ cl) {
  int wv = threadIdx.x >> 6, lane = threadIdx.x & 63;
  int n = blockIdx.x * 4 + wv;
  float s[NEXP] = {0.f, 0.f, 0.f, 0.f};
  for (int d = lane; d < NDIM; d += 64) {
    size_t gi = (size_t)n * NDIM + d;
    float a = (float)ohi[gi] + (float)olo[gi] * (1.f / 2048.f);
#pragma unroll
    for (int e = 0; e < NEXP; ++e) s[e] += a * wp[e * NDIM + d];
  }
#pragma unroll
  for (int e = 0; e < NEXP; ++e)
    for (int m = 32; m; m >>= 1) s[e] += __shfl_xor(s[e], m);
  if (lane == 0) {
#pragma unroll
    for (int e = 0; e < NEXP; ++e) cl[n * NEXP + e] = s[e] + bp[e];
  }
}

// ---------------- fp32 -> fp16 hi/lo split convert (lo pre-scaled by 2048) ----------------
__global__ void k_cvt_split(const float* __restrict__ src, f16* __restrict__ hi,
                            f16* __restrict__ lo, int n) {
  int i = (blockIdx.x * 256 + threadIdx.x) * 4;
  if (i + 3 < n) {
    float4 v = *(const float4*)(src + i);
    f16x4 h, l;
    h[0] = (f16)v.x; l[0] = (f16)((v.x - (float)h[0]) * 2048.f);
    h[1] = (f16)v.y; l[1] = (f16)((v.y - (float)h[1]) * 2048.f);
    h[2] = (f16)v.z; l[2] = (f16)((v.z - (float)h[2]) * 2048.f);
    h[3] = (f16)v.w; l[3] = (f16)((v.w - (float)h[3]) * 2048.f);
    *(f16x4*)(hi + i) = h;
    *(f16x4*)(lo + i) = l;
  }
}

// ---------------- QKV projection + fused weight cvt (slots 0-3) ----------------
// z<3: split-fp16 QKV GEMM (2-phase prefetch). z==2 (V) emits transposed split-fp16.
// z in {3,4}: grid-stride f32->f16 conversion of cap_w1/cap_w3/ac_w1/ac_w3.
__global__ __launch_bounds__(256) void k_gemm_qkv(
    const f16* __restrict__ xhi, const f16* __restrict__ xlo,
    const f16* __restrict__ caphi, const f16* __restrict__ caplo,
    const float* __restrict__ inw, const float* __restrict__ inb,
    f16* __restrict__ qhi, f16* __restrict__ qlo,
    f16* __restrict__ khi, f16* __restrict__ klo,
    f16* __restrict__ vthi, f16* __restrict__ vtlo,
    const float* __restrict__ w0, const float* __restrict__ w1,
    const float* __restrict__ w2, const float* __restrict__ w3,
    f16* __restrict__ wf16) {
  int z = blockIdx.z;
  if (z >= 3) {
    // 4*WSZ elems over 1152 blocks -> 12288 elems/block (6 iters x 2048)
    int cvtid = (z - 3) * 576 + blockIdx.y * 18 + blockIdx.x;
    size_t c0 = (size_t)cvtid * 12288;
    int slot = (int)(c0 / WSZ);               // block-uniform (12288 | WSZ)
    size_t base = c0 % WSZ;
    const float* s = ((slot == 0) ? w0 : (slot == 1) ? w1 : (slot == 2) ? w2 : w3) + base;
    f16* dst = wf16 + (size_t)slot * WSZ + base;
#pragma unroll
    for (int i = 0; i < 6; ++i) {
      size_t off = (size_t)(threadIdx.x + i * 256) * 8;
      float4 v0 = *(const float4*)(s + off);
      float4 v1 = *(const float4*)(s + off + 4);
      f16x8 h;
      h[0] = (f16)v0.x; h[1] = (f16)v0.y; h[2] = (f16)v0.z; h[3] = (f16)v0.w;
      h[4] = (f16)v1.x; h[5] = (f16)v1.y; h[6] = (f16)v1.z; h[7] = (f16)v1.w;
      *(f16x8*)(dst + off) = h;
    }
    return;
  }
  int M = (z == 0) ? NTOK : NCAP;
  int mt = blockIdx.y, nt = blockIdx.x;
  if (mt * 64 >= M) return;
  const f16* Ah_g = (z == 0) ? xhi : caphi;
  const f16* Al_g = (z == 0) ? xlo : caplo;
  __shared__ f16 Ash[64 * 72];
  __shared__ f16 Asl[64 * 72];
  __shared__ f16 Bsh[64 * 72];
  __shared__ f16 Bsl[64 * 72];
  int t = threadIdx.x;
  int wv = t >> 6, lane = t & 63, m16 = lane & 15, quad = lane >> 4;
  int r0 = t >> 3, ak = (t & 7) * 8;
  size_t a0o = (size_t)(mt * 64 + r0) * NDIM;
  size_t a1o = (size_t)(mt * 64 + r0 + 32) * NDIM;
  f32x4 zf = {0.f, 0.f, 0.f, 0.f};
  f32x4 ah[2][2] = {{zf, zf}, {zf, zf}};
  f32x4 am[2][2] = {{zf, zf}, {zf, zf}};
  uint4 rah0, rah1, ral0, ral1;
  float4 rbw[4];
  rah0 = *(const uint4*)(Ah_g + a0o + ak);
  rah1 = *(const uint4*)(Ah_g + a1o + ak);
  ral0 = *(const uint4*)(Al_g + a0o + ak);
  ral1 = *(const uint4*)(Al_g + a1o + ak);
#pragma unroll
  for (int uu = 0; uu < 4; ++uu) {
    int u = t + uu * 256;
    int rr = u >> 4, kp = (u & 15) * 4;
    rbw[uu] = *(const float4*)(inw + (size_t)(z * NDIM + nt * 64 + rr) * NDIM + kp);
  }
  for (int kc = 0; kc < NDIM; kc += 64) {
    __syncthreads();
    *(uint4*)&Ash[r0 * 72 + ak] = rah0;
    *(uint4*)&Ash[(r0 + 32) * 72 + ak] = rah1;
    *(uint4*)&Asl[r0 * 72 + ak] = ral0;
    *(uint4*)&Asl[(r0 + 32) * 72 + ak] = ral1;
#pragma unroll
    for (int uu = 0; uu < 4; ++uu) {
      int u = t + uu * 256;
      int rr = u >> 4, kp = (u & 15) * 4;
      f16x4 hb, lb;
      hb[0] = (f16)rbw[uu].x; lb[0] = (f16)((rbw[uu].x - (float)hb[0]) * 2048.f);
      hb[1] = (f16)rbw[uu].y; lb[1] = (f16)((rbw[uu].y - (float)hb[1]) * 2048.f);
      hb[2] = (f16)rbw[uu].z; lb[2] = (f16)((rbw[uu].z - (float)hb[2]) * 2048.f);
      hb[3] = (f16)rbw[uu].w; lb[3] = (f16)((rbw[uu].w - (float)hb[3]) * 2048.f);
      *(f16x4*)&Bsh[rr * 72 + kp] = hb;
      *(f16x4*)&Bsl[rr * 72 + kp] = lb;
    }
    __syncthreads();
    int kn = kc + 64;
    if (kn < NDIM) {
      rah0 = *(const uint4*)(Ah_g + a0o + kn + ak);
      rah1 = *(const uint4*)(Ah_g + a1o + kn + ak);
      ral0 = *(const uint4*)(Al_g + a0o + kn + ak);
      ral1 = *(const uint4*)(Al_g + a1o + kn + ak);
#pragma unroll
      for (int uu = 0; uu < 4; ++uu) {
        int u = t + uu * 256;
        int rr = u >> 4, kp = (u & 15) * 4;
        rbw[uu] = *(const float4*)(inw + (size_t)(z * NDIM + nt * 64 + rr) * NDIM + kn + kp);
      }
    }
#pragma unroll
    for (int ks = 0; ks < 2; ++ks) {
      int aoff = ((wv & 1) * 32 + m16) * 72 + ks * 32 + quad * 8;
      int boff = ((wv >> 1) * 32 + m16) * 72 + ks * 32 + quad * 8;
      f16x8 a0h = *(const f16x8*)&Ash[aoff];
      f16x8 a1h = *(const f16x8*)&Ash[aoff + 16 * 72];
      f16x8 a0l = *(const f16x8*)&Asl[aoff];
      f16x8 a1l = *(const f16x8*)&Asl[aoff + 16 * 72];
      f16x8 b0h = *(const f16x8*)&Bsh[boff];
      f16x8 b1h = *(const f16x8*)&Bsh[boff + 16 * 72];
      f16x8 b0l = *(const f16x8*)&Bsl[boff];
      f16x8 b1l = *(const f16x8*)&Bsl[boff + 16 * 72];
      ah[0][0] = MFMA16(a0h, b0h, ah[0][0]);
      ah[0][1] = MFMA16(a0h, b1h, ah[0][1]);
      ah[1][0] = MFMA16(a1h, b0h, ah[1][0]);
      ah[1][1] = MFMA16(a1h, b1h, ah[1][1]);
      am[0][0] = MFMA16(a0h, b0l, am[0][0]);
      am[0][1] = MFMA16(a0h, b1l, am[0][1]);
      am[1][0] = MFMA16(a1h, b0l, am[1][0]);
      am[1][1] = MFMA16(a1h, b1l, am[1][1]);
      am[0][0] = MFMA16(a0l, b0h, am[0][0]);
      am[0][1] = MFMA16(a0l, b1h, am[0][1]);
      am[1][0] = MFMA16(a1l, b0h, am[1][0]);
      am[1][1] = MFMA16(a1l, b1h, am[1][1]);
    }
  }
#pragma unroll
  for (int mi = 0; mi < 2; ++mi)
#pragma unroll
    for (int ni = 0; ni < 2; ++ni)
#pragma unroll
      for (int r = 0; r < 4; ++r) {
        int row = mt * 64 + (wv & 1) * 32 + mi * 16 + quad * 4 + r;
        int col = nt * 64 + (wv >> 1) * 32 + ni * 16 + m16;
        float v = ah[mi][ni][r] + am[mi][ni][r] * (1.f / 2048.f) + inb[z * NDIM + col];
        size_t idx = (size_t)row * NDIM + col;
        if (z == 0) {
          f16 hq = (f16)v;
          qhi[idx] = hq;
          qlo[idx] = (f16)((v - (float)hq) * 2048.f);
        } else if (z == 1) {
          f16 hk = (f16)v;
          khi[idx] = hk;
          klo[idx] = (f16)((v - (float)hk) * 2048.f);
        } else {
          f16 hv = (f16)v;
          int bb = row >> 7, kv = row & 127;
          size_t ti = (size_t)(bb * NDIM + col) * NSC + kv;
          vthi[ti] = hv;
          vtlo[ti] = (f16)((v - (float)hv) * 2048.f);
        }
      }
}

// ---------------- fused attention: QK^T + softmax + PV, split-fp16, writes o hi/lo ----
__global__ __launch_bounds__(256) void k_attn(
    const f16* __restrict__ qhi, const f16* __restrict__ qlo,
    const f16* __restrict__ khi, const f16* __restrict__ klo,
    const f16* __restrict__ vthi, const f16* __restrict__ vtlo,
    f16* __restrict__ ohi, f16* __restrict__ olo) {
  int mt = blockIdx.x, bh = blockIdx.y;
  int b = bh >> 3, h = bh & 7;
  __shared__ f16 Ah[64 * 160];
  __shared__ f16 Al[64 * 160];
  __shared__ f16 Bh[32 * 160];
  __shared__ f16 Bl[32 * 160];
  __shared__ f16 Ph[64 * 136];
  __shared__ f16 Pl[64 * 136];
  int t = threadIdx.x;
  int wv = t >> 6, lane = t & 63, m16 = lane & 15, quad = lane >> 4;
  for (int u = t; u < 64 * 20; u += 256) {
    int r = u / 20, kp = (u % 20) * 8;
    uint4 vh = make_uint4(0u, 0u, 0u, 0u), vl = vh;
    if (kp < HDIM) {
      size_t gi = (size_t)(b * NS + mt * 64 + r) * NDIM + h * HDIM + kp;
      vh = *(const uint4*)&qhi[gi];
      vl = *(const uint4*)&qlo[gi];
    }
    *(uint4*)&Ah[r * 160 + kp] = vh;
    *(uint4*)&Al[r * 160 + kp] = vl;
  }
  __syncthreads();
  f16x8 ahf[5], alf[5];
#pragma unroll
  for (int ks = 0; ks < 5; ++ks) {
    int ao = (wv * 16 + m16) * 160 + ks * 32 + quad * 8;
    ahf[ks] = *(const f16x8*)&Ah[ao];
    alf[ks] = *(const f16x8*)&Al[ao];
  }
  f32x4 zf = {0.f, 0.f, 0.f, 0.f};
  f32x4 sh_[4][2], sm_[4][2];
#pragma unroll
  for (int kt = 0; kt < 4; ++kt)
#pragma unroll
    for (int ni = 0; ni < 2; ++ni) { sh_[kt][ni] = zf; sm_[kt][ni] = zf; }
  for (int kt = 0; kt < 4; ++kt) {
    if (kt) __syncthreads();
    for (int u = t; u < 32 * 20; u += 256) {
      int r = u / 20, kp = (u % 20) * 8;
      uint4 vh = make_uint4(0u, 0u, 0u, 0u), vl = vh;
      if (kp < HDIM) {
        size_t gi = (size_t)(b * NSC + kt * 32 + r) * NDIM + h * HDIM + kp;
        vh = *(const uint4*)&khi[gi];
        vl = *(const uint4*)&klo[gi];
      }
      *(uint4*)&Bh[r * 160 + kp] = vh;
      *(uint4*)&Bl[r * 160 + kp] = vl;
    }
    __syncthreads();
#pragma unroll
    for (int ks = 0; ks < 5; ++ks) {
#pragma unroll
      for (int ni = 0; ni < 2; ++ni) {
        int bo = (ni * 16 + m16) * 160 + ks * 32 + quad * 8;
        f16x8 bhf = *(const f16x8*)&Bh[bo];
        f16x8 blf = *(const f16x8*)&Bl[bo];
        sh_[kt][ni] = MFMA16(ahf[ks], bhf, sh_[kt][ni]);
        sm_[kt][ni] = MFMA16(ahf[ks], blf, sm_[kt][ni]);
        sm_[kt][ni] = MFMA16(alf[ks], bhf, sm_[kt][ni]);
      }
    }
  }
  float sv[4][2][4];
  float mx[4] = {-1e30f, -1e30f, -1e30f, -1e30f};
#pragma unroll
  for (int kt = 0; kt < 4; ++kt)
#pragma unroll
    for (int ni = 0; ni < 2; ++ni)
#pragma unroll
      for (int r = 0; r < 4; ++r) {
        float s = (sh_[kt][ni][r] + sm_[kt][ni][r] * (1.f / 2048.f)) * (1.f / 12.f);
        sv[kt][ni][r] = s;
        mx[r] = fmaxf(mx[r], s);
      }
#pragma unroll
  for (int r = 0; r < 4; ++r) {
    mx[r] = fmaxf(mx[r], __shfl_xor(mx[r], 1));
    mx[r] = fmaxf(mx[r], __shfl_xor(mx[r], 2));
    mx[r] = fmaxf(mx[r], __shfl_xor(mx[r], 4));
    mx[r] = fmaxf(mx[r], __shfl_xor(mx[r], 8));
  }
  float sum[4] = {0.f, 0.f, 0.f, 0.f};
#pragma unroll
  for (int kt = 0; kt < 4; ++kt)
#pragma unroll
    for (int ni = 0; ni < 2; ++ni)
#pragma unroll
      for (int r = 0; r < 4; ++r) {
        float e = expf(sv[kt][ni][r] - mx[r]);
        sv[kt][ni][r] = e;
        sum[r] += e;
      }
  float inv[4];
#pragma unroll
  for (int r = 0; r < 4; ++r) {
    sum[r] += __shfl_xor(sum[r], 1);
    sum[r] += __shfl_xor(sum[r], 2);
    sum[r] += __shfl_xor(sum[r], 4);
    sum[r] += __shfl_xor(sum[r], 8);
    inv[r] = 1.0f / sum[r];
  }
#pragma unroll
  for (int kt = 0; kt < 4; ++kt)
#pragma unroll
    for (int ni = 0; ni < 2; ++ni)
#pragma unroll
      for (int r = 0; r < 4; ++r) {
        float p = sv[kt][ni][r] * inv[r];
        int row = wv * 16 + quad * 4 + r;
        int col = kt * 32 + ni * 16 + m16;
        f16 ph = (f16)p;
        Ph[row * 136 + col] = ph;
        Pl[row * 136 + col] = (f16)((p - (float)ph) * 2048.f);
      }
  const f16* vbh = vthi + (size_t)(b * NDIM + h * HDIM) * NSC;
  const f16* vbl = vtlo + (size_t)(b * NDIM + h * HDIM) * NSC;
  f32x4 oh_[9], om_[9];
#pragma unroll
  for (int nb = 0; nb < 9; ++nb) { oh_[nb] = zf; om_[nb] = zf; }
#pragma unroll
  for (int ks = 0; ks < 4; ++ks) {
    int po = (wv * 16 + m16) * 136 + ks * 32 + quad * 8;
    f16x8 pah = *(const f16x8*)&Ph[po];
    f16x8 pal = *(const f16x8*)&Pl[po];
#pragma unroll
    for (int nb = 0; nb < 9; ++nb) {
      size_t vo = (size_t)(nb * 16 + m16) * NSC + ks * 32 + quad * 8;
      f16x8 bvh = *(const f16x8*)&vbh[vo];
      f16x8 bvl = *(const f16x8*)&vbl[vo];
      oh_[nb] = MFMA16(pah, bvh, oh_[nb]);
      om_[nb] = MFMA16(pah, bvl, om_[nb]);
      om_[nb] = MFMA16(pal, bvh, om_[nb]);
    }
  }
#pragma unroll
  for (int nb = 0; nb < 9; ++nb)
#pragma unroll
    for (int r = 0; r < 4; ++r) {
      int row = mt * 64 + wv * 16 + quad * 4 + r;
      int col = h * HDIM + nb * 16 + m16;
      float v = oh_[nb][r] + om_[nb][r] * (1.f / 2048.f);
      size_t idx = (size_t)(b * NS + row) * NDIM + col;
      f16 hv = (f16)v;
      ohi[idx] = hv;
      olo[idx] = (f16)((v - (float)hv) * 2048.f);
    }
}

// ---------------- routing: argmax gates, cm/am, lists, loss ----------------
__global__ __launch_bounds__(1024) void k_route(
    const float* __restrict__ cl, const float* __restrict__ al,
    const float* __restrict__ g1, const float* __restrict__ g2,
    const float* __restrict__ g3, const float* __restrict__ tl,
    float* __restrict__ cmv, float* __restrict__ amv,
    int* __restrict__ lists, int* __restrict__ counts, float* __restrict__ out_loss) {
  __shared__ int lcnt[8];
  __shared__ float bins[8];
  __shared__ float ssum[2];
  int t = threadIdx.x;
  if (t < 8) { lcnt[t] = 0; bins[t] = 0.f; }
  if (t < 2) ssum[t] = 0.f;
  __syncthreads();
  for (int n = t; n < NTOK; n += 1024) {
    float lc[NEXP];
#pragma unroll
    for (int e = 0; e < NEXP; ++e) lc[e] = cl[n * NEXP + e] + g2[n * 4 + e];
    int ec = 0; float bv = lc[0];
#pragma unroll
    for (int e = 1; e < NEXP; ++e) if (lc[e] > bv) { bv = lc[e]; ec = e; }
    float la[NEXP];
#pragma unroll
    for (int e = 0; e < NEXP; ++e) la[e] = al[n * NEXP + e] + g3[n * 4 + e];
    int ea = 0; float bva = la[0];
#pragma unroll
    for (int e = 1; e < NEXP; ++e) if (la[e] > bva) { bva = la[e]; ea = e; }
    int b = n >> 10;
    float a0 = tl[b * 2 + 0] + g1[n * 2 + 0];
    float a1 = tl[b * 2 + 1] + g1[n * 2 + 1];
    float mx = fmaxf(a0, a1);
    float e0 = expf(a0 - mx), e1 = expf(a1 - mx);
    float cm = e0 / (e0 + e1), am = e1 / (e0 + e1);
    cmv[n] = cm; amv[n] = am;
    int p0 = atomicAdd(&lcnt[ec], 1);
    lists[ec * NTOK + p0] = n;
    int p1 = atomicAdd(&lcnt[4 + ea], 1);
    lists[(4 + ea) * NTOK + p1] = n;
    atomicAdd(&bins[ec], cm);
    atomicAdd(&bins[4 + ea], am);
    atomicAdd(&ssum[0], cm);
    atomicAdd(&ssum[1], am);
  }
  __syncthreads();
  if (t < 8) counts[t] = lcnt[t];
  if (t == 0) {
    float denom = 4.f * (ssum[0] + ssum[1]) + 1e-10f;
    float acc = 0.f;
    for (int j = 0; j < 8; ++j) {
      float u = bins[j] / denom;
      acc += u * logf(u + 1e-10f);
    }
    out_loss[0] = acc / 8.f;
  }
}

// ---------------- GEMM1 (MoE pass): M64, f16 weights, XCD remap, 2-phase --------------
// Blocks >= 3072 convert weight slots: cap_w2, ac_w2 (full), fr_w1/fr_w3/fr_w2 (compact).
__global__ __launch_bounds__(256) void k_gemm1(
    const f16* __restrict__ x16, f16* wf,
    const int* __restrict__ lists, const int* __restrict__ counts,
    f16* __restrict__ tbuf,
    const float* __restrict__ w4, const float* __restrict__ w5,
    const float* __restrict__ w6, const float* __restrict__ w7,
    const float* __restrict__ w8) {
  int bid = blockIdx.x;
  if (bid >= 3072) {
    int cvtid = bid - 3072;  // [0,594)
    int t = threadIdx.x;
    if (cvtid < 432) {
      // full-tensor copy: cap_w2 (w6) -> OFF_CW2, ac_w2 (w7) -> OFF_AW2
      int slot = cvtid / 216;
      size_t base = (size_t)(cvtid % 216) * 16384;
      const float* s = (slot ? w7 : w6) + base;
      f16* dst = wf + (slot ? OFF_AW2 : OFF_CW2) + base;
#pragma unroll
      for (int i = 0; i < 8; ++i) {
        size_t off = (size_t)(t + i * 256) * 8;
        float4 v0 = *(const float4*)(s + off);
        float4 v1 = *(const float4*)(s + off + 4);
        f16x8 h;
        h[0] = (f16)v0.x; h[1] = (f16)v0.y; h[2] = (f16)v0.z; h[3] = (f16)v0.w;
        h[4] = (f16)v1.x; h[5] = (f16)v1.y; h[6] = (f16)v1.z; h[7] = (f16)v1.w;
        *(f16x8*)(dst + off) = h;
      }
    } else {
      // compact-slice convert: fr_w1/fr_w3 (K-cols e*288..) , fr_w2 (rows e*288..)
      int fid = cvtid - 432;            // [0,162)
      int which = fid / 54;             // 0: fr_w1, 1: fr_w3, 2: fr_w2 (block-uniform)
      int base = (fid % 54) * 16384;
      const float* s = (which == 0) ? w4 : (which == 1) ? w5 : w8;
      f16* dst = wf + ((which == 0) ? OFF_FR1 : (which == 1) ? OFF_FR3 : OFF_FR2);
#pragma unroll
      for (int i = 0; i < 8; ++i) {
        int i0 = base + i * 2048 + t * 8;
        int e = i0 / 221184;
        int rem = i0 - e * 221184;
        size_t si;
        if (which < 2) {
          int hh = rem / 288, j = rem - (rem / 288) * 288;
          si = (size_t)e * 884736 + (size_t)hh * 1152 + e * 288 + j;
        } else {
          int rr = rem / 768, c = rem - (rem / 768) * 768;
          si = (size_t)e * 884736 + (size_t)(e * 288 + rr) * 768 + c;
        }
        float4 v0 = *(const float4*)(s + si);
        float4 v1 = *(const float4*)(s + si + 4);
        f16x8 h;
        h[0] = (f16)v0.x; h[1] = (f16)v0.y; h[2] = (f16)v0.z; h[3] = (f16)v0.w;
        h[4] = (f16)v1.x; h[5] = (f16)v1.y; h[6] = (f16)v1.z; h[7] = (f16)v1.w;
        *(f16x8*)(dst + i0) = h;
      }
    }
    return;
  }
  int xcd = bid & 7;
  int local = bid >> 3;
  int pair = xcd * 12 + (local >> 5);   // MT = 32
  int mt = local & 31;
  int g = pair / 12;
  int nt = pair % 12;
  int e = g & 3;
  int cnt = counts[g];
  if (mt * 64 >= cnt) return;
  const int* list = lists + g * NTOK;
  const f16* B1 = wf + (size_t)((g < 4) ? 0 : 2) * WSZ + (size_t)e * NHID * NDIM;
  const f16* B3 = wf + (size_t)((g < 4) ? 1 : 3) * WSZ + (size_t)e * NHID * NDIM;
  f16* tout = tbuf + (size_t)g * NTOK * NHID;
  int t = threadIdx.x;
  int wv = t >> 6, lane = t & 63, m16 = lane & 15, quad = lane >> 4;
  int r0 = t >> 3, ak = (t & 7) * 8;
  int m0 = mt * 64 + r0, m1 = m0 + 32;
  int tok0 = list[min(m0, cnt - 1)], tok1 = list[min(m1, cnt - 1)];
  const f16* ar0 = x16 + (size_t)tok0 * NDIM;
  const f16* ar1 = x16 + (size_t)tok1 * NDIM;
  const f16* b1r0 = B1 + (size_t)(nt * 64 + r0) * NDIM;
  const f16* b1r1 = B1 + (size_t)(nt * 64 + r0 + 32) * NDIM;
  const f16* b3r0 = B3 + (size_t)(nt * 64 + r0) * NDIM;
  const f16* b3r1 = B3 + (size_t)(nt * 64 + r0 + 32) * NDIM;
  __shared__ f16 As[64 * 72];
  __shared__ f16 Bs1[64 * 72];
  __shared__ f16 Bs2[64 * 72];
  f32x4 zf = {0.f, 0.f, 0.f, 0.f};
  f32x4 ac1[2][2] = {{zf, zf}, {zf, zf}};
  f32x4 ac2[2][2] = {{zf, zf}, {zf, zf}};
  uint4 ra0, ra1, rb10, rb11, rb30, rb31;
  ra0  = *(const uint4*)(ar0 + ak);
  ra1  = *(const uint4*)(ar1 + ak);
  rb10 = *(const uint4*)(b1r0 + ak);
  rb11 = *(const uint4*)(b1r1 + ak);
  rb30 = *(const uint4*)(b3r0 + ak);
  rb31 = *(const uint4*)(b3r1 + ak);
  for (int kc = 0; kc < NDIM; kc += 64) {
    __syncthreads();
    *(uint4*)&As[r0 * 72 + ak] = ra0;
    *(uint4*)&As[(r0 + 32) * 72 + ak] = ra1;
    *(uint4*)&Bs1[r0 * 72 + ak] = rb10;
    *(uint4*)&Bs1[(r0 + 32) * 72 + ak] = rb11;
    *(uint4*)&Bs2[r0 * 72 + ak] = rb30;
    *(uint4*)&Bs2[(r0 + 32) * 72 + ak] = rb31;
    __syncthreads();
    int kn = kc + 64;
    if (kn < NDIM) {
      ra0  = *(const uint4*)(ar0 + kn + ak);
      ra1  = *(const uint4*)(ar1 + kn + ak);
      rb10 = *(const uint4*)(b1r0 + kn + ak);
      rb11 = *(const uint4*)(b1r1 + kn + ak);
      rb30 = *(const uint4*)(b3r0 + kn + ak);
      rb31 = *(const uint4*)(b3r1 + kn + ak);
    }
#pragma unroll
    for (int ks = 0; ks < 2; ++ks) {
      int aoff = ((wv & 1) * 32 + m16) * 72 + ks * 32 + quad * 8;
      int boff = ((wv >> 1) * 32 + m16) * 72 + ks * 32 + quad * 8;
      f16x8 a0 = *(const f16x8*)&As[aoff];
      f16x8 a1 = *(const f16x8*)&As[aoff + 16 * 72];
      f16x8 b10 = *(const f16x8*)&Bs1[boff];
      f16x8 b11 = *(const f16x8*)&Bs1[boff + 16 * 72];
      f16x8 b30 = *(const f16x8*)&Bs2[boff];
      f16x8 b31 = *(const f16x8*)&Bs2[boff + 16 * 72];
      ac1[0][0] = MFMA16(a0, b10, ac1[0][0]);
      ac1[0][1] = MFMA16(a0, b11, ac1[0][1]);
      ac1[1][0] = MFMA16(a1, b10, ac1[1][0]);
      ac1[1][1] = MFMA16(a1, b11, ac1[1][1]);
      ac2[0][0] = MFMA16(a0, b30, ac2[0][0]);
      ac2[0][1] = MFMA16(a0, b31, ac2[0][1]);
      ac2[1][0] = MFMA16(a1, b30, ac2[1][0]);
      ac2[1][1] = MFMA16(a1, b31, ac2[1][1]);
    }
  }
#pragma unroll
  for (int mi = 0; mi < 2; ++mi)
#pragma unroll
    for (int ni = 0; ni < 2; ++ni)
#pragma unroll
      for (int r = 0; r < 4; ++r) {
        int row = mt * 64 + (wv & 1) * 32 + mi * 16 + quad * 4 + r;
        int col = nt * 64 + (wv >> 1) * 32 + ni * 16 + m16;
        float h1 = ac1[mi][ni][r];
        float h3 = ac2[mi][ni][r];
        float sl = h1 / (1.0f + expf(-h1));
        tout[(size_t)row * NHID + col] = (f16)(sl * h3);
      }
}

// ---------------- GEMM1 (fr pass): A = f16(ybc+yba) slice, B = compact fr1c/fr3c ------
__global__ __launch_bounds__(256) void k_gemm1_fr(
    const float* __restrict__ ybc, const float* __restrict__ yba,
    const f16* __restrict__ wf, f16* __restrict__ tbuf) {
  int e = blockIdx.z, mt = blockIdx.y, nt = blockIdx.x;
  const int K = 288;
  int koff = e * 288;
  const f16* B1 = wf + OFF_FR1 + (size_t)e * 768 * 288;
  const f16* B3 = wf + OFF_FR3 + (size_t)e * 768 * 288;
  f16* tout = tbuf + (size_t)e * NTOK * NHID;
  int t = threadIdx.x;
  int wv = t >> 6, lane = t & 63, m16 = lane & 15, quad = lane >> 4;
  int r0 = t >> 3, ak = (t & 7) * 8;
  const float* c0 = ybc + (size_t)(mt * 64 + r0) * NDIM + koff;
  const float* c1 = ybc + (size_t)(mt * 64 + r0 + 32) * NDIM + koff;
  const float* d0 = yba + (size_t)(mt * 64 + r0) * NDIM + koff;
  const float* d1 = yba + (size_t)(mt * 64 + r0 + 32) * NDIM + koff;
  const f16* b1r0 = B1 + (size_t)(nt * 64 + r0) * 288;
  const f16* b1r1 = B1 + (size_t)(nt * 64 + r0 + 32) * 288;
  const f16* b3r0 = B3 + (size_t)(nt * 64 + r0) * 288;
  const f16* b3r1 = B3 + (size_t)(nt * 64 + r0 + 32) * 288;
  __shared__ f16 As[64 * 72];
  __shared__ f16 Bs1[64 * 72];
  __shared__ f16 Bs2[64 * 72];
  f32x4 zf = {0.f, 0.f, 0.f, 0.f};
  f32x4 ac1[2][2] = {{zf, zf}, {zf, zf}};
  f32x4 ac2[2][2] = {{zf, zf}, {zf, zf}};
  uint4 rb10, rb11, rb30, rb31;
  rb10 = *(const uint4*)(b1r0 + ak);
  rb11 = *(const uint4*)(b1r1 + ak);
  rb30 = *(const uint4*)(b3r0 + ak);
  rb31 = *(const uint4*)(b3r1 + ak);
  for (int kc = 0; kc < K; kc += 64) {
    __syncthreads();
    {
      f16x8 h0, h1;
      int cb = kc + ak;
      if (cb < K) {
        float4 p0 = *(const float4*)(c0 + cb);
        float4 p1 = *(const float4*)(c0 + cb + 4);
        float4 q0 = *(const float4*)(d0 + cb);
        float4 q1 = *(const float4*)(d0 + cb + 4);
        h0[0] = (f16)(p0.x + q0.x); h0[1] = (f16)(p0.y + q0.y);
        h0[2] = (f16)(p0.z + q0.z); h0[3] = (f16)(p0.w + q0.w);
        h0[4] = (f16)(p1.x + q1.x); h0[5] = (f16)(p1.y + q1.y);
        h0[6] = (f16)(p1.z + q1.z); h0[7] = (f16)(p1.w + q1.w);
        p0 = *(const float4*)(c1 + cb);
        p1 = *(const float4*)(c1 + cb + 4);
        q0 = *(const float4*)(d1 + cb);
        q1 = *(const float4*)(d1 + cb + 4);
        h1[0] = (f16)(p0.x + q0.x); h1[1] = (f16)(p0.y + q0.y);
        h1[2] = (f16)(p0.z + q0.z); h1[3] = (f16)(p0.w + q0.w);
        h1[4] = (f16)(p1.x + q1.x); h1[5] = (f16)(p1.y + q1.y);
        h1[6] = (f16)(p1.z + q1.z); h1[7] = (f16)(p1.w + q1.w);
      } else {
#pragma unroll
        for (int j = 0; j < 8; ++j) { h0[j] = (f16)0.f; h1[j] = (f16)0.f; }
      }
      *(f16x8*)&As[r0 * 72 + ak] = h0;
      *(f16x8*)&As[(r0 + 32) * 72 + ak] = h1;
    }
    *(uint4*)&Bs1[r0 * 72 + ak] = rb10;
    *(uint4*)&Bs1[(r0 + 32) * 72 + ak] = rb11;
    *(uint4*)&Bs2[r0 * 72 + ak] = rb30;
    *(uint4*)&Bs2[(r0 + 32) * 72 + ak] = rb31;
    __syncthreads();
    int kn = kc + 64;
    if (kn < K) {
      bool v = (kn + ak < K);
      uint4 z4u = make_uint4(0u, 0u, 0u, 0u);
      rb10 = v ? *(const uint4*)(b1r0 + kn + ak) : z4u;
      rb11 = v ? *(const uint4*)(b1r1 + kn + ak) : z4u;
      rb30 = v ? *(const uint4*)(b3r0 + kn + ak) : z4u;
      rb31 = v ? *(const uint4*)(b3r1 + kn + ak) : z4u;
    }
#pragma unroll
    for (int ks = 0; ks < 2; ++ks) {
      int aoff = ((wv & 1) * 32 + m16) * 72 + ks * 32 + quad * 8;
      int boff = ((wv >> 1) * 32 + m16) * 72 + ks * 32 + quad * 8;
      f16x8 a0 = *(const f16x8*)&As[aoff];
      f16x8 a1 = *(const f16x8*)&As[aoff + 16 * 72];
      f16x8 b10 = *(const f16x8*)&Bs1[boff];
      f16x8 b11 = *(const f16x8*)&Bs1[boff + 16 * 72];
      f16x8 b30 = *(const f16x8*)&Bs2[boff];
      f16x8 b31 = *(const f16x8*)&Bs2[boff + 16 * 72];
      ac1[0][0] = MFMA16(a0, b10, ac1[0][0]);
      ac1[0][1] = MFMA16(a0, b11, ac1[0][1]);
      ac1[1][0] = MFMA16(a1, b10, ac1[1][0]);
      ac1[1][1] = MFMA16(a1, b11, ac1[1][1]);
      ac2[0][0] = MFMA16(a0, b30, ac2[0][0]);
      ac2[0][1] = MFMA16(a0, b31, ac2[0][1]);
      ac2[1][0] = MFMA16(a1, b30, ac2[1][0]);
      ac2[1][1] = MFMA16(a1, b31, ac2[1][1]);
    }
  }
#pragma unroll
  for (int mi = 0; mi < 2; ++mi)
#pragma unroll
    for (int ni = 0; ni < 2; ++ni)
#pragma unroll
      for (int r = 0; r < 4; ++r) {
        int row = mt * 64 + (wv & 1) * 32 + mi * 16 + quad * 4 + r;
        int col = nt * 64 + (wv >> 1) * 32 + ni * 16 + m16;
        float h1v = ac1[mi][ni][r];
        float h3v = ac2[mi][ni][r];
        float sl = h1v / (1.0f + expf(-h1v));
        tout[(size_t)row * NHID + col] = (f16)(sl * h3v);
      }
}

// ---------------- GEMM2 (MoE): f16 weights, XCD-grouped remap, 2-phase ----------------
__global__ __launch_bounds__(256) void k_gemm2(
    const f16* __restrict__ tbuf, const f16* __restrict__ wf,
    const int* __restrict__ lists, const int* __restrict__ counts,
    const float* __restrict__ cmv, const float* __restrict__ amv,
    float* __restrict__ yc, float* __restrict__ ya) {
  int bid = blockIdx.x;
  int xcd = bid & 7;
  int local = bid >> 3;
  int pair = xcd * 18 + (local >> 5);
  int mt = local & 31;
  int g = pair / 18;
  int nt = pair % 18;
  int e = g & 3;
  int cnt = counts[g];
  if (mt * 64 >= cnt) return;
  const int* list = lists + g * NTOK;
  const f16* A = tbuf + (size_t)g * NTOK * NHID;
  const f16* Bw = wf + ((g < 4) ? OFF_CW2 : OFF_AW2) + (size_t)e * NDIM * NHID;
  const float* sc = (g < 4) ? cmv : amv;
  float* y = (g < 4) ? yc : ya;
  int t = threadIdx.x;
  int wv = t >> 6, lane = t & 63, m16 = lane & 15, quad = lane >> 4;
  int r0 = t >> 3, ak = (t & 7) * 8;
  const f16* ar0 = A + (size_t)(mt * 64 + r0) * NHID;
  const f16* ar1 = A + (size_t)(mt * 64 + r0 + 32) * NHID;
  const f16* br0 = Bw + (size_t)(nt * 64 + r0) * NHID;
  const f16* br1 = Bw + (size_t)(nt * 64 + r0 + 32) * NHID;
  __shared__ f16 As[64 * 72];
  __shared__ f16 Bs[64 * 72];
  f32x4 zf = {0.f, 0.f, 0.f, 0.f};
  f32x4 acc[2][2] = {{zf, zf}, {zf, zf}};
  uint4 ra0, ra1, rb0, rb1;
  ra0 = *(const uint4*)(ar0 + ak);
  ra1 = *(const uint4*)(ar1 + ak);
  rb0 = *(const uint4*)(br0 + ak);
  rb1 = *(const uint4*)(br1 + ak);
  for (int kc = 0; kc < NHID; kc += 64) {
    __syncthreads();
    *(uint4*)&As[r0 * 72 + ak] = ra0;
    *(uint4*)&As[(r0 + 32) * 72 + ak] = ra1;
    *(uint4*)&Bs[r0 * 72 + ak] = rb0;
    *(uint4*)&Bs[(r0 + 32) * 72 + ak] = rb1;
    __syncthreads();
    int kn = kc + 64;
    if (kn < NHID) {
      ra0 = *(const uint4*)(ar0 + kn + ak);
      ra1 = *(const uint4*)(ar1 + kn + ak);
      rb0 = *(const uint4*)(br0 + kn + ak);
      rb1 = *(const uint4*)(br1 + kn + ak);
    }
#pragma unroll
    for (int ks = 0; ks < 2; ++ks) {
      int aoff = ((wv & 1) * 32 + m16) * 72 + ks * 32 + quad * 8;
      int boff = ((wv >> 1) * 32 + m16) * 72 + ks * 32 + quad * 8;
      f16x8 a0 = *(const f16x8*)&As[aoff];
      f16x8 a1 = *(const f16x8*)&As[aoff + 16 * 72];
      f16x8 b0 = *(const f16x8*)&Bs[boff];
      f16x8 b1 = *(const f16x8*)&Bs[boff + 16 * 72];
      acc[0][0] = MFMA16(a0, b0, acc[0][0]);
      acc[0][1] = MFMA16(a0, b1, acc[0][1]);
      acc[1][0] = MFMA16(a1, b0, acc[1][0]);
      acc[1][1] = MFMA16(a1, b1, acc[1][1]);
    }
  }
#pragma unroll
  for (int mi = 0; mi < 2; ++mi)
#pragma unroll
    for (int ni = 0; ni < 2; ++ni)
#pragma unroll
      for (int r = 0; r < 4; ++r) {
        int mg = mt * 64 + (wv & 1) * 32 + mi * 16 + quad * 4 + r;
        if (mg < cnt) {
          int tok = list[mg];
          int col = nt * 64 + (wv >> 1) * 32 + ni * 16 + m16;
          float v = acc[mi][ni][r] * sc[tok];
          y[(size_t)tok * NDIM + col] = v;
        }
      }
}

// ---------------- GEMM2 (fr): compact fr2c, t16 @ slice -> z, 2-phase -----------------
__global__ __launch_bounds__(256) void k_gemm2_fr(
    const f16* __restrict__ tbuf, const f16* __restrict__ wf, float* __restrict__ zz) {
  int e = blockIdx.z;
  int mt = blockIdx.y, nt = blockIdx.x;
  const f16* A = tbuf + (size_t)e * NTOK * NHID;
  const f16* Bw = wf + OFF_FR2 + (size_t)e * 288 * NHID;
  int t = threadIdx.x;
  int wv = t >> 6, lane = t & 63, m16 = lane & 15, quad = lane >> 4;
  int r0 = t >> 3, ak = (t & 7) * 8;
  const f16* ar0 = A + (size_t)(mt * 64 + r0) * NHID;
  const f16* ar1 = A + (size_t)(mt * 64 + r0 + 32) * NHID;
  int ne0 = min(nt * 64 + r0, 287), ne1 = min(nt * 64 + r0 + 32, 287);
  const f16* br0 = Bw + (size_t)ne0 * NHID;
  const f16* br1 = Bw + (size_t)ne1 * NHID;
  __shared__ f16 As[64 * 72];
  __shared__ f16 Bs[64 * 72];
  f32x4 zf = {0.f, 0.f, 0.f, 0.f};
  f32x4 acc[2][2] = {{zf, zf}, {zf, zf}};
  uint4 ra0, ra1, rb0, rb1;
  ra0 = *(const uint4*)(ar0 + ak);
  ra1 = *(const uint4*)(ar1 + ak);
  rb0 = *(const uint4*)(br0 + ak);
  rb1 = *(const uint4*)(br1 + ak);
  for (int kc = 0; kc < NHID; kc += 64) {
    __syncthreads();
    *(uint4*)&As[r0 * 72 + ak] = ra0;
    *(uint4*)&As[(r0 + 32) * 72 + ak] = ra1;
    *(uint4*)&Bs[r0 * 72 + ak] = rb0;
    *(uint4*)&Bs[(r0 + 32) * 72 + ak] = rb1;
    __syncthreads();
    int kn = kc + 64;
    if (kn < NHID) {
      ra0 = *(const uint4*)(ar0 + kn + ak);
      ra1 = *(const uint4*)(ar1 + kn + ak);
      rb0 = *(const uint4*)(br0 + kn + ak);
      rb1 = *(const uint4*)(br1 + kn + ak);
    }
#pragma unroll
    for (int ks = 0; ks < 2; ++ks) {
      int aoff = ((wv & 1) * 32 + m16) * 72 + ks * 32 + quad * 8;
      int boff = ((wv >> 1) * 32 + m16) * 72 + ks * 32 + quad * 8;
      f16x8 a0 = *(const f16x8*)&As[aoff];
      f16x8 a1 = *(const f16x8*)&As[aoff + 16 * 72];
      f16x8 b0 = *(const f16x8*)&Bs[boff];
      f16x8 b1 = *(const f16x8*)&Bs[boff + 16 * 72];
      acc[0][0] = MFMA16(a0, b0, acc[0][0]);
      acc[0][1] = MFMA16(a0, b1, acc[0][1]);
      acc[1][0] = MFMA16(a1, b0, acc[1][0]);
      acc[1][1] = MFMA16(a1, b1, acc[1][1]);
    }
  }
#pragma unroll
  for (int mi = 0; mi < 2; ++mi)
#pragma unroll
    for (int ni = 0; ni < 2; ++ni)
#pragma unroll
      for (int r = 0; r < 4; ++r) {
        int cg = nt * 64 + (wv >> 1) * 32 + ni * 16 + m16;
        if (cg < 288) {
          int row = mt * 64 + (wv & 1) * 32 + mi * 16 + quad * 4 + r;
          zz[(size_t)row * NDIM + e * 288 + cg] = acc[mi][ni][r];
        }
      }
}

// ---------------- host ----------------
extern "C" void kernel_launch(void* const* d_in, const int* in_sizes, int n_in,
                              void* d_out, int out_size, void* d_ws, size_t ws_size,
                              hipStream_t stream) {
  const float* x          = (const float*)d_in[0];
  const float* timep      = (const float*)d_in[1];
  const float* caption    = (const float*)d_in[2];
  const float* acoustic   = (const float*)d_in[3];
  const float* attn_in_w  = (const float*)d_in[4];
  const float* attn_in_b  = (const float*)d_in[5];
  const float* attn_out_w = (const float*)d_in[6];
  const float* attn_out_b = (const float*)d_in[7];
  const float* hl_w       = (const float*)d_in[8];
  const float* hl_b       = (const float*)d_in[9];
  const float* cap_gate_w = (const float*)d_in[10];
  const float* cap_gate_b = (const float*)d_in[11];
  const float* ac_gate_w  = (const float*)d_in[12];
  const float* ac_gate_b  = (const float*)d_in[13];
  const float* cap_w1     = (const float*)d_in[14];
  const float* cap_w2     = (const float*)d_in[15];
  const float* cap_w3     = (const float*)d_in[16];
  const float* ac_w1      = (const float*)d_in[17];
  const float* ac_w2      = (const float*)d_in[18];
  const float* ac_w3      = (const float*)d_in[19];
  const float* fr_w1      = (const float*)d_in[20];
  const float* fr_w2      = (const float*)d_in[21];
  const float* fr_w3      = (const float*)d_in[22];
  (void)in_sizes; (void)n_in; (void)out_size; (void)ws_size;

  float* zout = (float*)d_out;
  float* loss = zout + (size_t)NTOK * NDIM;

  char* wsb = (char*)d_ws;
  size_t off = 0;
  auto alloc = [&](size_t bytes) -> void* {
    void* p = wsb + off;
    off = (off + bytes + 255) & ~(size_t)255;
    return p;
  };
  // persistent small + xhi + converted weights
  float* g1     = (float*)alloc(4096 * 4);
  float* g2     = (float*)alloc(8192 * 4);
  float* g3     = (float*)alloc(8192 * 4);
  float* tl     = (float*)alloc(4 * 4);
  float* al     = (float*)alloc((size_t)NTOK * NEXP * 4);
  float* cl     = (float*)alloc((size_t)NTOK * NEXP * 4);
  float* cmv    = (float*)alloc((size_t)NTOK * 4);
  float* amv    = (float*)alloc((size_t)NTOK * 4);
  int*   lists  = (int*)alloc((size_t)8 * NTOK * 4);
  int*   counts = (int*)alloc(8 * 4);
  float* wp     = (float*)alloc((size_t)NEXP * NDIM * 4);
  float* bp     = (float*)alloc(NEXP * 4);
  float* wpp    = (float*)alloc((size_t)18 * NEXP * NDIM * 4);
  f16*   xhi    = (f16*)alloc((size_t)NTOK * NDIM * 2);
  f16*   wf16   = (f16*)alloc((size_t)(6 * WSZ + 3 * WQ) * 2);
  size_t region = off;
  // phase 1 (attention / routing inputs)
  f16*   xlo    = (f16*)alloc((size_t)NTOK * NDIM * 2);
  f16*   caphi  = (f16*)alloc((size_t)NCAP * NDIM * 2);
  f16*   caplo  = (f16*)alloc((size_t)NCAP * NDIM * 2);
  f16*   qhi    = (f16*)alloc((size_t)NTOK * NDIM * 2);
  f16*   qlo    = (f16*)alloc((size_t)NTOK * NDIM * 2);
  f16*   khi    = (f16*)alloc((size_t)NCAP * NDIM * 2);
  f16*   klo    = (f16*)alloc((size_t)NCAP * NDIM * 2);
  f16*   vthi   = (f16*)alloc((size_t)NB * NDIM * NSC * 2);
  f16*   vtlo   = (f16*)alloc((size_t)NB * NDIM * NSC * 2);
  f16*   ohi    = (f16*)alloc((size_t)NTOK * NDIM * 2);
  f16*   olo    = (f16*)alloc((size_t)NTOK * NDIM * 2);
  // phase 2 (MoE / fr) — reuses phase-1 region (all phase-1 buffers dead)
  off = region;
  f16*   tbuf   = (f16*)alloc((size_t)8 * NTOK * NHID * 2);
  float* ybc    = (float*)alloc((size_t)NTOK * NDIM * 4);
  float* yba    = (float*)alloc((size_t)NTOK * NDIM * 4);

  k_prep<<<dim3(1), dim3(256), 0, stream>>>(timep, hl_w, hl_b, g1, g2, g3, tl);
  k_fuse_gate1<<<dim3(90), dim3(256), 0, stream>>>(attn_out_w, cap_gate_w, wpp);
  k_fuse_gate2<<<dim3(19), dim3(256), 0, stream>>>(wpp, cap_gate_w, attn_out_b,
                                                   cap_gate_b, wp, bp);
  k_ac_logits<<<dim3(512), dim3(256), 0, stream>>>(acoustic, ac_gate_w, ac_gate_b, al);
  k_cvt_split<<<dim3(2304), dim3(256), 0, stream>>>(x, xhi, xlo, NTOK * NDIM);
  k_cvt_split<<<dim3(288), dim3(256), 0, stream>>>(caption, caphi, caplo, NCAP * NDIM);
  // fused: QKV projection (z<3) + grid-stride cvt of slots 0-3 (z=3,4)
  k_gemm_qkv<<<dim3(18, 32, 5), dim3(256), 0, stream>>>(
      xhi, xlo, caphi, caplo, attn_in_w, attn_in_b,
      qhi, qlo, khi, klo, vthi, vtlo,
      cap_w1, cap_w3, ac_w1, ac_w3, wf16);
  k_attn<<<dim3(16, 16), dim3(256), 0, stream>>>(qhi, qlo, khi, klo, vthi, vtlo, ohi, olo);
  k_o_logits<<<dim3(512), dim3(256), 0, stream>>>(ohi, olo, wp, bp, cl);
  k_route<<<dim3(1), dim3(1024), 0, stream>>>(cl, al, g1, g2, g3, tl,
                                              cmv, amv, lists, counts, loss);
  // gemm1 MoE pass (8 groups) + tail cvt blocks (cap_w2/ac_w2 full + fr compacts)
  k_gemm1<<<dim3(3666), dim3(256), 0, stream>>>(xhi, wf16, lists, counts, tbuf,
                                                fr_w1, fr_w3, cap_w2, ac_w2, fr_w2);
  k_gemm2<<<dim3(4608), dim3(256), 0, stream>>>(tbuf, wf16, lists, counts,
                                                cmv, amv, ybc, yba);
  k_gemm1_fr<<<dim3(12, 32, 4), dim3(256), 0, stream>>>(ybc, yba, wf16, tbuf);
  k_gemm2_fr<<<dim3(5, 32, 4), dim3(256), 0, stream>>>(tbuf, wf16, zout);
}

// Round 9
// 431.741 us; speedup vs baseline: 1.3481x; 1.0223x over previous
//
#include <hip/hip_runtime.h>
#include <stdint.h>

#define NDIM 1152
#define NEXP 4
#define NHID 768
#define NHEAD 8
#define HDIM 144
#define NB 2
#define NS 1024
#define NSC 128
#define NTOK 2048
#define NCAP 256

typedef _Float16 f16;
typedef _Float16 f16x4 __attribute__((ext_vector_type(4)));
typedef _Float16 f16x8 __attribute__((ext_vector_type(8)));
typedef float f32x4 __attribute__((ext_vector_type(4)));

#define MFMA16(a, b, c) __builtin_amdgcn_mfma_f32_16x16x32_f16(a, b, c, 0, 0, 0)

#define WSZ ((size_t)NEXP * NHID * NDIM)  // elems per full weight tensor (3,538,944)
#define WQ  ((size_t)(WSZ / 4))           // compact fr tensor elems (884,736)
#define OFF_CW2 ((size_t)4 * WSZ)
#define OFF_AW2 ((size_t)5 * WSZ)
#define OFF_FR1 ((size_t)6 * WSZ)
#define OFF_FR3 ((size_t)6 * WSZ + WQ)
#define OFF_FR2 ((size_t)6 * WSZ + 2 * WQ)

// k_pre block ranges
#define PRE_XB   2304                     // x split (4/thread)
#define PRE_CB   288                      // caption split
#define PRE_IWB  1944                     // attn_in_w split (8/thread)
#define PRE_X0   0
#define PRE_C0   (PRE_XB)
#define PRE_IW0  (PRE_C0 + PRE_CB)
#define PRE_GUM  (PRE_IW0 + PRE_IWB)      // 4536
#define PRE_FG0  (PRE_GUM + 1)            // 4537 .. 4555 (18 col blocks + 1 bias)
#define PRE_AL0  (PRE_FG0 + 19)           // 4556
#define PRE_NB   (PRE_AL0 + 512)          // 5068

// ---------------- Threefry2x32 (exact JAX replication) ----------------
__device__ inline uint2 tfry(uint32_t k0, uint32_t k1, uint32_t x0, uint32_t x1) {
  uint32_t k2 = k0 ^ k1 ^ 0x1BD11BDAu;
#define RND(r) { x0 += x1; x1 = (x1 << r) | (x1 >> (32 - r)); x1 ^= x0; }
  x0 += k0; x1 += k1;
  RND(13) RND(15) RND(26) RND(6)
  x0 += k1; x1 += k2 + 1u;
  RND(17) RND(29) RND(16) RND(24)
  x0 += k2; x1 += k0 + 2u;
  RND(13) RND(15) RND(26) RND(6)
  x0 += k0; x1 += k1 + 3u;
  RND(17) RND(29) RND(16) RND(24)
  x0 += k1; x1 += k2 + 4u;
  RND(13) RND(15) RND(26) RND(6)
  x0 += k2; x1 += k0 + 5u;
#undef RND
  return make_uint2(x0, x1);
}

__device__ inline float b2g(uint32_t bits) {
  uint32_t fb = (bits >> 9) | 0x3f800000u;
  float f = __uint_as_float(fb) - 1.0f;
  const float tiny = 1.1754943508222875e-38f;
  float u = f * 1.0f + tiny;
  u = fmaxf(tiny, u);
  return -logf(-logf(u));
}

// ---------------- k_pre: all preprocessing in one launch ----------------
// roles by blockIdx.x:
//  [0,2304)      : x f32 -> xhi/xlo split
//  [2304,2592)   : caption -> caphi/caplo split
//  [2592,4536)   : attn_in_w -> inwhi/inwlo split
//  4536          : gumbels + time-logits
//  [4537,4556)   : fused gate W' = gw @ ow (18 col blocks) + bias block
//  [4556,5068)   : acoustic gate logits al
__global__ __launch_bounds__(256) void k_pre(
    const float* __restrict__ x, const float* __restrict__ caption,
    const float* __restrict__ inw,
    const float* __restrict__ timep, const float* __restrict__ hlw,
    const float* __restrict__ hlb,
    const float* __restrict__ acous, const float* __restrict__ agw,
    const float* __restrict__ agb,
    const float* __restrict__ ow, const float* __restrict__ ob,
    const float* __restrict__ gw, const float* __restrict__ gb,
    f16* __restrict__ xhi, f16* __restrict__ xlo,
    f16* __restrict__ caphi, f16* __restrict__ caplo,
    f16* __restrict__ inwhi, f16* __restrict__ inwlo,
    float* __restrict__ g1, float* __restrict__ g2, float* __restrict__ g3,
    float* __restrict__ tl, float* __restrict__ al,
    float* __restrict__ wp, float* __restrict__ bp) {
  __shared__ float sm[4][4][64];
  int bid = blockIdx.x;
  int t = threadIdx.x;
  if (bid < PRE_C0) {
    int i = bid * 1024 + t * 4;
    float4 v = *(const float4*)(x + i);
    f16x4 h, l;
    h[0] = (f16)v.x; l[0] = (f16)((v.x - (float)h[0]) * 2048.f);
    h[1] = (f16)v.y; l[1] = (f16)((v.y - (float)h[1]) * 2048.f);
    h[2] = (f16)v.z; l[2] = (f16)((v.z - (float)h[2]) * 2048.f);
    h[3] = (f16)v.w; l[3] = (f16)((v.w - (float)h[3]) * 2048.f);
    *(f16x4*)(xhi + i) = h;
    *(f16x4*)(xlo + i) = l;
    return;
  }
  if (bid < PRE_IW0) {
    int i = (bid - PRE_C0) * 1024 + t * 4;
    float4 v = *(const float4*)(caption + i);
    f16x4 h, l;
    h[0] = (f16)v.x; l[0] = (f16)((v.x - (float)h[0]) * 2048.f);
    h[1] = (f16)v.y; l[1] = (f16)((v.y - (float)h[1]) * 2048.f);
    h[2] = (f16)v.z; l[2] = (f16)((v.z - (float)h[2]) * 2048.f);
    h[3] = (f16)v.w; l[3] = (f16)((v.w - (float)h[3]) * 2048.f);
    *(f16x4*)(caphi + i) = h;
    *(f16x4*)(caplo + i) = l;
    return;
  }
  if (bid < PRE_GUM) {
    size_t i = (size_t)(bid - PRE_IW0) * 2048 + (size_t)t * 8;
    float4 v0 = *(const float4*)(inw + i);
    float4 v1 = *(const float4*)(inw + i + 4);
    f16x8 h, l;
    h[0] = (f16)v0.x; l[0] = (f16)((v0.x - (float)h[0]) * 2048.f);
    h[1] = (f16)v0.y; l[1] = (f16)((v0.y - (float)h[1]) * 2048.f);
    h[2] = (f16)v0.z; l[2] = (f16)((v0.z - (float)h[2]) * 2048.f);
    h[3] = (f16)v0.w; l[3] = (f16)((v0.w - (float)h[3]) * 2048.f);
    h[4] = (f16)v1.x; l[4] = (f16)((v1.x - (float)h[4]) * 2048.f);
    h[5] = (f16)v1.y; l[5] = (f16)((v1.y - (float)h[5]) * 2048.f);
    h[6] = (f16)v1.z; l[6] = (f16)((v1.z - (float)h[6]) * 2048.f);
    h[7] = (f16)v1.w; l[7] = (f16)((v1.w - (float)h[7]) * 2048.f);
    *(f16x8*)(inwhi + i) = h;
    *(f16x8*)(inwlo + i) = l;
    return;
  }
  if (bid == PRE_GUM) {
    uint2 k1 = tfry(0u, 42u, 0u, 0u);
    uint2 k2 = tfry(0u, 42u, 0u, 1u);
    uint2 k3 = tfry(0u, 42u, 0u, 2u);
    for (int p = t; p < 4096; p += 256) {
      uint2 o = tfry(k1.x, k1.y, 0u, (uint32_t)p);
      g1[p] = b2g(o.x ^ o.y);
    }
    for (int p = t; p < 8192; p += 256) {
      uint2 o2 = tfry(k2.x, k2.y, 0u, (uint32_t)p);
      g2[p] = b2g(o2.x ^ o2.y);
      uint2 o3 = tfry(k3.x, k3.y, 0u, (uint32_t)p);
      g3[p] = b2g(o3.x ^ o3.y);
    }
    int wv = t >> 6, lane = t & 63;
    int b = wv >> 1, j = wv & 1;
    float s = 0.f;
    for (int k = lane; k < NDIM; k += 64) s += timep[b * NDIM + k] * hlw[j * NDIM + k];
    for (int m = 32; m; m >>= 1) s += __shfl_xor(s, m);
    if (lane == 0) tl[b * 2 + j] = s + hlb[j];
    return;
  }
  if (bid < PRE_AL0) {
    int blk = bid - PRE_FG0;
    if (blk == 18) {
      int wv = t >> 6, lane = t & 63;  // wv = e
      float s = 0.f;
      for (int d = lane; d < NDIM; d += 64) s += ob[d] * gw[wv * NDIM + d];
      for (int m = 32; m; m >>= 1) s += __shfl_xor(s, m);
      if (lane == 0) bp[wv] = s + gb[wv];
      return;
    }
    int j = t & 63, w = t >> 6;
    int k = blk * 64 + j;
    float a0 = 0.f, a1 = 0.f, a2 = 0.f, a3 = 0.f;
#pragma unroll 4
    for (int d = w * 288; d < (w + 1) * 288; ++d) {
      float o = ow[(size_t)d * NDIM + k];
      a0 += gw[d] * o;
      a1 += gw[NDIM + d] * o;
      a2 += gw[2 * NDIM + d] * o;
      a3 += gw[3 * NDIM + d] * o;
    }
    sm[w][0][j] = a0; sm[w][1][j] = a1; sm[w][2][j] = a2; sm[w][3][j] = a3;
    __syncthreads();
    if (w == 0) {
#pragma unroll
      for (int e = 0; e < 4; ++e)
        wp[e * NDIM + k] = sm[0][e][j] + sm[1][e][j] + sm[2][e][j] + sm[3][e][j];
    }
    return;
  }
  {
    int wv = t >> 6, lane = t & 63;
    int n = (bid - PRE_AL0) * 4 + wv;
    float s[NEXP] = {0.f, 0.f, 0.f, 0.f};
    for (int d = lane; d < NDIM; d += 64) {
      float a = acous[(size_t)n * NDIM + d];
#pragma unroll
      for (int e = 0; e < NEXP; ++e) s[e] += a * agw[e * NDIM + d];
    }
#pragma unroll
    for (int e = 0; e < NEXP; ++e)
      for (int m = 32; m; m >>= 1) s[e] += __shfl_xor(s[e], m);
    if (lane == 0) {
#pragma unroll
      for (int e = 0; e < NEXP; ++e) al[n * NEXP + e] = s[e] + agb[e];
    }
  }
}

// ---------------- cap logits from split-f16 o: cl[n,e] = o[n,:]·W'[e,:] + b'[e] -------
__global__ void k_o_logits(const f16* __restrict__ ohi, const f16* __restrict__ olo,
                           const float* __restrict__ wp, const float* __restrict__ bp,
                           float* __restrict__ cl) {
  int wv = threadIdx.x >> 6, lane = threadIdx.x & 63;
  int n = blockIdx.x * 4 + wv;
  float s[NEXP] = {0.f, 0.f, 0.f, 0.f};
  for (int d = lane; d < NDIM; d += 64) {
    size_t gi = (size_t)n * NDIM + d;
    float a = (float)ohi[gi] + (float)olo[gi] * (1.f / 2048.f);
#pragma unroll
    for (int e = 0; e < NEXP; ++e) s[e] += a * wp[e * NDIM + d];
  }
#pragma unroll
  for (int e = 0; e < NEXP; ++e)
    for (int m = 32; m; m >>= 1) s[e] += __shfl_xor(s[e], m);
  if (lane == 0) {
#pragma unroll
    for (int e = 0; e < NEXP; ++e) cl[n * NEXP + e] = s[e] + bp[e];
  }
}

// ---------------- QKV projection (all-f16 staging) + fused weight cvt (slots 0-3) -----
// z<3: split-fp16 QKV GEMM, B pre-split (inwhi/inwlo). z==2 emits transposed V.
// z in {3,4}: grid-stride f32->f16 conversion of cap_w1/cap_w3/ac_w1/ac_w3.
__global__ __launch_bounds__(256) void k_gemm_qkv(
    const f16* __restrict__ xhi, const f16* __restrict__ xlo,
    const f16* __restrict__ caphi, const f16* __restrict__ caplo,
    const f16* __restrict__ inwhi, const f16* __restrict__ inwlo,
    const float* __restrict__ inb,
    f16* __restrict__ qhi, f16* __restrict__ qlo,
    f16* __restrict__ khi, f16* __restrict__ klo,
    f16* __restrict__ vthi, f16* __restrict__ vtlo,
    const float* __restrict__ w0, const float* __restrict__ w1,
    const float* __restrict__ w2, const float* __restrict__ w3,
    f16* __restrict__ wf16) {
  int z = blockIdx.z;
  if (z >= 3) {
    int cvtid = (z - 3) * 576 + blockIdx.y * 18 + blockIdx.x;
    size_t c0 = (size_t)cvtid * 12288;
    int slot = (int)(c0 / WSZ);               // block-uniform (12288 | WSZ)
    size_t base = c0 % WSZ;
    const float* s = ((slot == 0) ? w0 : (slot == 1) ? w1 : (slot == 2) ? w2 : w3) + base;
    f16* dst = wf16 + (size_t)slot * WSZ + base;
#pragma unroll
    for (int i = 0; i < 6; ++i) {
      size_t off = (size_t)(threadIdx.x + i * 256) * 8;
      float4 v0 = *(const float4*)(s + off);
      float4 v1 = *(const float4*)(s + off + 4);
      f16x8 h;
      h[0] = (f16)v0.x; h[1] = (f16)v0.y; h[2] = (f16)v0.z; h[3] = (f16)v0.w;
      h[4] = (f16)v1.x; h[5] = (f16)v1.y; h[6] = (f16)v1.z; h[7] = (f16)v1.w;
      *(f16x8*)(dst + off) = h;
    }
    return;
  }
  int M = (z == 0) ? NTOK : NCAP;
  int mt = blockIdx.y, nt = blockIdx.x;
  if (mt * 64 >= M) return;
  const f16* Ah_g = (z == 0) ? xhi : caphi;
  const f16* Al_g = (z == 0) ? xlo : caplo;
  __shared__ f16 Ash[64 * 72];
  __shared__ f16 Asl[64 * 72];
  __shared__ f16 Bsh[64 * 72];
  __shared__ f16 Bsl[64 * 72];
  int t = threadIdx.x;
  int wv = t >> 6, lane = t & 63, m16 = lane & 15, quad = lane >> 4;
  int r0 = t >> 3, ak = (t & 7) * 8;
  size_t a0o = (size_t)(mt * 64 + r0) * NDIM;
  size_t a1o = (size_t)(mt * 64 + r0 + 32) * NDIM;
  const f16* bh0 = inwhi + (size_t)(z * NDIM + nt * 64 + r0) * NDIM;
  const f16* bh1 = bh0 + (size_t)32 * NDIM;
  const f16* bl0 = inwlo + (size_t)(z * NDIM + nt * 64 + r0) * NDIM;
  const f16* bl1 = bl0 + (size_t)32 * NDIM;
  f32x4 zf = {0.f, 0.f, 0.f, 0.f};
  f32x4 ah[2][2] = {{zf, zf}, {zf, zf}};
  f32x4 am[2][2] = {{zf, zf}, {zf, zf}};
  uint4 rah0, rah1, ral0, ral1, rbh0, rbh1, rbl0, rbl1;
  rah0 = *(const uint4*)(Ah_g + a0o + ak);
  rah1 = *(const uint4*)(Ah_g + a1o + ak);
  ral0 = *(const uint4*)(Al_g + a0o + ak);
  ral1 = *(const uint4*)(Al_g + a1o + ak);
  rbh0 = *(const uint4*)(bh0 + ak);
  rbh1 = *(const uint4*)(bh1 + ak);
  rbl0 = *(const uint4*)(bl0 + ak);
  rbl1 = *(const uint4*)(bl1 + ak);
  for (int kc = 0; kc < NDIM; kc += 64) {
    __syncthreads();
    *(uint4*)&Ash[r0 * 72 + ak] = rah0;
    *(uint4*)&Ash[(r0 + 32) * 72 + ak] = rah1;
    *(uint4*)&Asl[r0 * 72 + ak] = ral0;
    *(uint4*)&Asl[(r0 + 32) * 72 + ak] = ral1;
    *(uint4*)&Bsh[r0 * 72 + ak] = rbh0;
    *(uint4*)&Bsh[(r0 + 32) * 72 + ak] = rbh1;
    *(uint4*)&Bsl[r0 * 72 + ak] = rbl0;
    *(uint4*)&Bsl[(r0 + 32) * 72 + ak] = rbl1;
    __syncthreads();
    int kn = kc + 64;
    if (kn < NDIM) {
      rah0 = *(const uint4*)(Ah_g + a0o + kn + ak);
      rah1 = *(const uint4*)(Ah_g + a1o + kn + ak);
      ral0 = *(const uint4*)(Al_g + a0o + kn + ak);
      ral1 = *(const uint4*)(Al_g + a1o + kn + ak);
      rbh0 = *(const uint4*)(bh0 + kn + ak);
      rbh1 = *(const uint4*)(bh1 + kn + ak);
      rbl0 = *(const uint4*)(bl0 + kn + ak);
      rbl1 = *(const uint4*)(bl1 + kn + ak);
    }
#pragma unroll
    for (int ks = 0; ks < 2; ++ks) {
      int aoff = ((wv & 1) * 32 + m16) * 72 + ks * 32 + quad * 8;
      int boff = ((wv >> 1) * 32 + m16) * 72 + ks * 32 + quad * 8;
      f16x8 a0h = *(const f16x8*)&Ash[aoff];
      f16x8 a1h = *(const f16x8*)&Ash[aoff + 16 * 72];
      f16x8 a0l = *(const f16x8*)&Asl[aoff];
      f16x8 a1l = *(const f16x8*)&Asl[aoff + 16 * 72];
      f16x8 b0h = *(const f16x8*)&Bsh[boff];
      f16x8 b1h = *(const f16x8*)&Bsh[boff + 16 * 72];
      f16x8 b0l = *(const f16x8*)&Bsl[boff];
      f16x8 b1l = *(const f16x8*)&Bsl[boff + 16 * 72];
      ah[0][0] = MFMA16(a0h, b0h, ah[0][0]);
      ah[0][1] = MFMA16(a0h, b1h, ah[0][1]);
      ah[1][0] = MFMA16(a1h, b0h, ah[1][0]);
      ah[1][1] = MFMA16(a1h, b1h, ah[1][1]);
      am[0][0] = MFMA16(a0h, b0l, am[0][0]);
      am[0][1] = MFMA16(a0h, b1l, am[0][1]);
      am[1][0] = MFMA16(a1h, b0l, am[1][0]);
      am[1][1] = MFMA16(a1h, b1l, am[1][1]);
      am[0][0] = MFMA16(a0l, b0h, am[0][0]);
      am[0][1] = MFMA16(a0l, b1h, am[0][1]);
      am[1][0] = MFMA16(a1l, b0h, am[1][0]);
      am[1][1] = MFMA16(a1l, b1h, am[1][1]);
    }
  }
#pragma unroll
  for (int mi = 0; mi < 2; ++mi)
#pragma unroll
    for (int ni = 0; ni < 2; ++ni)
#pragma unroll
      for (int r = 0; r < 4; ++r) {
        int row = mt * 64 + (wv & 1) * 32 + mi * 16 + quad * 4 + r;
        int col = nt * 64 + (wv >> 1) * 32 + ni * 16 + m16;
        float v = ah[mi][ni][r] + am[mi][ni][r] * (1.f / 2048.f) + inb[z * NDIM + col];
        size_t idx = (size_t)row * NDIM + col;
        if (z == 0) {
          f16 hq = (f16)v;
          qhi[idx] = hq;
          qlo[idx] = (f16)((v - (float)hq) * 2048.f);
        } else if (z == 1) {
          f16 hk = (f16)v;
          khi[idx] = hk;
          klo[idx] = (f16)((v - (float)hk) * 2048.f);
        } else {
          f16 hv = (f16)v;
          int bb = row >> 7, kv = row & 127;
          size_t ti = (size_t)(bb * NDIM + col) * NSC + kv;
          vthi[ti] = hv;
          vtlo[ti] = (f16)((v - (float)hv) * 2048.f);
        }
      }
}

// ---------------- fused attention: QK^T + softmax + PV, split-fp16, writes o hi/lo ----
__global__ __launch_bounds__(256) void k_attn(
    const f16* __restrict__ qhi, const f16* __restrict__ qlo,
    const f16* __restrict__ khi, const f16* __restrict__ klo,
    const f16* __restrict__ vthi, const f16* __restrict__ vtlo,
    f16* __restrict__ ohi, f16* __restrict__ olo) {
  int mt = blockIdx.x, bh = blockIdx.y;
  int b = bh >> 3, h = bh & 7;
  __shared__ f16 Ah[64 * 160];
  __shared__ f16 Al[64 * 160];
  __shared__ f16 Bh[32 * 160];
  __shared__ f16 Bl[32 * 160];
  __shared__ f16 Ph[64 * 136];
  __shared__ f16 Pl[64 * 136];
  int t = threadIdx.x;
  int wv = t >> 6, lane = t & 63, m16 = lane & 15, quad = lane >> 4;
  for (int u = t; u < 64 * 20; u += 256) {
    int r = u / 20, kp = (u % 20) * 8;
    uint4 vh = make_uint4(0u, 0u, 0u, 0u), vl = vh;
    if (kp < HDIM) {
      size_t gi = (size_t)(b * NS + mt * 64 + r) * NDIM + h * HDIM + kp;
      vh = *(const uint4*)&qhi[gi];
      vl = *(const uint4*)&qlo[gi];
    }
    *(uint4*)&Ah[r * 160 + kp] = vh;
    *(uint4*)&Al[r * 160 + kp] = vl;
  }
  __syncthreads();
  f16x8 ahf[5], alf[5];
#pragma unroll
  for (int ks = 0; ks < 5; ++ks) {
    int ao = (wv * 16 + m16) * 160 + ks * 32 + quad * 8;
    ahf[ks] = *(const f16x8*)&Ah[ao];
    alf[ks] = *(const f16x8*)&Al[ao];
  }
  f32x4 zf = {0.f, 0.f, 0.f, 0.f};
  f32x4 sh_[4][2], sm_[4][2];
#pragma unroll
  for (int kt = 0; kt < 4; ++kt)
#pragma unroll
    for (int ni = 0; ni < 2; ++ni) { sh_[kt][ni] = zf; sm_[kt][ni] = zf; }
  for (int kt = 0; kt < 4; ++kt) {
    if (kt) __syncthreads();
    for (int u = t; u < 32 * 20; u += 256) {
      int r = u / 20, kp = (u % 20) * 8;
      uint4 vh = make_uint4(0u, 0u, 0u, 0u), vl = vh;
      if (kp < HDIM) {
        size_t gi = (size_t)(b * NSC + kt * 32 + r) * NDIM + h * HDIM + kp;
        vh = *(const uint4*)&khi[gi];
        vl = *(const uint4*)&klo[gi];
      }
      *(uint4*)&Bh[r * 160 + kp] = vh;
      *(uint4*)&Bl[r * 160 + kp] = vl;
    }
    __syncthreads();
#pragma unroll
    for (int ks = 0; ks < 5; ++ks) {
#pragma unroll
      for (int ni = 0; ni < 2; ++ni) {
        int bo = (ni * 16 + m16) * 160 + ks * 32 + quad * 8;
        f16x8 bhf = *(const f16x8*)&Bh[bo];
        f16x8 blf = *(const f16x8*)&Bl[bo];
        sh_[kt][ni] = MFMA16(ahf[ks], bhf, sh_[kt][ni]);
        sm_[kt][ni] = MFMA16(ahf[ks], blf, sm_[kt][ni]);
        sm_[kt][ni] = MFMA16(alf[ks], bhf, sm_[kt][ni]);
      }
    }
  }
  float sv[4][2][4];
  float mx[4] = {-1e30f, -1e30f, -1e30f, -1e30f};
#pragma unroll
  for (int kt = 0; kt < 4; ++kt)
#pragma unroll
    for (int ni = 0; ni < 2; ++ni)
#pragma unroll
      for (int r = 0; r < 4; ++r) {
        float s = (sh_[kt][ni][r] + sm_[kt][ni][r] * (1.f / 2048.f)) * (1.f / 12.f);
        sv[kt][ni][r] = s;
        mx[r] = fmaxf(mx[r], s);
      }
#pragma unroll
  for (int r = 0; r < 4; ++r) {
    mx[r] = fmaxf(mx[r], __shfl_xor(mx[r], 1));
    mx[r] = fmaxf(mx[r], __shfl_xor(mx[r], 2));
    mx[r] = fmaxf(mx[r], __shfl_xor(mx[r], 4));
    mx[r] = fmaxf(mx[r], __shfl_xor(mx[r], 8));
  }
  float sum[4] = {0.f, 0.f, 0.f, 0.f};
#pragma unroll
  for (int kt = 0; kt < 4; ++kt)
#pragma unroll
    for (int ni = 0; ni < 2; ++ni)
#pragma unroll
      for (int r = 0; r < 4; ++r) {
        float e = expf(sv[kt][ni][r] - mx[r]);
        sv[kt][ni][r] = e;
        sum[r] += e;
      }
  float inv[4];
#pragma unroll
  for (int r = 0; r < 4; ++r) {
    sum[r] += __shfl_xor(sum[r], 1);
    sum[r] += __shfl_xor(sum[r], 2);
    sum[r] += __shfl_xor(sum[r], 4);
    sum[r] += __shfl_xor(sum[r], 8);
    inv[r] = 1.0f / sum[r];
  }
#pragma unroll
  for (int kt = 0; kt < 4; ++kt)
#pragma unroll
    for (int ni = 0; ni < 2; ++ni)
#pragma unroll
      for (int r = 0; r < 4; ++r) {
        float p = sv[kt][ni][r] * inv[r];
        int row = wv * 16 + quad * 4 + r;
        int col = kt * 32 + ni * 16 + m16;
        f16 ph = (f16)p;
        Ph[row * 136 + col] = ph;
        Pl[row * 136 + col] = (f16)((p - (float)ph) * 2048.f);
      }
  const f16* vbh = vthi + (size_t)(b * NDIM + h * HDIM) * NSC;
  const f16* vbl = vtlo + (size_t)(b * NDIM + h * HDIM) * NSC;
  f32x4 oh_[9], om_[9];
#pragma unroll
  for (int nb = 0; nb < 9; ++nb) { oh_[nb] = zf; om_[nb] = zf; }
#pragma unroll
  for (int ks = 0; ks < 4; ++ks) {
    int po = (wv * 16 + m16) * 136 + ks * 32 + quad * 8;
    f16x8 pah = *(const f16x8*)&Ph[po];
    f16x8 pal = *(const f16x8*)&Pl[po];
#pragma unroll
    for (int nb = 0; nb < 9; ++nb) {
      size_t vo = (size_t)(nb * 16 + m16) * NSC + ks * 32 + quad * 8;
      f16x8 bvh = *(const f16x8*)&vbh[vo];
      f16x8 bvl = *(const f16x8*)&vbl[vo];
      oh_[nb] = MFMA16(pah, bvh, oh_[nb]);
      om_[nb] = MFMA16(pah, bvl, om_[nb]);
      om_[nb] = MFMA16(pal, bvh, om_[nb]);
    }
  }
#pragma unroll
  for (int nb = 0; nb < 9; ++nb)
#pragma unroll
    for (int r = 0; r < 4; ++r) {
      int row = mt * 64 + wv * 16 + quad * 4 + r;
      int col = h * HDIM + nb * 16 + m16;
      float v = oh_[nb][r] + om_[nb][r] * (1.f / 2048.f);
      size_t idx = (size_t)(b * NS + row) * NDIM + col;
      f16 hv = (f16)v;
      ohi[idx] = hv;
      olo[idx] = (f16)((v - (float)hv) * 2048.f);
    }
}

// ---------------- routing: argmax gates, cm/am, lists, loss ----------------
__global__ __launch_bounds__(1024) void k_route(
    const float* __restrict__ cl, const float* __restrict__ al,
    const float* __restrict__ g1, const float* __restrict__ g2,
    const float* __restrict__ g3, const float* __restrict__ tl,
    float* __restrict__ cmv, float* __restrict__ amv,
    int* __restrict__ lists, int* __restrict__ counts, float* __restrict__ out_loss) {
  __shared__ int lcnt[8];
  __shared__ float bins[8];
  __shared__ float ssum[2];
  int t = threadIdx.x;
  if (t < 8) { lcnt[t] = 0; bins[t] = 0.f; }
  if (t < 2) ssum[t] = 0.f;
  __syncthreads();
  for (int n = t; n < NTOK; n += 1024) {
    float lc[NEXP];
#pragma unroll
    for (int e = 0; e < NEXP; ++e) lc[e] = cl[n * NEXP + e] + g2[n * 4 + e];
    int ec = 0; float bv = lc[0];
#pragma unroll
    for (int e = 1; e < NEXP; ++e) if (lc[e] > bv) { bv = lc[e]; ec = e; }
    float la[NEXP];
#pragma unroll
    for (int e = 0; e < NEXP; ++e) la[e] = al[n * NEXP + e] + g3[n * 4 + e];
    int ea = 0; float bva = la[0];
#pragma unroll
    for (int e = 1; e < NEXP; ++e) if (la[e] > bva) { bva = la[e]; ea = e; }
    int b = n >> 10;
    float a0 = tl[b * 2 + 0] + g1[n * 2 + 0];
    float a1 = tl[b * 2 + 1] + g1[n * 2 + 1];
    float mx = fmaxf(a0, a1);
    float e0 = expf(a0 - mx), e1 = expf(a1 - mx);
    float cm = e0 / (e0 + e1), am = e1 / (e0 + e1);
    cmv[n] = cm; amv[n] = am;
    int p0 = atomicAdd(&lcnt[ec], 1);
    lists[ec * NTOK + p0] = n;
    int p1 = atomicAdd(&lcnt[4 + ea], 1);
    lists[(4 + ea) * NTOK + p1] = n;
    atomicAdd(&bins[ec], cm);
    atomicAdd(&bins[4 + ea], am);
    atomicAdd(&ssum[0], cm);
    atomicAdd(&ssum[1], am);
  }
  __syncthreads();
  if (t < 8) counts[t] = lcnt[t];
  if (t == 0) {
    float denom = 4.f * (ssum[0] + ssum[1]) + 1e-10f;
    float acc = 0.f;
    for (int j = 0; j < 8; ++j) {
      float u = bins[j] / denom;
      acc += u * logf(u + 1e-10f);
    }
    out_loss[0] = acc / 8.f;
  }
}

// ---------------- GEMM1 (MoE pass): M64, f16 weights, XCD remap, 2-phase --------------
// Blocks >= 3072 convert weight slots: cap_w2, ac_w2 (full), fr_w1/fr_w3/fr_w2 (compact).
__global__ __launch_bounds__(256) void k_gemm1(
    const f16* __restrict__ x16, f16* wf,
    const int* __restrict__ lists, const int* __restrict__ counts,
    f16* __restrict__ tbuf,
    const float* __restrict__ w4, const float* __restrict__ w5,
    const float* __restrict__ w6, const float* __restrict__ w7,
    const float* __restrict__ w8) {
  int bid = blockIdx.x;
  if (bid >= 3072) {
    int cvtid = bid - 3072;  // [0,594)
    int t = threadIdx.x;
    if (cvtid < 432) {
      int slot = cvtid / 216;
      size_t base = (size_t)(cvtid % 216) * 16384;
      const float* s = (slot ? w7 : w6) + base;
      f16* dst = wf + (slot ? OFF_AW2 : OFF_CW2) + base;
#pragma unroll
      for (int i = 0; i < 8; ++i) {
        size_t off = (size_t)(t + i * 256) * 8;
        float4 v0 = *(const float4*)(s + off);
        float4 v1 = *(const float4*)(s + off + 4);
        f16x8 h;
        h[0] = (f16)v0.x; h[1] = (f16)v0.y; h[2] = (f16)v0.z; h[3] = (f16)v0.w;
        h[4] = (f16)v1.x; h[5] = (f16)v1.y; h[6] = (f16)v1.z; h[7] = (f16)v1.w;
        *(f16x8*)(dst + off) = h;
      }
    } else {
      int fid = cvtid - 432;            // [0,162)
      int which = fid / 54;             // 0: fr_w1, 1: fr_w3, 2: fr_w2 (block-uniform)
      int base = (fid % 54) * 16384;
      const float* s = (which == 0) ? w4 : (which == 1) ? w5 : w8;
      f16* dst = wf + ((which == 0) ? OFF_FR1 : (which == 1) ? OFF_FR3 : OFF_FR2);
#pragma unroll
      for (int i = 0; i < 8; ++i) {
        int i0 = base + i * 2048 + t * 8;
        int e = i0 / 221184;
        int rem = i0 - e * 221184;
        size_t si;
        if (which < 2) {
          int hh = rem / 288, j = rem - (rem / 288) * 288;
          si = (size_t)e * 884736 + (size_t)hh * 1152 + e * 288 + j;
        } else {
          int rr = rem / 768, c = rem - (rem / 768) * 768;
          si = (size_t)e * 884736 + (size_t)(e * 288 + rr) * 768 + c;
        }
        float4 v0 = *(const float4*)(s + si);
        float4 v1 = *(const float4*)(s + si + 4);
        f16x8 h;
        h[0] = (f16)v0.x; h[1] = (f16)v0.y; h[2] = (f16)v0.z; h[3] = (f16)v0.w;
        h[4] = (f16)v1.x; h[5] = (f16)v1.y; h[6] = (f16)v1.z; h[7] = (f16)v1.w;
        *(f16x8*)(dst + i0) = h;
      }
    }
    return;
  }
  int xcd = bid & 7;
  int local = bid >> 3;
  int pair = xcd * 12 + (local >> 5);   // MT = 32
  int mt = local & 31;
  int g = pair / 12;
  int nt = pair % 12;
  int e = g & 3;
  int cnt = counts[g];
  if (mt * 64 >= cnt) return;
  const int* list = lists + g * NTOK;
  const f16* B1 = wf + (size_t)((g < 4) ? 0 : 2) * WSZ + (size_t)e * NHID * NDIM;
  const f16* B3 = wf + (size_t)((g < 4) ? 1 : 3) * WSZ + (size_t)e * NHID * NDIM;
  f16* tout = tbuf + (size_t)g * NTOK * NHID;
  int t = threadIdx.x;
  int wv = t >> 6, lane = t & 63, m16 = lane & 15, quad = lane >> 4;
  int r0 = t >> 3, ak = (t & 7) * 8;
  int m0 = mt * 64 + r0, m1 = m0 + 32;
  int tok0 = list[min(m0, cnt - 1)], tok1 = list[min(m1, cnt - 1)];
  const f16* ar0 = x16 + (size_t)tok0 * NDIM;
  const f16* ar1 = x16 + (size_t)tok1 * NDIM;
  const f16* b1r0 = B1 + (size_t)(nt * 64 + r0) * NDIM;
  const f16* b1r1 = B1 + (size_t)(nt * 64 + r0 + 32) * NDIM;
  const f16* b3r0 = B3 + (size_t)(nt * 64 + r0) * NDIM;
  const f16* b3r1 = B3 + (size_t)(nt * 64 + r0 + 32) * NDIM;
  __shared__ f16 As[64 * 72];
  __shared__ f16 Bs1[64 * 72];
  __shared__ f16 Bs2[64 * 72];
  f32x4 zf = {0.f, 0.f, 0.f, 0.f};
  f32x4 ac1[2][2] = {{zf, zf}, {zf, zf}};
  f32x4 ac2[2][2] = {{zf, zf}, {zf, zf}};
  uint4 ra0, ra1, rb10, rb11, rb30, rb31;
  ra0  = *(const uint4*)(ar0 + ak);
  ra1  = *(const uint4*)(ar1 + ak);
  rb10 = *(const uint4*)(b1r0 + ak);
  rb11 = *(const uint4*)(b1r1 + ak);
  rb30 = *(const uint4*)(b3r0 + ak);
  rb31 = *(const uint4*)(b3r1 + ak);
  for (int kc = 0; kc < NDIM; kc += 64) {
    __syncthreads();
    *(uint4*)&As[r0 * 72 + ak] = ra0;
    *(uint4*)&As[(r0 + 32) * 72 + ak] = ra1;
    *(uint4*)&Bs1[r0 * 72 + ak] = rb10;
    *(uint4*)&Bs1[(r0 + 32) * 72 + ak] = rb11;
    *(uint4*)&Bs2[r0 * 72 + ak] = rb30;
    *(uint4*)&Bs2[(r0 + 32) * 72 + ak] = rb31;
    __syncthreads();
    int kn = kc + 64;
    if (kn < NDIM) {
      ra0  = *(const uint4*)(ar0 + kn + ak);
      ra1  = *(const uint4*)(ar1 + kn + ak);
      rb10 = *(const uint4*)(b1r0 + kn + ak);
      rb11 = *(const uint4*)(b1r1 + kn + ak);
      rb30 = *(const uint4*)(b3r0 + kn + ak);
      rb31 = *(const uint4*)(b3r1 + kn + ak);
    }
#pragma unroll
    for (int ks = 0; ks < 2; ++ks) {
      int aoff = ((wv & 1) * 32 + m16) * 72 + ks * 32 + quad * 8;
      int boff = ((wv >> 1) * 32 + m16) * 72 + ks * 32 + quad * 8;
      f16x8 a0 = *(const f16x8*)&As[aoff];
      f16x8 a1 = *(const f16x8*)&As[aoff + 16 * 72];
      f16x8 b10 = *(const f16x8*)&Bs1[boff];
      f16x8 b11 = *(const f16x8*)&Bs1[boff + 16 * 72];
      f16x8 b30 = *(const f16x8*)&Bs2[boff];
      f16x8 b31 = *(const f16x8*)&Bs2[boff + 16 * 72];
      ac1[0][0] = MFMA16(a0, b10, ac1[0][0]);
      ac1[0][1] = MFMA16(a0, b11, ac1[0][1]);
      ac1[1][0] = MFMA16(a1, b10, ac1[1][0]);
      ac1[1][1] = MFMA16(a1, b11, ac1[1][1]);
      ac2[0][0] = MFMA16(a0, b30, ac2[0][0]);
      ac2[0][1] = MFMA16(a0, b31, ac2[0][1]);
      ac2[1][0] = MFMA16(a1, b30, ac2[1][0]);
      ac2[1][1] = MFMA16(a1, b31, ac2[1][1]);
    }
  }
#pragma unroll
  for (int mi = 0; mi < 2; ++mi)
#pragma unroll
    for (int ni = 0; ni < 2; ++ni)
#pragma unroll
      for (int r = 0; r < 4; ++r) {
        int row = mt * 64 + (wv & 1) * 32 + mi * 16 + quad * 4 + r;
        int col = nt * 64 + (wv >> 1) * 32 + ni * 16 + m16;
        float h1 = ac1[mi][ni][r];
        float h3 = ac2[mi][ni][r];
        float sl = h1 / (1.0f + expf(-h1));
        tout[(size_t)row * NHID + col] = (f16)(sl * h3);
      }
}

// ---------------- GEMM1 (fr pass): A = f16(ybc+yba) slice, B = compact fr1c/fr3c ------
__global__ __launch_bounds__(256) void k_gemm1_fr(
    const float* __restrict__ ybc, const float* __restrict__ yba,
    const f16* __restrict__ wf, f16* __restrict__ tbuf) {
  int e = blockIdx.z, mt = blockIdx.y, nt = blockIdx.x;
  const int K = 288;
  int koff = e * 288;
  const f16* B1 = wf + OFF_FR1 + (size_t)e * 768 * 288;
  const f16* B3 = wf + OFF_FR3 + (size_t)e * 768 * 288;
  f16* tout = tbuf + (size_t)e * NTOK * NHID;
  int t = threadIdx.x;
  int wv = t >> 6, lane = t & 63, m16 = lane & 15, quad = lane >> 4;
  int r0 = t >> 3, ak = (t & 7) * 8;
  const float* c0 = ybc + (size_t)(mt * 64 + r0) * NDIM + koff;
  const float* c1 = ybc + (size_t)(mt * 64 + r0 + 32) * NDIM + koff;
  const float* d0 = yba + (size_t)(mt * 64 + r0) * NDIM + koff;
  const float* d1 = yba + (size_t)(mt * 64 + r0 + 32) * NDIM + koff;
  const f16* b1r0 = B1 + (size_t)(nt * 64 + r0) * 288;
  const f16* b1r1 = B1 + (size_t)(nt * 64 + r0 + 32) * 288;
  const f16* b3r0 = B3 + (size_t)(nt * 64 + r0) * 288;
  const f16* b3r1 = B3 + (size_t)(nt * 64 + r0 + 32) * 288;
  __shared__ f16 As[64 * 72];
  __shared__ f16 Bs1[64 * 72];
  __shared__ f16 Bs2[64 * 72];
  f32x4 zf = {0.f, 0.f, 0.f, 0.f};
  f32x4 ac1[2][2] = {{zf, zf}, {zf, zf}};
  f32x4 ac2[2][2] = {{zf, zf}, {zf, zf}};
  uint4 rb10, rb11, rb30, rb31;
  rb10 = *(const uint4*)(b1r0 + ak);
  rb11 = *(const uint4*)(b1r1 + ak);
  rb30 = *(const uint4*)(b3r0 + ak);
  rb31 = *(const uint4*)(b3r1 + ak);
  for (int kc = 0; kc < K; kc += 64) {
    __syncthreads();
    {
      f16x8 h0, h1;
      int cb = kc + ak;
      if (cb < K) {
        float4 p0 = *(const float4*)(c0 + cb);
        float4 p1 = *(const float4*)(c0 + cb + 4);
        float4 q0 = *(const float4*)(d0 + cb);
        float4 q1 = *(const float4*)(d0 + cb + 4);
        h0[0] = (f16)(p0.x + q0.x); h0[1] = (f16)(p0.y + q0.y);
        h0[2] = (f16)(p0.z + q0.z); h0[3] = (f16)(p0.w + q0.w);
        h0[4] = (f16)(p1.x + q1.x); h0[5] = (f16)(p1.y + q1.y);
        h0[6] = (f16)(p1.z + q1.z); h0[7] = (f16)(p1.w + q1.w);
        p0 = *(const float4*)(c1 + cb);
        p1 = *(const float4*)(c1 + cb + 4);
        q0 = *(const float4*)(d1 + cb);
        q1 = *(const float4*)(d1 + cb + 4);
        h1[0] = (f16)(p0.x + q0.x); h1[1] = (f16)(p0.y + q0.y);
        h1[2] = (f16)(p0.z + q0.z); h1[3] = (f16)(p0.w + q0.w);
        h1[4] = (f16)(p1.x + q1.x); h1[5] = (f16)(p1.y + q1.y);
        h1[6] = (f16)(p1.z + q1.z); h1[7] = (f16)(p1.w + q1.w);
      } else {
#pragma unroll
        for (int j = 0; j < 8; ++j) { h0[j] = (f16)0.f; h1[j] = (f16)0.f; }
      }
      *(f16x8*)&As[r0 * 72 + ak] = h0;
      *(f16x8*)&As[(r0 + 32) * 72 + ak] = h1;
    }
    *(uint4*)&Bs1[r0 * 72 + ak] = rb10;
    *(uint4*)&Bs1[(r0 + 32) * 72 + ak] = rb11;
    *(uint4*)&Bs2[r0 * 72 + ak] = rb30;
    *(uint4*)&Bs2[(r0 + 32) * 72 + ak] = rb31;
    __syncthreads();
    int kn = kc + 64;
    if (kn < K) {
      bool v = (kn + ak < K);
      uint4 z4u = make_uint4(0u, 0u, 0u, 0u);
      rb10 = v ? *(const uint4*)(b1r0 + kn + ak) : z4u;
      rb11 = v ? *(const uint4*)(b1r1 + kn + ak) : z4u;
      rb30 = v ? *(const uint4*)(b3r0 + kn + ak) : z4u;
      rb31 = v ? *(const uint4*)(b3r1 + kn + ak) : z4u;
    }
#pragma unroll
    for (int ks = 0; ks < 2; ++ks) {
      int aoff = ((wv & 1) * 32 + m16) * 72 + ks * 32 + quad * 8;
      int boff = ((wv >> 1) * 32 + m16) * 72 + ks * 32 + quad * 8;
      f16x8 a0 = *(const f16x8*)&As[aoff];
      f16x8 a1 = *(const f16x8*)&As[aoff + 16 * 72];
      f16x8 b10 = *(const f16x8*)&Bs1[boff];
      f16x8 b11 = *(const f16x8*)&Bs1[boff + 16 * 72];
      f16x8 b30 = *(const f16x8*)&Bs2[boff];
      f16x8 b31 = *(const f16x8*)&Bs2[boff + 16 * 72];
      ac1[0][0] = MFMA16(a0, b10, ac1[0][0]);
      ac1[0][1] = MFMA16(a0, b11, ac1[0][1]);
      ac1[1][0] = MFMA16(a1, b10, ac1[1][0]);
      ac1[1][1] = MFMA16(a1, b11, ac1[1][1]);
      ac2[0][0] = MFMA16(a0, b30, ac2[0][0]);
      ac2[0][1] = MFMA16(a0, b31, ac2[0][1]);
      ac2[1][0] = MFMA16(a1, b30, ac2[1][0]);
      ac2[1][1] = MFMA16(a1, b31, ac2[1][1]);
    }
  }
#pragma unroll
  for (int mi = 0; mi < 2; ++mi)
#pragma unroll
    for (int ni = 0; ni < 2; ++ni)
#pragma unroll
      for (int r = 0; r < 4; ++r) {
        int row = mt * 64 + (wv & 1) * 32 + mi * 16 + quad * 4 + r;
        int col = nt * 64 + (wv >> 1) * 32 + ni * 16 + m16;
        float h1v = ac1[mi][ni][r];
        float h3v = ac2[mi][ni][r];
        float sl = h1v / (1.0f + expf(-h1v));
        tout[(size_t)row * NHID + col] = (f16)(sl * h3v);
      }
}

// ---------------- GEMM2 (MoE): f16 weights, XCD-grouped remap, 2-phase ----------------
__global__ __launch_bounds__(256) void k_gemm2(
    const f16* __restrict__ tbuf, const f16* __restrict__ wf,
    const int* __restrict__ lists, const int* __restrict__ counts,
    const float* __restrict__ cmv, const float* __restrict__ amv,
    float* __restrict__ yc, float* __restrict__ ya) {
  int bid = blockIdx.x;
  int xcd = bid & 7;
  int local = bid >> 3;
  int pair = xcd * 18 + (local >> 5);
  int mt = local & 31;
  int g = pair / 18;
  int nt = pair % 18;
  int e = g & 3;
  int cnt = counts[g];
  if (mt * 64 >= cnt) return;
  const int* list = lists + g * NTOK;
  const f16* A = tbuf + (size_t)g * NTOK * NHID;
  const f16* Bw = wf + ((g < 4) ? OFF_CW2 : OFF_AW2) + (size_t)e * NDIM * NHID;
  const float* sc = (g < 4) ? cmv : amv;
  float* y = (g < 4) ? yc : ya;
  int t = threadIdx.x;
  int wv = t >> 6, lane = t & 63, m16 = lane & 15, quad = lane >> 4;
  int r0 = t >> 3, ak = (t & 7) * 8;
  const f16* ar0 = A + (size_t)(mt * 64 + r0) * NHID;
  const f16* ar1 = A + (size_t)(mt * 64 + r0 + 32) * NHID;
  const f16* br0 = Bw + (size_t)(nt * 64 + r0) * NHID;
  const f16* br1 = Bw + (size_t)(nt * 64 + r0 + 32) * NHID;
  __shared__ f16 As[64 * 72];
  __shared__ f16 Bs[64 * 72];
  f32x4 zf = {0.f, 0.f, 0.f, 0.f};
  f32x4 acc[2][2] = {{zf, zf}, {zf, zf}};
  uint4 ra0, ra1, rb0, rb1;
  ra0 = *(const uint4*)(ar0 + ak);
  ra1 = *(const uint4*)(ar1 + ak);
  rb0 = *(const uint4*)(br0 + ak);
  rb1 = *(const uint4*)(br1 + ak);
  for (int kc = 0; kc < NHID; kc += 64) {
    __syncthreads();
    *(uint4*)&As[r0 * 72 + ak] = ra0;
    *(uint4*)&As[(r0 + 32) * 72 + ak] = ra1;
    *(uint4*)&Bs[r0 * 72 + ak] = rb0;
    *(uint4*)&Bs[(r0 + 32) * 72 + ak] = rb1;
    __syncthreads();
    int kn = kc + 64;
    if (kn < NHID) {
      ra0 = *(const uint4*)(ar0 + kn + ak);
      ra1 = *(const uint4*)(ar1 + kn + ak);
      rb0 = *(const uint4*)(br0 + kn + ak);
      rb1 = *(const uint4*)(br1 + kn + ak);
    }
#pragma unroll
    for (int ks = 0; ks < 2; ++ks) {
      int aoff = ((wv & 1) * 32 + m16) * 72 + ks * 32 + quad * 8;
      int boff = ((wv >> 1) * 32 + m16) * 72 + ks * 32 + quad * 8;
      f16x8 a0 = *(const f16x8*)&As[aoff];
      f16x8 a1 = *(const f16x8*)&As[aoff + 16 * 72];
      f16x8 b0 = *(const f16x8*)&Bs[boff];
      f16x8 b1 = *(const f16x8*)&Bs[boff + 16 * 72];
      acc[0][0] = MFMA16(a0, b0, acc[0][0]);
      acc[0][1] = MFMA16(a0, b1, acc[0][1]);
      acc[1][0] = MFMA16(a1, b0, acc[1][0]);
      acc[1][1] = MFMA16(a1, b1, acc[1][1]);
    }
  }
#pragma unroll
  for (int mi = 0; mi < 2; ++mi)
#pragma unroll
    for (int ni = 0; ni < 2; ++ni)
#pragma unroll
      for (int r = 0; r < 4; ++r) {
        int mg = mt * 64 + (wv & 1) * 32 + mi * 16 + quad * 4 + r;
        if (mg < cnt) {
          int tok = list[mg];
          int col = nt * 64 + (wv >> 1) * 32 + ni * 16 + m16;
          float v = acc[mi][ni][r] * sc[tok];
          y[(size_t)tok * NDIM + col] = v;
        }
      }
}

// ---------------- GEMM2 (fr): compact fr2c, t16 @ slice -> z, 2-phase -----------------
__global__ __launch_bounds__(256) void k_gemm2_fr(
    const f16* __restrict__ tbuf, const f16* __restrict__ wf, float* __restrict__ zz) {
  int e = blockIdx.z;
  int mt = blockIdx.y, nt = blockIdx.x;
  const f16* A = tbuf + (size_t)e * NTOK * NHID;
  const f16* Bw = wf + OFF_FR2 + (size_t)e * 288 * NHID;
  int t = threadIdx.x;
  int wv = t >> 6, lane = t & 63, m16 = lane & 15, quad = lane >> 4;
  int r0 = t >> 3, ak = (t & 7) * 8;
  const f16* ar0 = A + (size_t)(mt * 64 + r0) * NHID;
  const f16* ar1 = A + (size_t)(mt * 64 + r0 + 32) * NHID;
  int ne0 = min(nt * 64 + r0, 287), ne1 = min(nt * 64 + r0 + 32, 287);
  const f16* br0 = Bw + (size_t)ne0 * NHID;
  const f16* br1 = Bw + (size_t)ne1 * NHID;
  __shared__ f16 As[64 * 72];
  __shared__ f16 Bs[64 * 72];
  f32x4 zf = {0.f, 0.f, 0.f, 0.f};
  f32x4 acc[2][2] = {{zf, zf}, {zf, zf}};
  uint4 ra0, ra1, rb0, rb1;
  ra0 = *(const uint4*)(ar0 + ak);
  ra1 = *(const uint4*)(ar1 + ak);
  rb0 = *(const uint4*)(br0 + ak);
  rb1 = *(const uint4*)(br1 + ak);
  for (int kc = 0; kc < NHID; kc += 64) {
    __syncthreads();
    *(uint4*)&As[r0 * 72 + ak] = ra0;
    *(uint4*)&As[(r0 + 32) * 72 + ak] = ra1;
    *(uint4*)&Bs[r0 * 72 + ak] = rb0;
    *(uint4*)&Bs[(r0 + 32) * 72 + ak] = rb1;
    __syncthreads();
    int kn = kc + 64;
    if (kn < NHID) {
      ra0 = *(const uint4*)(ar0 + kn + ak);
      ra1 = *(const uint4*)(ar1 + kn + ak);
      rb0 = *(const uint4*)(br0 + kn + ak);
      rb1 = *(const uint4*)(br1 + kn + ak);
    }
#pragma unroll
    for (int ks = 0; ks < 2; ++ks) {
      int aoff = ((wv & 1) * 32 + m16) * 72 + ks * 32 + quad * 8;
      int boff = ((wv >> 1) * 32 + m16) * 72 + ks * 32 + quad * 8;
      f16x8 a0 = *(const f16x8*)&As[aoff];
      f16x8 a1 = *(const f16x8*)&As[aoff + 16 * 72];
      f16x8 b0 = *(const f16x8*)&Bs[boff];
      f16x8 b1 = *(const f16x8*)&Bs[boff + 16 * 72];
      acc[0][0] = MFMA16(a0, b0, acc[0][0]);
      acc[0][1] = MFMA16(a0, b1, acc[0][1]);
      acc[1][0] = MFMA16(a1, b0, acc[1][0]);
      acc[1][1] = MFMA16(a1, b1, acc[1][1]);
    }
  }
#pragma unroll
  for (int mi = 0; mi < 2; ++mi)
#pragma unroll
    for (int ni = 0; ni < 2; ++ni)
#pragma unroll
      for (int r = 0; r < 4; ++r) {
        int cg = nt * 64 + (wv >> 1) * 32 + ni * 16 + m16;
        if (cg < 288) {
          int row = mt * 64 + (wv & 1) * 32 + mi * 16 + quad * 4 + r;
          zz[(size_t)row * NDIM + e * 288 + cg] = acc[mi][ni][r];
        }
      }
}

// ---------------- host ----------------
extern "C" void kernel_launch(void* const* d_in, const int* in_sizes, int n_in,
                              void* d_out, int out_size, void* d_ws, size_t ws_size,
                              hipStream_t stream) {
  const float* x          = (const float*)d_in[0];
  const float* timep      = (const float*)d_in[1];
  const float* caption    = (const float*)d_in[2];
  const float* acoustic   = (const float*)d_in[3];
  const float* attn_in_w  = (const float*)d_in[4];
  const float* attn_in_b  = (const float*)d_in[5];
  const float* attn_out_w = (const float*)d_in[6];
  const float* attn_out_b = (const float*)d_in[7];
  const float* hl_w       = (const float*)d_in[8];
  const float* hl_b       = (const float*)d_in[9];
  const float* cap_gate_w = (const float*)d_in[10];
  const float* cap_gate_b = (const float*)d_in[11];
  const float* ac_gate_w  = (const float*)d_in[12];
  const float* ac_gate_b  = (const float*)d_in[13];
  const float* cap_w1     = (const float*)d_in[14];
  const float* cap_w2     = (const float*)d_in[15];
  const float* cap_w3     = (const float*)d_in[16];
  const float* ac_w1      = (const float*)d_in[17];
  const float* ac_w2      = (const float*)d_in[18];
  const float* ac_w3      = (const float*)d_in[19];
  const float* fr_w1      = (const float*)d_in[20];
  const float* fr_w2      = (const float*)d_in[21];
  const float* fr_w3      = (const float*)d_in[22];
  (void)in_sizes; (void)n_in; (void)out_size; (void)ws_size;

  float* zout = (float*)d_out;
  float* loss = zout + (size_t)NTOK * NDIM;

  char* wsb = (char*)d_ws;
  size_t off = 0;
  auto alloc = [&](size_t bytes) -> void* {
    void* p = wsb + off;
    off = (off + bytes + 255) & ~(size_t)255;
    return p;
  };
  // persistent small + xhi + converted weights
  float* g1     = (float*)alloc(4096 * 4);
  float* g2     = (float*)alloc(8192 * 4);
  float* g3     = (float*)alloc(8192 * 4);
  float* tl     = (float*)alloc(4 * 4);
  float* al     = (float*)alloc((size_t)NTOK * NEXP * 4);
  float* cl     = (float*)alloc((size_t)NTOK * NEXP * 4);
  float* cmv    = (float*)alloc((size_t)NTOK * 4);
  float* amv    = (float*)alloc((size_t)NTOK * 4);
  int*   lists  = (int*)alloc((size_t)8 * NTOK * 4);
  int*   counts = (int*)alloc(8 * 4);
  float* wp     = (float*)alloc((size_t)NEXP * NDIM * 4);
  float* bp     = (float*)alloc(NEXP * 4);
  f16*   xhi    = (f16*)alloc((size_t)NTOK * NDIM * 2);
  f16*   wf16   = (f16*)alloc((size_t)(6 * WSZ + 3 * WQ) * 2);
  size_t region = off;
  // phase 1 (attention / routing inputs)
  f16*   xlo    = (f16*)alloc((size_t)NTOK * NDIM * 2);
  f16*   caphi  = (f16*)alloc((size_t)NCAP * NDIM * 2);
  f16*   caplo  = (f16*)alloc((size_t)NCAP * NDIM * 2);
  f16*   qhi    = (f16*)alloc((size_t)NTOK * NDIM * 2);
  f16*   qlo    = (f16*)alloc((size_t)NTOK * NDIM * 2);
  f16*   khi    = (f16*)alloc((size_t)NCAP * NDIM * 2);
  f16*   klo    = (f16*)alloc((size_t)NCAP * NDIM * 2);
  f16*   vthi   = (f16*)alloc((size_t)NB * NDIM * NSC * 2);
  f16*   vtlo   = (f16*)alloc((size_t)NB * NDIM * NSC * 2);
  f16*   ohi    = (f16*)alloc((size_t)NTOK * NDIM * 2);
  f16*   olo    = (f16*)alloc((size_t)NTOK * NDIM * 2);
  f16*   inwhi  = (f16*)alloc((size_t)3 * NDIM * NDIM * 2);
  f16*   inwlo  = (f16*)alloc((size_t)3 * NDIM * NDIM * 2);
  // phase 2 (MoE / fr) — reuses phase-1 region (all phase-1 buffers dead)
  off = region;
  f16*   tbuf   = (f16*)alloc((size_t)8 * NTOK * NHID * 2);
  float* ybc    = (float*)alloc((size_t)NTOK * NDIM * 4);
  float* yba    = (float*)alloc((size_t)NTOK * NDIM * 4);

  // single merged preprocessing launch
  k_pre<<<dim3(PRE_NB), dim3(256), 0, stream>>>(
      x, caption, attn_in_w, timep, hl_w, hl_b,
      acoustic, ac_gate_w, ac_gate_b,
      attn_out_w, attn_out_b, cap_gate_w, cap_gate_b,
      xhi, xlo, caphi, caplo, inwhi, inwlo,
      g1, g2, g3, tl, al, wp, bp);
  // fused: QKV projection (z<3, f16 B) + grid-stride cvt of slots 0-3 (z=3,4)
  k_gemm_qkv<<<dim3(18, 32, 5), dim3(256), 0, stream>>>(
      xhi, xlo, caphi, caplo, inwhi, inwlo, attn_in_b,
      qhi, qlo, khi, klo, vthi, vtlo,
      cap_w1, cap_w3, ac_w1, ac_w3, wf16);
  k_attn<<<dim3(16, 16), dim3(256), 0, stream>>>(qhi, qlo, khi, klo, vthi, vtlo, ohi, olo);
  k_o_logits<<<dim3(512), dim3(256), 0, stream>>>(ohi, olo, wp, bp, cl);
  k_route<<<dim3(1), dim3(1024), 0, stream>>>(cl, al, g1, g2, g3, tl,
                                              cmv, amv, lists, counts, loss);
  // gemm1 MoE pass (8 groups) + tail cvt blocks (cap_w2/ac_w2 full + fr compacts)
  k_gemm1<<<dim3(3666), dim3(256), 0, stream>>>(xhi, wf16, lists, counts, tbuf,
                                                fr_w1, fr_w3, cap_w2, ac_w2, fr_w2);
  k_gemm2<<<dim3(4608), dim3(256), 0, stream>>>(tbuf, wf16, lists, counts,
                                                cmv, amv, ybc, yba);
  k_gemm1_fr<<<dim3(12, 32, 4), dim3(256), 0, stream>>>(ybc, yba, wf16, tbuf);
  k_gemm2_fr<<<dim3(5, 32, 4), dim3(256), 0, stream>>>(tbuf, wf16, zout);
}

// Round 10
// 425.181 us; speedup vs baseline: 1.3689x; 1.0154x over previous
//
#include <hip/hip_runtime.h>
#include <stdint.h>

#define NDIM 1152
#define NEXP 4
#define NHID 768
#define NHEAD 8
#define HDIM 144
#define NB 2
#define NS 1024
#define NSC 128
#define NTOK 2048
#define NCAP 256

typedef _Float16 f16;
typedef _Float16 f16x4 __attribute__((ext_vector_type(4)));
typedef _Float16 f16x8 __attribute__((ext_vector_type(8)));
typedef float f32x4 __attribute__((ext_vector_type(4)));

#define MFMA16(a, b, c) __builtin_amdgcn_mfma_f32_16x16x32_f16(a, b, c, 0, 0, 0)

#define WSZ ((size_t)NEXP * NHID * NDIM)  // elems per full weight tensor (3,538,944)
#define WQ  ((size_t)(WSZ / 4))           // compact fr tensor elems (884,736)
#define OFF_CW2 ((size_t)4 * WSZ)
#define OFF_AW2 ((size_t)5 * WSZ)
#define OFF_FR1 ((size_t)6 * WSZ)
#define OFF_FR3 ((size_t)6 * WSZ + WQ)
#define OFF_FR2 ((size_t)6 * WSZ + 2 * WQ)

// k_pre block ranges
#define PRE_XB   2304                     // x split (4/thread)
#define PRE_CB   288                      // caption split
#define PRE_IWB  1944                     // attn_in_w split (8/thread)
#define PRE_X0   0
#define PRE_C0   (PRE_XB)
#define PRE_IW0  (PRE_C0 + PRE_CB)
#define PRE_GUM  (PRE_IW0 + PRE_IWB)      // 4536
#define PRE_FG0  (PRE_GUM + 1)            // 4537 .. 4555 (18 col blocks + 1 bias)
#define PRE_AL0  (PRE_FG0 + 19)           // 4556
#define PRE_NB   (PRE_AL0 + 512)          // 5068

// ---------------- Threefry2x32 (exact JAX replication) ----------------
__device__ inline uint2 tfry(uint32_t k0, uint32_t k1, uint32_t x0, uint32_t x1) {
  uint32_t k2 = k0 ^ k1 ^ 0x1BD11BDAu;
#define RND(r) { x0 += x1; x1 = (x1 << r) | (x1 >> (32 - r)); x1 ^= x0; }
  x0 += k0; x1 += k1;
  RND(13) RND(15) RND(26) RND(6)
  x0 += k1; x1 += k2 + 1u;
  RND(17) RND(29) RND(16) RND(24)
  x0 += k2; x1 += k0 + 2u;
  RND(13) RND(15) RND(26) RND(6)
  x0 += k0; x1 += k1 + 3u;
  RND(17) RND(29) RND(16) RND(24)
  x0 += k1; x1 += k2 + 4u;
  RND(13) RND(15) RND(26) RND(6)
  x0 += k2; x1 += k0 + 5u;
#undef RND
  return make_uint2(x0, x1);
}

__device__ inline float b2g(uint32_t bits) {
  uint32_t fb = (bits >> 9) | 0x3f800000u;
  float f = __uint_as_float(fb) - 1.0f;
  const float tiny = 1.1754943508222875e-38f;
  float u = f * 1.0f + tiny;
  u = fmaxf(tiny, u);
  return -logf(-logf(u));
}

// ---------------- k_pre: all preprocessing in one launch ----------------
__global__ __launch_bounds__(256) void k_pre(
    const float* __restrict__ x, const float* __restrict__ caption,
    const float* __restrict__ inw,
    const float* __restrict__ timep, const float* __restrict__ hlw,
    const float* __restrict__ hlb,
    const float* __restrict__ acous, const float* __restrict__ agw,
    const float* __restrict__ agb,
    const float* __restrict__ ow, const float* __restrict__ ob,
    const float* __restrict__ gw, const float* __restrict__ gb,
    f16* __restrict__ xhi, f16* __restrict__ xlo,
    f16* __restrict__ caphi, f16* __restrict__ caplo,
    f16* __restrict__ inwhi, f16* __restrict__ inwlo,
    float* __restrict__ g1, float* __restrict__ g2, float* __restrict__ g3,
    float* __restrict__ tl, float* __restrict__ al,
    float* __restrict__ wp, float* __restrict__ bp) {
  __shared__ float sm[4][4][64];
  int bid = blockIdx.x;
  int t = threadIdx.x;
  if (bid < PRE_C0) {
    int i = bid * 1024 + t * 4;
    float4 v = *(const float4*)(x + i);
    f16x4 h, l;
    h[0] = (f16)v.x; l[0] = (f16)((v.x - (float)h[0]) * 2048.f);
    h[1] = (f16)v.y; l[1] = (f16)((v.y - (float)h[1]) * 2048.f);
    h[2] = (f16)v.z; l[2] = (f16)((v.z - (float)h[2]) * 2048.f);
    h[3] = (f16)v.w; l[3] = (f16)((v.w - (float)h[3]) * 2048.f);
    *(f16x4*)(xhi + i) = h;
    *(f16x4*)(xlo + i) = l;
    return;
  }
  if (bid < PRE_IW0) {
    int i = (bid - PRE_C0) * 1024 + t * 4;
    float4 v = *(const float4*)(caption + i);
    f16x4 h, l;
    h[0] = (f16)v.x; l[0] = (f16)((v.x - (float)h[0]) * 2048.f);
    h[1] = (f16)v.y; l[1] = (f16)((v.y - (float)h[1]) * 2048.f);
    h[2] = (f16)v.z; l[2] = (f16)((v.z - (float)h[2]) * 2048.f);
    h[3] = (f16)v.w; l[3] = (f16)((v.w - (float)h[3]) * 2048.f);
    *(f16x4*)(caphi + i) = h;
    *(f16x4*)(caplo + i) = l;
    return;
  }
  if (bid < PRE_GUM) {
    size_t i = (size_t)(bid - PRE_IW0) * 2048 + (size_t)t * 8;
    float4 v0 = *(const float4*)(inw + i);
    float4 v1 = *(const float4*)(inw + i + 4);
    f16x8 h, l;
    h[0] = (f16)v0.x; l[0] = (f16)((v0.x - (float)h[0]) * 2048.f);
    h[1] = (f16)v0.y; l[1] = (f16)((v0.y - (float)h[1]) * 2048.f);
    h[2] = (f16)v0.z; l[2] = (f16)((v0.z - (float)h[2]) * 2048.f);
    h[3] = (f16)v0.w; l[3] = (f16)((v0.w - (float)h[3]) * 2048.f);
    h[4] = (f16)v1.x; l[4] = (f16)((v1.x - (float)h[4]) * 2048.f);
    h[5] = (f16)v1.y; l[5] = (f16)((v1.y - (float)h[5]) * 2048.f);
    h[6] = (f16)v1.z; l[6] = (f16)((v1.z - (float)h[6]) * 2048.f);
    h[7] = (f16)v1.w; l[7] = (f16)((v1.w - (float)h[7]) * 2048.f);
    *(f16x8*)(inwhi + i) = h;
    *(f16x8*)(inwlo + i) = l;
    return;
  }
  if (bid == PRE_GUM) {
    uint2 k1 = tfry(0u, 42u, 0u, 0u);
    uint2 k2 = tfry(0u, 42u, 0u, 1u);
    uint2 k3 = tfry(0u, 42u, 0u, 2u);
    for (int p = t; p < 4096; p += 256) {
      uint2 o = tfry(k1.x, k1.y, 0u, (uint32_t)p);
      g1[p] = b2g(o.x ^ o.y);
    }
    for (int p = t; p < 8192; p += 256) {
      uint2 o2 = tfry(k2.x, k2.y, 0u, (uint32_t)p);
      g2[p] = b2g(o2.x ^ o2.y);
      uint2 o3 = tfry(k3.x, k3.y, 0u, (uint32_t)p);
      g3[p] = b2g(o3.x ^ o3.y);
    }
    int wv = t >> 6, lane = t & 63;
    int b = wv >> 1, j = wv & 1;
    float s = 0.f;
    for (int k = lane; k < NDIM; k += 64) s += timep[b * NDIM + k] * hlw[j * NDIM + k];
    for (int m = 32; m; m >>= 1) s += __shfl_xor(s, m);
    if (lane == 0) tl[b * 2 + j] = s + hlb[j];
    return;
  }
  if (bid < PRE_AL0) {
    int blk = bid - PRE_FG0;
    if (blk == 18) {
      int wv = t >> 6, lane = t & 63;  // wv = e
      float s = 0.f;
      for (int d = lane; d < NDIM; d += 64) s += ob[d] * gw[wv * NDIM + d];
      for (int m = 32; m; m >>= 1) s += __shfl_xor(s, m);
      if (lane == 0) bp[wv] = s + gb[wv];
      return;
    }
    int j = t & 63, w = t >> 6;
    int k = blk * 64 + j;
    float a0 = 0.f, a1 = 0.f, a2 = 0.f, a3 = 0.f;
#pragma unroll 4
    for (int d = w * 288; d < (w + 1) * 288; ++d) {
      float o = ow[(size_t)d * NDIM + k];
      a0 += gw[d] * o;
      a1 += gw[NDIM + d] * o;
      a2 += gw[2 * NDIM + d] * o;
      a3 += gw[3 * NDIM + d] * o;
    }
    sm[w][0][j] = a0; sm[w][1][j] = a1; sm[w][2][j] = a2; sm[w][3][j] = a3;
    __syncthreads();
    if (w == 0) {
#pragma unroll
      for (int e = 0; e < 4; ++e)
        wp[e * NDIM + k] = sm[0][e][j] + sm[1][e][j] + sm[2][e][j] + sm[3][e][j];
    }
    return;
  }
  {
    int wv = t >> 6, lane = t & 63;
    int n = (bid - PRE_AL0) * 4 + wv;
    float s[NEXP] = {0.f, 0.f, 0.f, 0.f};
    for (int d = lane; d < NDIM; d += 64) {
      float a = acous[(size_t)n * NDIM + d];
#pragma unroll
      for (int e = 0; e < NEXP; ++e) s[e] += a * agw[e * NDIM + d];
    }
#pragma unroll
    for (int e = 0; e < NEXP; ++e)
      for (int m = 32; m; m >>= 1) s[e] += __shfl_xor(s[e], m);
    if (lane == 0) {
#pragma unroll
      for (int e = 0; e < NEXP; ++e) al[n * NEXP + e] = s[e] + agb[e];
    }
  }
}

// ---------------- cap logits from split-f16 o: cl[n,e] = o[n,:]·W'[e,:] + b'[e] -------
__global__ void k_o_logits(const f16* __restrict__ ohi, const f16* __restrict__ olo,
                           const float* __restrict__ wp, const float* __restrict__ bp,
                           float* __restrict__ cl) {
  int wv = threadIdx.x >> 6, lane = threadIdx.x & 63;
  int n = blockIdx.x * 4 + wv;
  float s[NEXP] = {0.f, 0.f, 0.f, 0.f};
  for (int d = lane; d < NDIM; d += 64) {
    size_t gi = (size_t)n * NDIM + d;
    float a = (float)ohi[gi] + (float)olo[gi] * (1.f / 2048.f);
#pragma unroll
    for (int e = 0; e < NEXP; ++e) s[e] += a * wp[e * NDIM + d];
  }
#pragma unroll
  for (int e = 0; e < NEXP; ++e)
    for (int m = 32; m; m >>= 1) s[e] += __shfl_xor(s[e], m);
  if (lane == 0) {
#pragma unroll
    for (int e = 0; e < NEXP; ++e) cl[n * NEXP + e] = s[e] + bp[e];
  }
}

// ---------------- QKV projection (all-f16 staging), pure GEMM ----------------
__global__ __launch_bounds__(256) void k_gemm_qkv(
    const f16* __restrict__ xhi, const f16* __restrict__ xlo,
    const f16* __restrict__ caphi, const f16* __restrict__ caplo,
    const f16* __restrict__ inwhi, const f16* __restrict__ inwlo,
    const float* __restrict__ inb,
    f16* __restrict__ qhi, f16* __restrict__ qlo,
    f16* __restrict__ khi, f16* __restrict__ klo,
    f16* __restrict__ vthi, f16* __restrict__ vtlo) {
  int z = blockIdx.z;
  int M = (z == 0) ? NTOK : NCAP;
  int mt = blockIdx.y, nt = blockIdx.x;
  if (mt * 64 >= M) return;
  const f16* Ah_g = (z == 0) ? xhi : caphi;
  const f16* Al_g = (z == 0) ? xlo : caplo;
  __shared__ f16 Ash[64 * 72];
  __shared__ f16 Asl[64 * 72];
  __shared__ f16 Bsh[64 * 72];
  __shared__ f16 Bsl[64 * 72];
  int t = threadIdx.x;
  int wv = t >> 6, lane = t & 63, m16 = lane & 15, quad = lane >> 4;
  int r0 = t >> 3, ak = (t & 7) * 8;
  size_t a0o = (size_t)(mt * 64 + r0) * NDIM;
  size_t a1o = (size_t)(mt * 64 + r0 + 32) * NDIM;
  const f16* bh0 = inwhi + (size_t)(z * NDIM + nt * 64 + r0) * NDIM;
  const f16* bh1 = bh0 + (size_t)32 * NDIM;
  const f16* bl0 = inwlo + (size_t)(z * NDIM + nt * 64 + r0) * NDIM;
  const f16* bl1 = bl0 + (size_t)32 * NDIM;
  f32x4 zf = {0.f, 0.f, 0.f, 0.f};
  f32x4 ah[2][2] = {{zf, zf}, {zf, zf}};
  f32x4 am[2][2] = {{zf, zf}, {zf, zf}};
  uint4 rah0, rah1, ral0, ral1, rbh0, rbh1, rbl0, rbl1;
  rah0 = *(const uint4*)(Ah_g + a0o + ak);
  rah1 = *(const uint4*)(Ah_g + a1o + ak);
  ral0 = *(const uint4*)(Al_g + a0o + ak);
  ral1 = *(const uint4*)(Al_g + a1o + ak);
  rbh0 = *(const uint4*)(bh0 + ak);
  rbh1 = *(const uint4*)(bh1 + ak);
  rbl0 = *(const uint4*)(bl0 + ak);
  rbl1 = *(const uint4*)(bl1 + ak);
  for (int kc = 0; kc < NDIM; kc += 64) {
    __syncthreads();
    *(uint4*)&Ash[r0 * 72 + ak] = rah0;
    *(uint4*)&Ash[(r0 + 32) * 72 + ak] = rah1;
    *(uint4*)&Asl[r0 * 72 + ak] = ral0;
    *(uint4*)&Asl[(r0 + 32) * 72 + ak] = ral1;
    *(uint4*)&Bsh[r0 * 72 + ak] = rbh0;
    *(uint4*)&Bsh[(r0 + 32) * 72 + ak] = rbh1;
    *(uint4*)&Bsl[r0 * 72 + ak] = rbl0;
    *(uint4*)&Bsl[(r0 + 32) * 72 + ak] = rbl1;
    __syncthreads();
    int kn = kc + 64;
    if (kn < NDIM) {
      rah0 = *(const uint4*)(Ah_g + a0o + kn + ak);
      rah1 = *(const uint4*)(Ah_g + a1o + kn + ak);
      ral0 = *(const uint4*)(Al_g + a0o + kn + ak);
      ral1 = *(const uint4*)(Al_g + a1o + kn + ak);
      rbh0 = *(const uint4*)(bh0 + kn + ak);
      rbh1 = *(const uint4*)(bh1 + kn + ak);
      rbl0 = *(const uint4*)(bl0 + kn + ak);
      rbl1 = *(const uint4*)(bl1 + kn + ak);
    }
#pragma unroll
    for (int ks = 0; ks < 2; ++ks) {
      int aoff = ((wv & 1) * 32 + m16) * 72 + ks * 32 + quad * 8;
      int boff = ((wv >> 1) * 32 + m16) * 72 + ks * 32 + quad * 8;
      f16x8 a0h = *(const f16x8*)&Ash[aoff];
      f16x8 a1h = *(const f16x8*)&Ash[aoff + 16 * 72];
      f16x8 a0l = *(const f16x8*)&Asl[aoff];
      f16x8 a1l = *(const f16x8*)&Asl[aoff + 16 * 72];
      f16x8 b0h = *(const f16x8*)&Bsh[boff];
      f16x8 b1h = *(const f16x8*)&Bsh[boff + 16 * 72];
      f16x8 b0l = *(const f16x8*)&Bsl[boff];
      f16x8 b1l = *(const f16x8*)&Bsl[boff + 16 * 72];
      ah[0][0] = MFMA16(a0h, b0h, ah[0][0]);
      ah[0][1] = MFMA16(a0h, b1h, ah[0][1]);
      ah[1][0] = MFMA16(a1h, b0h, ah[1][0]);
      ah[1][1] = MFMA16(a1h, b1h, ah[1][1]);
      am[0][0] = MFMA16(a0h, b0l, am[0][0]);
      am[0][1] = MFMA16(a0h, b1l, am[0][1]);
      am[1][0] = MFMA16(a1h, b0l, am[1][0]);
      am[1][1] = MFMA16(a1h, b1l, am[1][1]);
      am[0][0] = MFMA16(a0l, b0h, am[0][0]);
      am[0][1] = MFMA16(a0l, b1h, am[0][1]);
      am[1][0] = MFMA16(a1l, b0h, am[1][0]);
      am[1][1] = MFMA16(a1l, b1h, am[1][1]);
    }
  }
#pragma unroll
  for (int mi = 0; mi < 2; ++mi)
#pragma unroll
    for (int ni = 0; ni < 2; ++ni)
#pragma unroll
      for (int r = 0; r < 4; ++r) {
        int row = mt * 64 + (wv & 1) * 32 + mi * 16 + quad * 4 + r;
        int col = nt * 64 + (wv >> 1) * 32 + ni * 16 + m16;
        float v = ah[mi][ni][r] + am[mi][ni][r] * (1.f / 2048.f) + inb[z * NDIM + col];
        size_t idx = (size_t)row * NDIM + col;
        if (z == 0) {
          f16 hq = (f16)v;
          qhi[idx] = hq;
          qlo[idx] = (f16)((v - (float)hq) * 2048.f);
        } else if (z == 1) {
          f16 hk = (f16)v;
          khi[idx] = hk;
          klo[idx] = (f16)((v - (float)hk) * 2048.f);
        } else {
          f16 hv = (f16)v;
          int bb = row >> 7, kv = row & 127;
          size_t ti = (size_t)(bb * NDIM + col) * NSC + kv;
          vthi[ti] = hv;
          vtlo[ti] = (f16)((v - (float)hv) * 2048.f);
        }
      }
}

// ---------------- fused attention: QK^T + softmax + PV, split-fp16, writes o hi/lo ----
__global__ __launch_bounds__(256) void k_attn(
    const f16* __restrict__ qhi, const f16* __restrict__ qlo,
    const f16* __restrict__ khi, const f16* __restrict__ klo,
    const f16* __restrict__ vthi, const f16* __restrict__ vtlo,
    f16* __restrict__ ohi, f16* __restrict__ olo) {
  int mt = blockIdx.x, bh = blockIdx.y;
  int b = bh >> 3, h = bh & 7;
  __shared__ f16 Ah[64 * 160];
  __shared__ f16 Al[64 * 160];
  __shared__ f16 Bh[32 * 160];
  __shared__ f16 Bl[32 * 160];
  __shared__ f16 Ph[64 * 136];
  __shared__ f16 Pl[64 * 136];
  int t = threadIdx.x;
  int wv = t >> 6, lane = t & 63, m16 = lane & 15, quad = lane >> 4;
  for (int u = t; u < 64 * 20; u += 256) {
    int r = u / 20, kp = (u % 20) * 8;
    uint4 vh = make_uint4(0u, 0u, 0u, 0u), vl = vh;
    if (kp < HDIM) {
      size_t gi = (size_t)(b * NS + mt * 64 + r) * NDIM + h * HDIM + kp;
      vh = *(const uint4*)&qhi[gi];
      vl = *(const uint4*)&qlo[gi];
    }
    *(uint4*)&Ah[r * 160 + kp] = vh;
    *(uint4*)&Al[r * 160 + kp] = vl;
  }
  __syncthreads();
  f16x8 ahf[5], alf[5];
#pragma unroll
  for (int ks = 0; ks < 5; ++ks) {
    int ao = (wv * 16 + m16) * 160 + ks * 32 + quad * 8;
    ahf[ks] = *(const f16x8*)&Ah[ao];
    alf[ks] = *(const f16x8*)&Al[ao];
  }
  f32x4 zf = {0.f, 0.f, 0.f, 0.f};
  f32x4 sh_[4][2], sm_[4][2];
#pragma unroll
  for (int kt = 0; kt < 4; ++kt)
#pragma unroll
    for (int ni = 0; ni < 2; ++ni) { sh_[kt][ni] = zf; sm_[kt][ni] = zf; }
  for (int kt = 0; kt < 4; ++kt) {
    if (kt) __syncthreads();
    for (int u = t; u < 32 * 20; u += 256) {
      int r = u / 20, kp = (u % 20) * 8;
      uint4 vh = make_uint4(0u, 0u, 0u, 0u), vl = vh;
      if (kp < HDIM) {
        size_t gi = (size_t)(b * NSC + kt * 32 + r) * NDIM + h * HDIM + kp;
        vh = *(const uint4*)&khi[gi];
        vl = *(const uint4*)&klo[gi];
      }
      *(uint4*)&Bh[r * 160 + kp] = vh;
      *(uint4*)&Bl[r * 160 + kp] = vl;
    }
    __syncthreads();
#pragma unroll
    for (int ks = 0; ks < 5; ++ks) {
#pragma unroll
      for (int ni = 0; ni < 2; ++ni) {
        int bo = (ni * 16 + m16) * 160 + ks * 32 + quad * 8;
        f16x8 bhf = *(const f16x8*)&Bh[bo];
        f16x8 blf = *(const f16x8*)&Bl[bo];
        sh_[kt][ni] = MFMA16(ahf[ks], bhf, sh_[kt][ni]);
        sm_[kt][ni] = MFMA16(ahf[ks], blf, sm_[kt][ni]);
        sm_[kt][ni] = MFMA16(alf[ks], bhf, sm_[kt][ni]);
      }
    }
  }
  float sv[4][2][4];
  float mx[4] = {-1e30f, -1e30f, -1e30f, -1e30f};
#pragma unroll
  for (int kt = 0; kt < 4; ++kt)
#pragma unroll
    for (int ni = 0; ni < 2; ++ni)
#pragma unroll
      for (int r = 0; r < 4; ++r) {
        float s = (sh_[kt][ni][r] + sm_[kt][ni][r] * (1.f / 2048.f)) * (1.f / 12.f);
        sv[kt][ni][r] = s;
        mx[r] = fmaxf(mx[r], s);
      }
#pragma unroll
  for (int r = 0; r < 4; ++r) {
    mx[r] = fmaxf(mx[r], __shfl_xor(mx[r], 1));
    mx[r] = fmaxf(mx[r], __shfl_xor(mx[r], 2));
    mx[r] = fmaxf(mx[r], __shfl_xor(mx[r], 4));
    mx[r] = fmaxf(mx[r], __shfl_xor(mx[r], 8));
  }
  float sum[4] = {0.f, 0.f, 0.f, 0.f};
#pragma unroll
  for (int kt = 0; kt < 4; ++kt)
#pragma unroll
    for (int ni = 0; ni < 2; ++ni)
#pragma unroll
      for (int r = 0; r < 4; ++r) {
        float e = expf(sv[kt][ni][r] - mx[r]);
        sv[kt][ni][r] = e;
        sum[r] += e;
      }
  float inv[4];
#pragma unroll
  for (int r = 0; r < 4; ++r) {
    sum[r] += __shfl_xor(sum[r], 1);
    sum[r] += __shfl_xor(sum[r], 2);
    sum[r] += __shfl_xor(sum[r], 4);
    sum[r] += __shfl_xor(sum[r], 8);
    inv[r] = 1.0f / sum[r];
  }
#pragma unroll
  for (int kt = 0; kt < 4; ++kt)
#pragma unroll
    for (int ni = 0; ni < 2; ++ni)
#pragma unroll
      for (int r = 0; r < 4; ++r) {
        float p = sv[kt][ni][r] * inv[r];
        int row = wv * 16 + quad * 4 + r;
        int col = kt * 32 + ni * 16 + m16;
        f16 ph = (f16)p;
        Ph[row * 136 + col] = ph;
        Pl[row * 136 + col] = (f16)((p - (float)ph) * 2048.f);
      }
  const f16* vbh = vthi + (size_t)(b * NDIM + h * HDIM) * NSC;
  const f16* vbl = vtlo + (size_t)(b * NDIM + h * HDIM) * NSC;
  f32x4 oh_[9], om_[9];
#pragma unroll
  for (int nb = 0; nb < 9; ++nb) { oh_[nb] = zf; om_[nb] = zf; }
#pragma unroll
  for (int ks = 0; ks < 4; ++ks) {
    int po = (wv * 16 + m16) * 136 + ks * 32 + quad * 8;
    f16x8 pah = *(const f16x8*)&Ph[po];
    f16x8 pal = *(const f16x8*)&Pl[po];
#pragma unroll
    for (int nb = 0; nb < 9; ++nb) {
      size_t vo = (size_t)(nb * 16 + m16) * NSC + ks * 32 + quad * 8;
      f16x8 bvh = *(const f16x8*)&vbh[vo];
      f16x8 bvl = *(const f16x8*)&vbl[vo];
      oh_[nb] = MFMA16(pah, bvh, oh_[nb]);
      om_[nb] = MFMA16(pah, bvl, om_[nb]);
      om_[nb] = MFMA16(pal, bvh, om_[nb]);
    }
  }
#pragma unroll
  for (int nb = 0; nb < 9; ++nb)
#pragma unroll
    for (int r = 0; r < 4; ++r) {
      int row = mt * 64 + wv * 16 + quad * 4 + r;
      int col = h * HDIM + nb * 16 + m16;
      float v = oh_[nb][r] + om_[nb][r] * (1.f / 2048.f);
      size_t idx = (size_t)(b * NS + row) * NDIM + col;
      f16 hv = (f16)v;
      ohi[idx] = hv;
      olo[idx] = (f16)((v - (float)hv) * 2048.f);
    }
}

// ---------------- routing + hosted weight cvt (slots 0-3) ----------------
// bid==0: argmax gates, cm/am, lists, loss (1024 thr).
// bid>=1: grid-stride f32->f16 of cap_w1/cap_w3/ac_w1/ac_w3 (8192 elems/block).
__global__ __launch_bounds__(1024) void k_route(
    const float* __restrict__ cl, const float* __restrict__ al,
    const float* __restrict__ g1, const float* __restrict__ g2,
    const float* __restrict__ g3, const float* __restrict__ tl,
    float* __restrict__ cmv, float* __restrict__ amv,
    int* __restrict__ lists, int* __restrict__ counts, float* __restrict__ out_loss,
    const float* __restrict__ w0, const float* __restrict__ w1,
    const float* __restrict__ w2, const float* __restrict__ w3,
    f16* __restrict__ wf16) {
  int t = threadIdx.x;
  if (blockIdx.x >= 1) {
    // 4*WSZ elems over 1728 blocks -> 8192 elems/block (8192 | WSZ)
    size_t c0 = (size_t)(blockIdx.x - 1) * 8192;
    int slot = (int)(c0 / WSZ);               // block-uniform
    size_t base = (c0 % WSZ) + (size_t)t * 8;
    const float* s = ((slot == 0) ? w0 : (slot == 1) ? w1 : (slot == 2) ? w2 : w3) + base;
    float4 v0 = *(const float4*)(s);
    float4 v1 = *(const float4*)(s + 4);
    f16x8 h;
    h[0] = (f16)v0.x; h[1] = (f16)v0.y; h[2] = (f16)v0.z; h[3] = (f16)v0.w;
    h[4] = (f16)v1.x; h[5] = (f16)v1.y; h[6] = (f16)v1.z; h[7] = (f16)v1.w;
    *(f16x8*)(wf16 + (size_t)slot * WSZ + base) = h;
    return;
  }
  __shared__ int lcnt[8];
  __shared__ float bins[8];
  __shared__ float ssum[2];
  if (t < 8) { lcnt[t] = 0; bins[t] = 0.f; }
  if (t < 2) ssum[t] = 0.f;
  __syncthreads();
  for (int n = t; n < NTOK; n += 1024) {
    float lc[NEXP];
#pragma unroll
    for (int e = 0; e < NEXP; ++e) lc[e] = cl[n * NEXP + e] + g2[n * 4 + e];
    int ec = 0; float bv = lc[0];
#pragma unroll
    for (int e = 1; e < NEXP; ++e) if (lc[e] > bv) { bv = lc[e]; ec = e; }
    float la[NEXP];
#pragma unroll
    for (int e = 0; e < NEXP; ++e) la[e] = al[n * NEXP + e] + g3[n * 4 + e];
    int ea = 0; float bva = la[0];
#pragma unroll
    for (int e = 1; e < NEXP; ++e) if (la[e] > bva) { bva = la[e]; ea = e; }
    int b = n >> 10;
    float a0 = tl[b * 2 + 0] + g1[n * 2 + 0];
    float a1 = tl[b * 2 + 1] + g1[n * 2 + 1];
    float mx = fmaxf(a0, a1);
    float e0 = expf(a0 - mx), e1 = expf(a1 - mx);
    float cm = e0 / (e0 + e1), am = e1 / (e0 + e1);
    cmv[n] = cm; amv[n] = am;
    int p0 = atomicAdd(&lcnt[ec], 1);
    lists[ec * NTOK + p0] = n;
    int p1 = atomicAdd(&lcnt[4 + ea], 1);
    lists[(4 + ea) * NTOK + p1] = n;
    atomicAdd(&bins[ec], cm);
    atomicAdd(&bins[4 + ea], am);
    atomicAdd(&ssum[0], cm);
    atomicAdd(&ssum[1], am);
  }
  __syncthreads();
  if (t < 8) counts[t] = lcnt[t];
  if (t == 0) {
    float denom = 4.f * (ssum[0] + ssum[1]) + 1e-10f;
    float acc = 0.f;
    for (int j = 0; j < 8; ++j) {
      float u = bins[j] / denom;
      acc += u * logf(u + 1e-10f);
    }
    out_loss[0] = acc / 8.f;
  }
}

// ---------------- GEMM1 (MoE pass): M64, f16 weights, XCD remap, 2-phase --------------
// Blocks >= 3072 convert weight slots: cap_w2, ac_w2 (full), fr_w1/fr_w3/fr_w2 (compact).
__global__ __launch_bounds__(256) void k_gemm1(
    const f16* __restrict__ x16, f16* wf,
    const int* __restrict__ lists, const int* __restrict__ counts,
    f16* __restrict__ tbuf,
    const float* __restrict__ w4, const float* __restrict__ w5,
    const float* __restrict__ w6, const float* __restrict__ w7,
    const float* __restrict__ w8) {
  int bid = blockIdx.x;
  if (bid >= 3072) {
    int cvtid = bid - 3072;  // [0,594)
    int t = threadIdx.x;
    if (cvtid < 432) {
      int slot = cvtid / 216;
      size_t base = (size_t)(cvtid % 216) * 16384;
      const float* s = (slot ? w7 : w6) + base;
      f16* dst = wf + (slot ? OFF_AW2 : OFF_CW2) + base;
#pragma unroll
      for (int i = 0; i < 8; ++i) {
        size_t off = (size_t)(t + i * 256) * 8;
        float4 v0 = *(const float4*)(s + off);
        float4 v1 = *(const float4*)(s + off + 4);
        f16x8 h;
        h[0] = (f16)v0.x; h[1] = (f16)v0.y; h[2] = (f16)v0.z; h[3] = (f16)v0.w;
        h[4] = (f16)v1.x; h[5] = (f16)v1.y; h[6] = (f16)v1.z; h[7] = (f16)v1.w;
        *(f16x8*)(dst + off) = h;
      }
    } else {
      int fid = cvtid - 432;            // [0,162)
      int which = fid / 54;             // 0: fr_w1, 1: fr_w3, 2: fr_w2 (block-uniform)
      int base = (fid % 54) * 16384;
      const float* s = (which == 0) ? w4 : (which == 1) ? w5 : w8;
      f16* dst = wf + ((which == 0) ? OFF_FR1 : (which == 1) ? OFF_FR3 : OFF_FR2);
#pragma unroll
      for (int i = 0; i < 8; ++i) {
        int i0 = base + i * 2048 + t * 8;
        int e = i0 / 221184;
        int rem = i0 - e * 221184;
        size_t si;
        if (which < 2) {
          int hh = rem / 288, j = rem - (rem / 288) * 288;
          si = (size_t)e * 884736 + (size_t)hh * 1152 + e * 288 + j;
        } else {
          int rr = rem / 768, c = rem - (rem / 768) * 768;
          si = (size_t)e * 884736 + (size_t)(e * 288 + rr) * 768 + c;
        }
        float4 v0 = *(const float4*)(s + si);
        float4 v1 = *(const float4*)(s + si + 4);
        f16x8 h;
        h[0] = (f16)v0.x; h[1] = (f16)v0.y; h[2] = (f16)v0.z; h[3] = (f16)v0.w;
        h[4] = (f16)v1.x; h[5] = (f16)v1.y; h[6] = (f16)v1.z; h[7] = (f16)v1.w;
        *(f16x8*)(dst + i0) = h;
      }
    }
    return;
  }
  int xcd = bid & 7;
  int local = bid >> 3;
  int pair = xcd * 12 + (local >> 5);   // MT = 32
  int mt = local & 31;
  int g = pair / 12;
  int nt = pair % 12;
  int e = g & 3;
  int cnt = counts[g];
  if (mt * 64 >= cnt) return;
  const int* list = lists + g * NTOK;
  const f16* B1 = wf + (size_t)((g < 4) ? 0 : 2) * WSZ + (size_t)e * NHID * NDIM;
  const f16* B3 = wf + (size_t)((g < 4) ? 1 : 3) * WSZ + (size_t)e * NHID * NDIM;
  f16* tout = tbuf + (size_t)g * NTOK * NHID;
  int t = threadIdx.x;
  int wv = t >> 6, lane = t & 63, m16 = lane & 15, quad = lane >> 4;
  int r0 = t >> 3, ak = (t & 7) * 8;
  int m0 = mt * 64 + r0, m1 = m0 + 32;
  int tok0 = list[min(m0, cnt - 1)], tok1 = list[min(m1, cnt - 1)];
  const f16* ar0 = x16 + (size_t)tok0 * NDIM;
  const f16* ar1 = x16 + (size_t)tok1 * NDIM;
  const f16* b1r0 = B1 + (size_t)(nt * 64 + r0) * NDIM;
  const f16* b1r1 = B1 + (size_t)(nt * 64 + r0 + 32) * NDIM;
  const f16* b3r0 = B3 + (size_t)(nt * 64 + r0) * NDIM;
  const f16* b3r1 = B3 + (size_t)(nt * 64 + r0 + 32) * NDIM;
  __shared__ f16 As[64 * 72];
  __shared__ f16 Bs1[64 * 72];
  __shared__ f16 Bs2[64 * 72];
  f32x4 zf = {0.f, 0.f, 0.f, 0.f};
  f32x4 ac1[2][2] = {{zf, zf}, {zf, zf}};
  f32x4 ac2[2][2] = {{zf, zf}, {zf, zf}};
  uint4 ra0, ra1, rb10, rb11, rb30, rb31;
  ra0  = *(const uint4*)(ar0 + ak);
  ra1  = *(const uint4*)(ar1 + ak);
  rb10 = *(const uint4*)(b1r0 + ak);
  rb11 = *(const uint4*)(b1r1 + ak);
  rb30 = *(const uint4*)(b3r0 + ak);
  rb31 = *(const uint4*)(b3r1 + ak);
  for (int kc = 0; kc < NDIM; kc += 64) {
    __syncthreads();
    *(uint4*)&As[r0 * 72 + ak] = ra0;
    *(uint4*)&As[(r0 + 32) * 72 + ak] = ra1;
    *(uint4*)&Bs1[r0 * 72 + ak] = rb10;
    *(uint4*)&Bs1[(r0 + 32) * 72 + ak] = rb11;
    *(uint4*)&Bs2[r0 * 72 + ak] = rb30;
    *(uint4*)&Bs2[(r0 + 32) * 72 + ak] = rb31;
    __syncthreads();
    int kn = kc + 64;
    if (kn < NDIM) {
      ra0  = *(const uint4*)(ar0 + kn + ak);
      ra1  = *(const uint4*)(ar1 + kn + ak);
      rb10 = *(const uint4*)(b1r0 + kn + ak);
      rb11 = *(const uint4*)(b1r1 + kn + ak);
      rb30 = *(const uint4*)(b3r0 + kn + ak);
      rb31 = *(const uint4*)(b3r1 + kn + ak);
    }
#pragma unroll
    for (int ks = 0; ks < 2; ++ks) {
      int aoff = ((wv & 1) * 32 + m16) * 72 + ks * 32 + quad * 8;
      int boff = ((wv >> 1) * 32 + m16) * 72 + ks * 32 + quad * 8;
      f16x8 a0 = *(const f16x8*)&As[aoff];
      f16x8 a1 = *(const f16x8*)&As[aoff + 16 * 72];
      f16x8 b10 = *(const f16x8*)&Bs1[boff];
      f16x8 b11 = *(const f16x8*)&Bs1[boff + 16 * 72];
      f16x8 b30 = *(const f16x8*)&Bs2[boff];
      f16x8 b31 = *(const f16x8*)&Bs2[boff + 16 * 72];
      ac1[0][0] = MFMA16(a0, b10, ac1[0][0]);
      ac1[0][1] = MFMA16(a0, b11, ac1[0][1]);
      ac1[1][0] = MFMA16(a1, b10, ac1[1][0]);
      ac1[1][1] = MFMA16(a1, b11, ac1[1][1]);
      ac2[0][0] = MFMA16(a0, b30, ac2[0][0]);
      ac2[0][1] = MFMA16(a0, b31, ac2[0][1]);
      ac2[1][0] = MFMA16(a1, b30, ac2[1][0]);
      ac2[1][1] = MFMA16(a1, b31, ac2[1][1]);
    }
  }
#pragma unroll
  for (int mi = 0; mi < 2; ++mi)
#pragma unroll
    for (int ni = 0; ni < 2; ++ni)
#pragma unroll
      for (int r = 0; r < 4; ++r) {
        int row = mt * 64 + (wv & 1) * 32 + mi * 16 + quad * 4 + r;
        int col = nt * 64 + (wv >> 1) * 32 + ni * 16 + m16;
        float h1 = ac1[mi][ni][r];
        float h3 = ac2[mi][ni][r];
        float sl = h1 / (1.0f + expf(-h1));
        tout[(size_t)row * NHID + col] = (f16)(sl * h3);
      }
}

// ---------------- GEMM1 (fr pass): A = f16(ybc+yba) slice, B = compact fr1c/fr3c ------
__global__ __launch_bounds__(256) void k_gemm1_fr(
    const float* __restrict__ ybc, const float* __restrict__ yba,
    const f16* __restrict__ wf, f16* __restrict__ tbuf) {
  int e = blockIdx.z, mt = blockIdx.y, nt = blockIdx.x;
  const int K = 288;
  int koff = e * 288;
  const f16* B1 = wf + OFF_FR1 + (size_t)e * 768 * 288;
  const f16* B3 = wf + OFF_FR3 + (size_t)e * 768 * 288;
  f16* tout = tbuf + (size_t)e * NTOK * NHID;
  int t = threadIdx.x;
  int wv = t >> 6, lane = t & 63, m16 = lane & 15, quad = lane >> 4;
  int r0 = t >> 3, ak = (t & 7) * 8;
  const float* c0 = ybc + (size_t)(mt * 64 + r0) * NDIM + koff;
  const float* c1 = ybc + (size_t)(mt * 64 + r0 + 32) * NDIM + koff;
  const float* d0 = yba + (size_t)(mt * 64 + r0) * NDIM + koff;
  const float* d1 = yba + (size_t)(mt * 64 + r0 + 32) * NDIM + koff;
  const f16* b1r0 = B1 + (size_t)(nt * 64 + r0) * 288;
  const f16* b1r1 = B1 + (size_t)(nt * 64 + r0 + 32) * 288;
  const f16* b3r0 = B3 + (size_t)(nt * 64 + r0) * 288;
  const f16* b3r1 = B3 + (size_t)(nt * 64 + r0 + 32) * 288;
  __shared__ f16 As[64 * 72];
  __shared__ f16 Bs1[64 * 72];
  __shared__ f16 Bs2[64 * 72];
  f32x4 zf = {0.f, 0.f, 0.f, 0.f};
  f32x4 ac1[2][2] = {{zf, zf}, {zf, zf}};
  f32x4 ac2[2][2] = {{zf, zf}, {zf, zf}};
  uint4 rb10, rb11, rb30, rb31;
  rb10 = *(const uint4*)(b1r0 + ak);
  rb11 = *(const uint4*)(b1r1 + ak);
  rb30 = *(const uint4*)(b3r0 + ak);
  rb31 = *(const uint4*)(b3r1 + ak);
  for (int kc = 0; kc < K; kc += 64) {
    __syncthreads();
    {
      f16x8 h0, h1;
      int cb = kc + ak;
      if (cb < K) {
        float4 p0 = *(const float4*)(c0 + cb);
        float4 p1 = *(const float4*)(c0 + cb + 4);
        float4 q0 = *(const float4*)(d0 + cb);
        float4 q1 = *(const float4*)(d0 + cb + 4);
        h0[0] = (f16)(p0.x + q0.x); h0[1] = (f16)(p0.y + q0.y);
        h0[2] = (f16)(p0.z + q0.z); h0[3] = (f16)(p0.w + q0.w);
        h0[4] = (f16)(p1.x + q1.x); h0[5] = (f16)(p1.y + q1.y);
        h0[6] = (f16)(p1.z + q1.z); h0[7] = (f16)(p1.w + q1.w);
        p0 = *(const float4*)(c1 + cb);
        p1 = *(const float4*)(c1 + cb + 4);
        q0 = *(const float4*)(d1 + cb);
        q1 = *(const float4*)(d1 + cb + 4);
        h1[0] = (f16)(p0.x + q0.x); h1[1] = (f16)(p0.y + q0.y);
        h1[2] = (f16)(p0.z + q0.z); h1[3] = (f16)(p0.w + q0.w);
        h1[4] = (f16)(p1.x + q1.x); h1[5] = (f16)(p1.y + q1.y);
        h1[6] = (f16)(p1.z + q1.z); h1[7] = (f16)(p1.w + q1.w);
      } else {
#pragma unroll
        for (int j = 0; j < 8; ++j) { h0[j] = (f16)0.f; h1[j] = (f16)0.f; }
      }
      *(f16x8*)&As[r0 * 72 + ak] = h0;
      *(f16x8*)&As[(r0 + 32) * 72 + ak] = h1;
    }
    *(uint4*)&Bs1[r0 * 72 + ak] = rb10;
    *(uint4*)&Bs1[(r0 + 32) * 72 + ak] = rb11;
    *(uint4*)&Bs2[r0 * 72 + ak] = rb30;
    *(uint4*)&Bs2[(r0 + 32) * 72 + ak] = rb31;
    __syncthreads();
    int kn = kc + 64;
    if (kn < K) {
      bool v = (kn + ak < K);
      uint4 z4u = make_uint4(0u, 0u, 0u, 0u);
      rb10 = v ? *(const uint4*)(b1r0 + kn + ak) : z4u;
      rb11 = v ? *(const uint4*)(b1r1 + kn + ak) : z4u;
      rb30 = v ? *(const uint4*)(b3r0 + kn + ak) : z4u;
      rb31 = v ? *(const uint4*)(b3r1 + kn + ak) : z4u;
    }
#pragma unroll
    for (int ks = 0; ks < 2; ++ks) {
      int aoff = ((wv & 1) * 32 + m16) * 72 + ks * 32 + quad * 8;
      int boff = ((wv >> 1) * 32 + m16) * 72 + ks * 32 + quad * 8;
      f16x8 a0 = *(const f16x8*)&As[aoff];
      f16x8 a1 = *(const f16x8*)&As[aoff + 16 * 72];
      f16x8 b10 = *(const f16x8*)&Bs1[boff];
      f16x8 b11 = *(const f16x8*)&Bs1[boff + 16 * 72];
      f16x8 b30 = *(const f16x8*)&Bs2[boff];
      f16x8 b31 = *(const f16x8*)&Bs2[boff + 16 * 72];
      ac1[0][0] = MFMA16(a0, b10, ac1[0][0]);
      ac1[0][1] = MFMA16(a0, b11, ac1[0][1]);
      ac1[1][0] = MFMA16(a1, b10, ac1[1][0]);
      ac1[1][1] = MFMA16(a1, b11, ac1[1][1]);
      ac2[0][0] = MFMA16(a0, b30, ac2[0][0]);
      ac2[0][1] = MFMA16(a0, b31, ac2[0][1]);
      ac2[1][0] = MFMA16(a1, b30, ac2[1][0]);
      ac2[1][1] = MFMA16(a1, b31, ac2[1][1]);
    }
  }
#pragma unroll
  for (int mi = 0; mi < 2; ++mi)
#pragma unroll
    for (int ni = 0; ni < 2; ++ni)
#pragma unroll
      for (int r = 0; r < 4; ++r) {
        int row = mt * 64 + (wv & 1) * 32 + mi * 16 + quad * 4 + r;
        int col = nt * 64 + (wv >> 1) * 32 + ni * 16 + m16;
        float h1v = ac1[mi][ni][r];
        float h3v = ac2[mi][ni][r];
        float sl = h1v / (1.0f + expf(-h1v));
        tout[(size_t)row * NHID + col] = (f16)(sl * h3v);
      }
}

// ---------------- GEMM2 (MoE): f16 weights, XCD-grouped remap, 2-phase ----------------
__global__ __launch_bounds__(256) void k_gemm2(
    const f16* __restrict__ tbuf, const f16* __restrict__ wf,
    const int* __restrict__ lists, const int* __restrict__ counts,
    const float* __restrict__ cmv, const float* __restrict__ amv,
    float* __restrict__ yc, float* __restrict__ ya) {
  int bid = blockIdx.x;
  int xcd = bid & 7;
  int local = bid >> 3;
  int pair = xcd * 18 + (local >> 5);
  int mt = local & 31;
  int g = pair / 18;
  int nt = pair % 18;
  int e = g & 3;
  int cnt = counts[g];
  if (mt * 64 >= cnt) return;
  const int* list = lists + g * NTOK;
  const f16* A = tbuf + (size_t)g * NTOK * NHID;
  const f16* Bw = wf + ((g < 4) ? OFF_CW2 : OFF_AW2) + (size_t)e * NDIM * NHID;
  const float* sc = (g < 4) ? cmv : amv;
  float* y = (g < 4) ? yc : ya;
  int t = threadIdx.x;
  int wv = t >> 6, lane = t & 63, m16 = lane & 15, quad = lane >> 4;
  int r0 = t >> 3, ak = (t & 7) * 8;
  const f16* ar0 = A + (size_t)(mt * 64 + r0) * NHID;
  const f16* ar1 = A + (size_t)(mt * 64 + r0 + 32) * NHID;
  const f16* br0 = Bw + (size_t)(nt * 64 + r0) * NHID;
  const f16* br1 = Bw + (size_t)(nt * 64 + r0 + 32) * NHID;
  __shared__ f16 As[64 * 72];
  __shared__ f16 Bs[64 * 72];
  f32x4 zf = {0.f, 0.f, 0.f, 0.f};
  f32x4 acc[2][2] = {{zf, zf}, {zf, zf}};
  uint4 ra0, ra1, rb0, rb1;
  ra0 = *(const uint4*)(ar0 + ak);
  ra1 = *(const uint4*)(ar1 + ak);
  rb0 = *(const uint4*)(br0 + ak);
  rb1 = *(const uint4*)(br1 + ak);
  for (int kc = 0; kc < NHID; kc += 64) {
    __syncthreads();
    *(uint4*)&As[r0 * 72 + ak] = ra0;
    *(uint4*)&As[(r0 + 32) * 72 + ak] = ra1;
    *(uint4*)&Bs[r0 * 72 + ak] = rb0;
    *(uint4*)&Bs[(r0 + 32) * 72 + ak] = rb1;
    __syncthreads();
    int kn = kc + 64;
    if (kn < NHID) {
      ra0 = *(const uint4*)(ar0 + kn + ak);
      ra1 = *(const uint4*)(ar1 + kn + ak);
      rb0 = *(const uint4*)(br0 + kn + ak);
      rb1 = *(const uint4*)(br1 + kn + ak);
    }
#pragma unroll
    for (int ks = 0; ks < 2; ++ks) {
      int aoff = ((wv & 1) * 32 + m16) * 72 + ks * 32 + quad * 8;
      int boff = ((wv >> 1) * 32 + m16) * 72 + ks * 32 + quad * 8;
      f16x8 a0 = *(const f16x8*)&As[aoff];
      f16x8 a1 = *(const f16x8*)&As[aoff + 16 * 72];
      f16x8 b0 = *(const f16x8*)&Bs[boff];
      f16x8 b1 = *(const f16x8*)&Bs[boff + 16 * 72];
      acc[0][0] = MFMA16(a0, b0, acc[0][0]);
      acc[0][1] = MFMA16(a0, b1, acc[0][1]);
      acc[1][0] = MFMA16(a1, b0, acc[1][0]);
      acc[1][1] = MFMA16(a1, b1, acc[1][1]);
    }
  }
#pragma unroll
  for (int mi = 0; mi < 2; ++mi)
#pragma unroll
    for (int ni = 0; ni < 2; ++ni)
#pragma unroll
      for (int r = 0; r < 4; ++r) {
        int mg = mt * 64 + (wv & 1) * 32 + mi * 16 + quad * 4 + r;
        if (mg < cnt) {
          int tok = list[mg];
          int col = nt * 64 + (wv >> 1) * 32 + ni * 16 + m16;
          float v = acc[mi][ni][r] * sc[tok];
          y[(size_t)tok * NDIM + col] = v;
        }
      }
}

// ---------------- GEMM2 (fr): compact fr2c, t16 @ slice -> z, 2-phase -----------------
__global__ __launch_bounds__(256) void k_gemm2_fr(
    const f16* __restrict__ tbuf, const f16* __restrict__ wf, float* __restrict__ zz) {
  int e = blockIdx.z;
  int mt = blockIdx.y, nt = blockIdx.x;
  const f16* A = tbuf + (size_t)e * NTOK * NHID;
  const f16* Bw = wf + OFF_FR2 + (size_t)e * 288 * NHID;
  int t = threadIdx.x;
  int wv = t >> 6, lane = t & 63, m16 = lane & 15, quad = lane >> 4;
  int r0 = t >> 3, ak = (t & 7) * 8;
  const f16* ar0 = A + (size_t)(mt * 64 + r0) * NHID;
  const f16* ar1 = A + (size_t)(mt * 64 + r0 + 32) * NHID;
  int ne0 = min(nt * 64 + r0, 287), ne1 = min(nt * 64 + r0 + 32, 287);
  const f16* br0 = Bw + (size_t)ne0 * NHID;
  const f16* br1 = Bw + (size_t)ne1 * NHID;
  __shared__ f16 As[64 * 72];
  __shared__ f16 Bs[64 * 72];
  f32x4 zf = {0.f, 0.f, 0.f, 0.f};
  f32x4 acc[2][2] = {{zf, zf}, {zf, zf}};
  uint4 ra0, ra1, rb0, rb1;
  ra0 = *(const uint4*)(ar0 + ak);
  ra1 = *(const uint4*)(ar1 + ak);
  rb0 = *(const uint4*)(br0 + ak);
  rb1 = *(const uint4*)(br1 + ak);
  for (int kc = 0; kc < NHID; kc += 64) {
    __syncthreads();
    *(uint4*)&As[r0 * 72 + ak] = ra0;
    *(uint4*)&As[(r0 + 32) * 72 + ak] = ra1;
    *(uint4*)&Bs[r0 * 72 + ak] = rb0;
    *(uint4*)&Bs[(r0 + 32) * 72 + ak] = rb1;
    __syncthreads();
    int kn = kc + 64;
    if (kn < NHID) {
      ra0 = *(const uint4*)(ar0 + kn + ak);
      ra1 = *(const uint4*)(ar1 + kn + ak);
      rb0 = *(const uint4*)(br0 + kn + ak);
      rb1 = *(const uint4*)(br1 + kn + ak);
    }
#pragma unroll
    for (int ks = 0; ks < 2; ++ks) {
      int aoff = ((wv & 1) * 32 + m16) * 72 + ks * 32 + quad * 8;
      int boff = ((wv >> 1) * 32 + m16) * 72 + ks * 32 + quad * 8;
      f16x8 a0 = *(const f16x8*)&As[aoff];
      f16x8 a1 = *(const f16x8*)&As[aoff + 16 * 72];
      f16x8 b0 = *(const f16x8*)&Bs[boff];
      f16x8 b1 = *(const f16x8*)&Bs[boff + 16 * 72];
      acc[0][0] = MFMA16(a0, b0, acc[0][0]);
      acc[0][1] = MFMA16(a0, b1, acc[0][1]);
      acc[1][0] = MFMA16(a1, b0, acc[1][0]);
      acc[1][1] = MFMA16(a1, b1, acc[1][1]);
    }
  }
#pragma unroll
  for (int mi = 0; mi < 2; ++mi)
#pragma unroll
    for (int ni = 0; ni < 2; ++ni)
#pragma unroll
      for (int r = 0; r < 4; ++r) {
        int cg = nt * 64 + (wv >> 1) * 32 + ni * 16 + m16;
        if (cg < 288) {
          int row = mt * 64 + (wv & 1) * 32 + mi * 16 + quad * 4 + r;
          zz[(size_t)row * NDIM + e * 288 + cg] = acc[mi][ni][r];
        }
      }
}

// ---------------- host ----------------
extern "C" void kernel_launch(void* const* d_in, const int* in_sizes, int n_in,
                              void* d_out, int out_size, void* d_ws, size_t ws_size,
                              hipStream_t stream) {
  const float* x          = (const float*)d_in[0];
  const float* timep      = (const float*)d_in[1];
  const float* caption    = (const float*)d_in[2];
  const float* acoustic   = (const float*)d_in[3];
  const float* attn_in_w  = (const float*)d_in[4];
  const float* attn_in_b  = (const float*)d_in[5];
  const float* attn_out_w = (const float*)d_in[6];
  const float* attn_out_b = (const float*)d_in[7];
  const float* hl_w       = (const float*)d_in[8];
  const float* hl_b       = (const float*)d_in[9];
  const float* cap_gate_w = (const float*)d_in[10];
  const float* cap_gate_b = (const float*)d_in[11];
  const float* ac_gate_w  = (const float*)d_in[12];
  const float* ac_gate_b  = (const float*)d_in[13];
  const float* cap_w1     = (const float*)d_in[14];
  const float* cap_w2     = (const float*)d_in[15];
  const float* cap_w3     = (const float*)d_in[16];
  const float* ac_w1      = (const float*)d_in[17];
  const float* ac_w2      = (const float*)d_in[18];
  const float* ac_w3      = (const float*)d_in[19];
  const float* fr_w1      = (const float*)d_in[20];
  const float* fr_w2      = (const float*)d_in[21];
  const float* fr_w3      = (const float*)d_in[22];
  (void)in_sizes; (void)n_in; (void)out_size; (void)ws_size;

  float* zout = (float*)d_out;
  float* loss = zout + (size_t)NTOK * NDIM;

  char* wsb = (char*)d_ws;
  size_t off = 0;
  auto alloc = [&](size_t bytes) -> void* {
    void* p = wsb + off;
    off = (off + bytes + 255) & ~(size_t)255;
    return p;
  };
  // persistent small + xhi + converted weights
  float* g1     = (float*)alloc(4096 * 4);
  float* g2     = (float*)alloc(8192 * 4);
  float* g3     = (float*)alloc(8192 * 4);
  float* tl     = (float*)alloc(4 * 4);
  float* al     = (float*)alloc((size_t)NTOK * NEXP * 4);
  float* cl     = (float*)alloc((size_t)NTOK * NEXP * 4);
  float* cmv    = (float*)alloc((size_t)NTOK * 4);
  float* amv    = (float*)alloc((size_t)NTOK * 4);
  int*   lists  = (int*)alloc((size_t)8 * NTOK * 4);
  int*   counts = (int*)alloc(8 * 4);
  float* wp     = (float*)alloc((size_t)NEXP * NDIM * 4);
  float* bp     = (float*)alloc(NEXP * 4);
  f16*   xhi    = (f16*)alloc((size_t)NTOK * NDIM * 2);
  f16*   wf16   = (f16*)alloc((size_t)(6 * WSZ + 3 * WQ) * 2);
  size_t region = off;
  // phase 1 (attention / routing inputs)
  f16*   xlo    = (f16*)alloc((size_t)NTOK * NDIM * 2);
  f16*   caphi  = (f16*)alloc((size_t)NCAP * NDIM * 2);
  f16*   caplo  = (f16*)alloc((size_t)NCAP * NDIM * 2);
  f16*   qhi    = (f16*)alloc((size_t)NTOK * NDIM * 2);
  f16*   qlo    = (f16*)alloc((size_t)NTOK * NDIM * 2);
  f16*   khi    = (f16*)alloc((size_t)NCAP * NDIM * 2);
  f16*   klo    = (f16*)alloc((size_t)NCAP * NDIM * 2);
  f16*   vthi   = (f16*)alloc((size_t)NB * NDIM * NSC * 2);
  f16*   vtlo   = (f16*)alloc((size_t)NB * NDIM * NSC * 2);
  f16*   ohi    = (f16*)alloc((size_t)NTOK * NDIM * 2);
  f16*   olo    = (f16*)alloc((size_t)NTOK * NDIM * 2);
  f16*   inwhi  = (f16*)alloc((size_t)3 * NDIM * NDIM * 2);
  f16*   inwlo  = (f16*)alloc((size_t)3 * NDIM * NDIM * 2);
  // phase 2 (MoE / fr) — reuses phase-1 region (all phase-1 buffers dead)
  off = region;
  f16*   tbuf   = (f16*)alloc((size_t)8 * NTOK * NHID * 2);
  float* ybc    = (float*)alloc((size_t)NTOK * NDIM * 4);
  float* yba    = (float*)alloc((size_t)NTOK * NDIM * 4);

  // single merged preprocessing launch
  k_pre<<<dim3(PRE_NB), dim3(256), 0, stream>>>(
      x, caption, attn_in_w, timep, hl_w, hl_b,
      acoustic, ac_gate_w, ac_gate_b,
      attn_out_w, attn_out_b, cap_gate_w, cap_gate_b,
      xhi, xlo, caphi, caplo, inwhi, inwlo,
      g1, g2, g3, tl, al, wp, bp);
  // pure f16 QKV projection
  k_gemm_qkv<<<dim3(18, 32, 3), dim3(256), 0, stream>>>(
      xhi, xlo, caphi, caplo, inwhi, inwlo, attn_in_b,
      qhi, qlo, khi, klo, vthi, vtlo);
  k_attn<<<dim3(16, 16), dim3(256), 0, stream>>>(qhi, qlo, khi, klo, vthi, vtlo, ohi, olo);
  k_o_logits<<<dim3(512), dim3(256), 0, stream>>>(ohi, olo, wp, bp, cl);
  // routing + hosted cvt of slots 0-3 on otherwise-idle CUs
  k_route<<<dim3(1 + 1728), dim3(1024), 0, stream>>>(cl, al, g1, g2, g3, tl,
                                                     cmv, amv, lists, counts, loss,
                                                     cap_w1, cap_w3, ac_w1, ac_w3, wf16);
  // gemm1 MoE pass (8 groups) + tail cvt blocks (cap_w2/ac_w2 full + fr compacts)
  k_gemm1<<<dim3(3666), dim3(256), 0, stream>>>(xhi, wf16, lists, counts, tbuf,
                                                fr_w1, fr_w3, cap_w2, ac_w2, fr_w2);
  k_gemm2<<<dim3(4608), dim3(256), 0, stream>>>(tbuf, wf16, lists, counts,
                                                cmv, amv, ybc, yba);
  k_gemm1_fr<<<dim3(12, 32, 4), dim3(256), 0, stream>>>(ybc, yba, wf16, tbuf);
  k_gemm2_fr<<<dim3(5, 32, 4), dim3(256), 0, stream>>>(tbuf, wf16, zout);
}

// Round 11
// 407.117 us; speedup vs baseline: 1.4296x; 1.0444x over previous
//
#include <hip/hip_runtime.h>
#include <stdint.h>

#define NDIM 1152
#define NEXP 4
#define NHID 768
#define NHEAD 8
#define HDIM 144
#define NB 2
#define NS 1024
#define NSC 128
#define NTOK 2048
#define NCAP 256

typedef _Float16 f16;
typedef _Float16 f16x4 __attribute__((ext_vector_type(4)));
typedef _Float16 f16x8 __attribute__((ext_vector_type(8)));
typedef float f32x4 __attribute__((ext_vector_type(4)));

#define MFMA16(a, b, c) __builtin_amdgcn_mfma_f32_16x16x32_f16(a, b, c, 0, 0, 0)

#define WSZ ((size_t)NEXP * NHID * NDIM)  // elems per full weight tensor (3,538,944)
#define WQ  ((size_t)(WSZ / 4))           // compact fr tensor elems (884,736)
#define OFF_CW2 ((size_t)4 * WSZ)
#define OFF_AW2 ((size_t)5 * WSZ)
#define OFF_FR1 ((size_t)6 * WSZ)
#define OFF_FR3 ((size_t)6 * WSZ + WQ)
#define OFF_FR2 ((size_t)6 * WSZ + 2 * WQ)

// k_pre block ranges
#define PRE_XB   2304                     // x split (4/thread)
#define PRE_CB   288                      // caption split
#define PRE_IWB  1944                     // attn_in_w split (8/thread)
#define PRE_C0   (PRE_XB)                 // 2304
#define PRE_IW0  (PRE_C0 + PRE_CB)        // 2592
#define PRE_G1   (PRE_IW0 + PRE_IWB)      // 4536 .. 4539 (4 blocks, g1)
#define PRE_G23  (PRE_G1 + 4)             // 4540 .. 4555 (16 blocks, g2+g3)
#define PRE_TL   (PRE_G23 + 16)           // 4556 (time-logits)
#define PRE_FG0  (PRE_TL + 1)             // 4557 .. 4575 (18 col blocks + 1 bias)
#define PRE_AL0  (PRE_FG0 + 19)           // 4576
#define PRE_NB   (PRE_AL0 + 512)          // 5088

// ---------------- Threefry2x32 (exact JAX replication) ----------------
__device__ inline uint2 tfry(uint32_t k0, uint32_t k1, uint32_t x0, uint32_t x1) {
  uint32_t k2 = k0 ^ k1 ^ 0x1BD11BDAu;
#define RND(r) { x0 += x1; x1 = (x1 << r) | (x1 >> (32 - r)); x1 ^= x0; }
  x0 += k0; x1 += k1;
  RND(13) RND(15) RND(26) RND(6)
  x0 += k1; x1 += k2 + 1u;
  RND(17) RND(29) RND(16) RND(24)
  x0 += k2; x1 += k0 + 2u;
  RND(13) RND(15) RND(26) RND(6)
  x0 += k0; x1 += k1 + 3u;
  RND(17) RND(29) RND(16) RND(24)
  x0 += k1; x1 += k2 + 4u;
  RND(13) RND(15) RND(26) RND(6)
  x0 += k2; x1 += k0 + 5u;
#undef RND
  return make_uint2(x0, x1);
}

__device__ inline float b2g(uint32_t bits) {
  uint32_t fb = (bits >> 9) | 0x3f800000u;
  float f = __uint_as_float(fb) - 1.0f;
  const float tiny = 1.1754943508222875e-38f;
  float u = f * 1.0f + tiny;
  u = fmaxf(tiny, u);
  return -logf(-logf(u));
}

// ---------------- k_pre: all preprocessing in one launch ----------------
__global__ __launch_bounds__(256) void k_pre(
    const float* __restrict__ x, const float* __restrict__ caption,
    const float* __restrict__ inw,
    const float* __restrict__ timep, const float* __restrict__ hlw,
    const float* __restrict__ hlb,
    const float* __restrict__ acous, const float* __restrict__ agw,
    const float* __restrict__ agb,
    const float* __restrict__ ow, const float* __restrict__ ob,
    const float* __restrict__ gw, const float* __restrict__ gb,
    f16* __restrict__ xhi, f16* __restrict__ xlo,
    f16* __restrict__ caphi, f16* __restrict__ caplo,
    f16* __restrict__ inwhi, f16* __restrict__ inwlo,
    float* __restrict__ g1, float* __restrict__ g2, float* __restrict__ g3,
    float* __restrict__ tl, float* __restrict__ al,
    float* __restrict__ wp, float* __restrict__ bp) {
  __shared__ float sm[4][4][64];
  int bid = blockIdx.x;
  int t = threadIdx.x;
  if (bid < PRE_C0) {
    int i = bid * 1024 + t * 4;
    float4 v = *(const float4*)(x + i);
    f16x4 h, l;
    h[0] = (f16)v.x; l[0] = (f16)((v.x - (float)h[0]) * 2048.f);
    h[1] = (f16)v.y; l[1] = (f16)((v.y - (float)h[1]) * 2048.f);
    h[2] = (f16)v.z; l[2] = (f16)((v.z - (float)h[2]) * 2048.f);
    h[3] = (f16)v.w; l[3] = (f16)((v.w - (float)h[3]) * 2048.f);
    *(f16x4*)(xhi + i) = h;
    *(f16x4*)(xlo + i) = l;
    return;
  }
  if (bid < PRE_IW0) {
    int i = (bid - PRE_C0) * 1024 + t * 4;
    float4 v = *(const float4*)(caption + i);
    f16x4 h, l;
    h[0] = (f16)v.x; l[0] = (f16)((v.x - (float)h[0]) * 2048.f);
    h[1] = (f16)v.y; l[1] = (f16)((v.y - (float)h[1]) * 2048.f);
    h[2] = (f16)v.z; l[2] = (f16)((v.z - (float)h[2]) * 2048.f);
    h[3] = (f16)v.w; l[3] = (f16)((v.w - (float)h[3]) * 2048.f);
    *(f16x4*)(caphi + i) = h;
    *(f16x4*)(caplo + i) = l;
    return;
  }
  if (bid < PRE_G1) {
    size_t i = (size_t)(bid - PRE_IW0) * 2048 + (size_t)t * 8;
    float4 v0 = *(const float4*)(inw + i);
    float4 v1 = *(const float4*)(inw + i + 4);
    f16x8 h, l;
    h[0] = (f16)v0.x; l[0] = (f16)((v0.x - (float)h[0]) * 2048.f);
    h[1] = (f16)v0.y; l[1] = (f16)((v0.y - (float)h[1]) * 2048.f);
    h[2] = (f16)v0.z; l[2] = (f16)((v0.z - (float)h[2]) * 2048.f);
    h[3] = (f16)v0.w; l[3] = (f16)((v0.w - (float)h[3]) * 2048.f);
    h[4] = (f16)v1.x; l[4] = (f16)((v1.x - (float)h[4]) * 2048.f);
    h[5] = (f16)v1.y; l[5] = (f16)((v1.y - (float)h[5]) * 2048.f);
    h[6] = (f16)v1.z; l[6] = (f16)((v1.z - (float)h[6]) * 2048.f);
    h[7] = (f16)v1.w; l[7] = (f16)((v1.w - (float)h[7]) * 2048.f);
    *(f16x8*)(inwhi + i) = h;
    *(f16x8*)(inwlo + i) = l;
    return;
  }
  if (bid < PRE_G23) {
    // g1: 4096 values over 4 blocks (4/thread)
    uint2 k1 = tfry(0u, 42u, 0u, 0u);
    int p0 = (bid - PRE_G1) * 1024 + t * 4;
#pragma unroll
    for (int i = 0; i < 4; ++i) {
      int p = p0 + i;
      uint2 o = tfry(k1.x, k1.y, 0u, (uint32_t)p);
      g1[p] = b2g(o.x ^ o.y);
    }
    return;
  }
  if (bid < PRE_TL) {
    // g2+g3: 8192 values each over 16 blocks (2/thread, both streams)
    uint2 k2 = tfry(0u, 42u, 0u, 1u);
    uint2 k3 = tfry(0u, 42u, 0u, 2u);
    int p0 = (bid - PRE_G23) * 512 + t * 2;
#pragma unroll
    for (int i = 0; i < 2; ++i) {
      int p = p0 + i;
      uint2 o2 = tfry(k2.x, k2.y, 0u, (uint32_t)p);
      g2[p] = b2g(o2.x ^ o2.y);
      uint2 o3 = tfry(k3.x, k3.y, 0u, (uint32_t)p);
      g3[p] = b2g(o3.x ^ o3.y);
    }
    return;
  }
  if (bid == PRE_TL) {
    int wv = t >> 6, lane = t & 63;
    int b = wv >> 1, j = wv & 1;
    float s = 0.f;
    for (int k = lane; k < NDIM; k += 64) s += timep[b * NDIM + k] * hlw[j * NDIM + k];
    for (int m = 32; m; m >>= 1) s += __shfl_xor(s, m);
    if (lane == 0) tl[b * 2 + j] = s + hlb[j];
    return;
  }
  if (bid < PRE_AL0) {
    int blk = bid - PRE_FG0;
    if (blk == 18) {
      int wv = t >> 6, lane = t & 63;  // wv = e
      float s = 0.f;
      for (int d = lane; d < NDIM; d += 64) s += ob[d] * gw[wv * NDIM + d];
      for (int m = 32; m; m >>= 1) s += __shfl_xor(s, m);
      if (lane == 0) bp[wv] = s + gb[wv];
      return;
    }
    int j = t & 63, w = t >> 6;
    int k = blk * 64 + j;
    float a0 = 0.f, a1 = 0.f, a2 = 0.f, a3 = 0.f;
#pragma unroll 16
    for (int d = w * 288; d < (w + 1) * 288; ++d) {
      float o = ow[(size_t)d * NDIM + k];
      a0 += gw[d] * o;
      a1 += gw[NDIM + d] * o;
      a2 += gw[2 * NDIM + d] * o;
      a3 += gw[3 * NDIM + d] * o;
    }
    sm[w][0][j] = a0; sm[w][1][j] = a1; sm[w][2][j] = a2; sm[w][3][j] = a3;
    __syncthreads();
    if (w == 0) {
#pragma unroll
      for (int e = 0; e < 4; ++e)
        wp[e * NDIM + k] = sm[0][e][j] + sm[1][e][j] + sm[2][e][j] + sm[3][e][j];
    }
    return;
  }
  {
    int wv = t >> 6, lane = t & 63;
    int n = (bid - PRE_AL0) * 4 + wv;
    float s[NEXP] = {0.f, 0.f, 0.f, 0.f};
    for (int d = lane; d < NDIM; d += 64) {
      float a = acous[(size_t)n * NDIM + d];
#pragma unroll
      for (int e = 0; e < NEXP; ++e) s[e] += a * agw[e * NDIM + d];
    }
#pragma unroll
    for (int e = 0; e < NEXP; ++e)
      for (int m = 32; m; m >>= 1) s[e] += __shfl_xor(s[e], m);
    if (lane == 0) {
#pragma unroll
      for (int e = 0; e < NEXP; ++e) al[n * NEXP + e] = s[e] + agb[e];
    }
  }
}

// ---------------- cap logits from split-f16 o: cl[n,e] = o[n,:]·W'[e,:] + b'[e] -------
__global__ void k_o_logits(const f16* __restrict__ ohi, const f16* __restrict__ olo,
                           const float* __restrict__ wp, const float* __restrict__ bp,
                           float* __restrict__ cl) {
  int wv = threadIdx.x >> 6, lane = threadIdx.x & 63;
  int n = blockIdx.x * 4 + wv;
  float s[NEXP] = {0.f, 0.f, 0.f, 0.f};
  for (int d = lane; d < NDIM; d += 64) {
    size_t gi = (size_t)n * NDIM + d;
    float a = (float)ohi[gi] + (float)olo[gi] * (1.f / 2048.f);
#pragma unroll
    for (int e = 0; e < NEXP; ++e) s[e] += a * wp[e * NDIM + d];
  }
#pragma unroll
  for (int e = 0; e < NEXP; ++e)
    for (int m = 32; m; m >>= 1) s[e] += __shfl_xor(s[e], m);
  if (lane == 0) {
#pragma unroll
    for (int e = 0; e < NEXP; ++e) cl[n * NEXP + e] = s[e] + bp[e];
  }
}

// ---------------- QKV projection (all-f16 staging), pure GEMM ----------------
__global__ __launch_bounds__(256) void k_gemm_qkv(
    const f16* __restrict__ xhi, const f16* __restrict__ xlo,
    const f16* __restrict__ caphi, const f16* __restrict__ caplo,
    const f16* __restrict__ inwhi, const f16* __restrict__ inwlo,
    const float* __restrict__ inb,
    f16* __restrict__ qhi, f16* __restrict__ qlo,
    f16* __restrict__ khi, f16* __restrict__ klo,
    f16* __restrict__ vthi, f16* __restrict__ vtlo) {
  int z = blockIdx.z;
  int M = (z == 0) ? NTOK : NCAP;
  int mt = blockIdx.y, nt = blockIdx.x;
  if (mt * 64 >= M) return;
  const f16* Ah_g = (z == 0) ? xhi : caphi;
  const f16* Al_g = (z == 0) ? xlo : caplo;
  __shared__ f16 Ash[64 * 72];
  __shared__ f16 Asl[64 * 72];
  __shared__ f16 Bsh[64 * 72];
  __shared__ f16 Bsl[64 * 72];
  int t = threadIdx.x;
  int wv = t >> 6, lane = t & 63, m16 = lane & 15, quad = lane >> 4;
  int r0 = t >> 3, ak = (t & 7) * 8;
  size_t a0o = (size_t)(mt * 64 + r0) * NDIM;
  size_t a1o = (size_t)(mt * 64 + r0 + 32) * NDIM;
  const f16* bh0 = inwhi + (size_t)(z * NDIM + nt * 64 + r0) * NDIM;
  const f16* bh1 = bh0 + (size_t)32 * NDIM;
  const f16* bl0 = inwlo + (size_t)(z * NDIM + nt * 64 + r0) * NDIM;
  const f16* bl1 = bl0 + (size_t)32 * NDIM;
  f32x4 zf = {0.f, 0.f, 0.f, 0.f};
  f32x4 ah[2][2] = {{zf, zf}, {zf, zf}};
  f32x4 am[2][2] = {{zf, zf}, {zf, zf}};
  uint4 rah0, rah1, ral0, ral1, rbh0, rbh1, rbl0, rbl1;
  rah0 = *(const uint4*)(Ah_g + a0o + ak);
  rah1 = *(const uint4*)(Ah_g + a1o + ak);
  ral0 = *(const uint4*)(Al_g + a0o + ak);
  ral1 = *(const uint4*)(Al_g + a1o + ak);
  rbh0 = *(const uint4*)(bh0 + ak);
  rbh1 = *(const uint4*)(bh1 + ak);
  rbl0 = *(const uint4*)(bl0 + ak);
  rbl1 = *(const uint4*)(bl1 + ak);
  for (int kc = 0; kc < NDIM; kc += 64) {
    __syncthreads();
    *(uint4*)&Ash[r0 * 72 + ak] = rah0;
    *(uint4*)&Ash[(r0 + 32) * 72 + ak] = rah1;
    *(uint4*)&Asl[r0 * 72 + ak] = ral0;
    *(uint4*)&Asl[(r0 + 32) * 72 + ak] = ral1;
    *(uint4*)&Bsh[r0 * 72 + ak] = rbh0;
    *(uint4*)&Bsh[(r0 + 32) * 72 + ak] = rbh1;
    *(uint4*)&Bsl[r0 * 72 + ak] = rbl0;
    *(uint4*)&Bsl[(r0 + 32) * 72 + ak] = rbl1;
    __syncthreads();
    int kn = kc + 64;
    if (kn < NDIM) {
      rah0 = *(const uint4*)(Ah_g + a0o + kn + ak);
      rah1 = *(const uint4*)(Ah_g + a1o + kn + ak);
      ral0 = *(const uint4*)(Al_g + a0o + kn + ak);
      ral1 = *(const uint4*)(Al_g + a1o + kn + ak);
      rbh0 = *(const uint4*)(bh0 + kn + ak);
      rbh1 = *(const uint4*)(bh1 + kn + ak);
      rbl0 = *(const uint4*)(bl0 + kn + ak);
      rbl1 = *(const uint4*)(bl1 + kn + ak);
    }
#pragma unroll
    for (int ks = 0; ks < 2; ++ks) {
      int aoff = ((wv & 1) * 32 + m16) * 72 + ks * 32 + quad * 8;
      int boff = ((wv >> 1) * 32 + m16) * 72 + ks * 32 + quad * 8;
      f16x8 a0h = *(const f16x8*)&Ash[aoff];
      f16x8 a1h = *(const f16x8*)&Ash[aoff + 16 * 72];
      f16x8 a0l = *(const f16x8*)&Asl[aoff];
      f16x8 a1l = *(const f16x8*)&Asl[aoff + 16 * 72];
      f16x8 b0h = *(const f16x8*)&Bsh[boff];
      f16x8 b1h = *(const f16x8*)&Bsh[boff + 16 * 72];
      f16x8 b0l = *(const f16x8*)&Bsl[boff];
      f16x8 b1l = *(const f16x8*)&Bsl[boff + 16 * 72];
      ah[0][0] = MFMA16(a0h, b0h, ah[0][0]);
      ah[0][1] = MFMA16(a0h, b1h, ah[0][1]);
      ah[1][0] = MFMA16(a1h, b0h, ah[1][0]);
      ah[1][1] = MFMA16(a1h, b1h, ah[1][1]);
      am[0][0] = MFMA16(a0h, b0l, am[0][0]);
      am[0][1] = MFMA16(a0h, b1l, am[0][1]);
      am[1][0] = MFMA16(a1h, b0l, am[1][0]);
      am[1][1] = MFMA16(a1h, b1l, am[1][1]);
      am[0][0] = MFMA16(a0l, b0h, am[0][0]);
      am[0][1] = MFMA16(a0l, b1h, am[0][1]);
      am[1][0] = MFMA16(a1l, b0h, am[1][0]);
      am[1][1] = MFMA16(a1l, b1h, am[1][1]);
    }
  }
#pragma unroll
  for (int mi = 0; mi < 2; ++mi)
#pragma unroll
    for (int ni = 0; ni < 2; ++ni)
#pragma unroll
      for (int r = 0; r < 4; ++r) {
        int row = mt * 64 + (wv & 1) * 32 + mi * 16 + quad * 4 + r;
        int col = nt * 64 + (wv >> 1) * 32 + ni * 16 + m16;
        float v = ah[mi][ni][r] + am[mi][ni][r] * (1.f / 2048.f) + inb[z * NDIM + col];
        size_t idx = (size_t)row * NDIM + col;
        if (z == 0) {
          f16 hq = (f16)v;
          qhi[idx] = hq;
          qlo[idx] = (f16)((v - (float)hq) * 2048.f);
        } else if (z == 1) {
          f16 hk = (f16)v;
          khi[idx] = hk;
          klo[idx] = (f16)((v - (float)hk) * 2048.f);
        } else {
          f16 hv = (f16)v;
          int bb = row >> 7, kv = row & 127;
          size_t ti = (size_t)(bb * NDIM + col) * NSC + kv;
          vthi[ti] = hv;
          vtlo[ti] = (f16)((v - (float)hv) * 2048.f);
        }
      }
}

// ---------------- fused attention: QK^T + softmax + PV, split-fp16, writes o hi/lo ----
__global__ __launch_bounds__(256) void k_attn(
    const f16* __restrict__ qhi, const f16* __restrict__ qlo,
    const f16* __restrict__ khi, const f16* __restrict__ klo,
    const f16* __restrict__ vthi, const f16* __restrict__ vtlo,
    f16* __restrict__ ohi, f16* __restrict__ olo) {
  int mt = blockIdx.x, bh = blockIdx.y;
  int b = bh >> 3, h = bh & 7;
  __shared__ f16 Ah[64 * 160];
  __shared__ f16 Al[64 * 160];
  __shared__ f16 Bh[32 * 160];
  __shared__ f16 Bl[32 * 160];
  __shared__ f16 Ph[64 * 136];
  __shared__ f16 Pl[64 * 136];
  int t = threadIdx.x;
  int wv = t >> 6, lane = t & 63, m16 = lane & 15, quad = lane >> 4;
  for (int u = t; u < 64 * 20; u += 256) {
    int r = u / 20, kp = (u % 20) * 8;
    uint4 vh = make_uint4(0u, 0u, 0u, 0u), vl = vh;
    if (kp < HDIM) {
      size_t gi = (size_t)(b * NS + mt * 64 + r) * NDIM + h * HDIM + kp;
      vh = *(const uint4*)&qhi[gi];
      vl = *(const uint4*)&qlo[gi];
    }
    *(uint4*)&Ah[r * 160 + kp] = vh;
    *(uint4*)&Al[r * 160 + kp] = vl;
  }
  __syncthreads();
  f16x8 ahf[5], alf[5];
#pragma unroll
  for (int ks = 0; ks < 5; ++ks) {
    int ao = (wv * 16 + m16) * 160 + ks * 32 + quad * 8;
    ahf[ks] = *(const f16x8*)&Ah[ao];
    alf[ks] = *(const f16x8*)&Al[ao];
  }
  f32x4 zf = {0.f, 0.f, 0.f, 0.f};
  f32x4 sh_[4][2], sm_[4][2];
#pragma unroll
  for (int kt = 0; kt < 4; ++kt)
#pragma unroll
    for (int ni = 0; ni < 2; ++ni) { sh_[kt][ni] = zf; sm_[kt][ni] = zf; }
  for (int kt = 0; kt < 4; ++kt) {
    if (kt) __syncthreads();
    for (int u = t; u < 32 * 20; u += 256) {
      int r = u / 20, kp = (u % 20) * 8;
      uint4 vh = make_uint4(0u, 0u, 0u, 0u), vl = vh;
      if (kp < HDIM) {
        size_t gi = (size_t)(b * NSC + kt * 32 + r) * NDIM + h * HDIM + kp;
        vh = *(const uint4*)&khi[gi];
        vl = *(const uint4*)&klo[gi];
      }
      *(uint4*)&Bh[r * 160 + kp] = vh;
      *(uint4*)&Bl[r * 160 + kp] = vl;
    }
    __syncthreads();
#pragma unroll
    for (int ks = 0; ks < 5; ++ks) {
#pragma unroll
      for (int ni = 0; ni < 2; ++ni) {
        int bo = (ni * 16 + m16) * 160 + ks * 32 + quad * 8;
        f16x8 bhf = *(const f16x8*)&Bh[bo];
        f16x8 blf = *(const f16x8*)&Bl[bo];
        sh_[kt][ni] = MFMA16(ahf[ks], bhf, sh_[kt][ni]);
        sm_[kt][ni] = MFMA16(ahf[ks], blf, sm_[kt][ni]);
        sm_[kt][ni] = MFMA16(alf[ks], bhf, sm_[kt][ni]);
      }
    }
  }
  float sv[4][2][4];
  float mx[4] = {-1e30f, -1e30f, -1e30f, -1e30f};
#pragma unroll
  for (int kt = 0; kt < 4; ++kt)
#pragma unroll
    for (int ni = 0; ni < 2; ++ni)
#pragma unroll
      for (int r = 0; r < 4; ++r) {
        float s = (sh_[kt][ni][r] + sm_[kt][ni][r] * (1.f / 2048.f)) * (1.f / 12.f);
        sv[kt][ni][r] = s;
        mx[r] = fmaxf(mx[r], s);
      }
#pragma unroll
  for (int r = 0; r < 4; ++r) {
    mx[r] = fmaxf(mx[r], __shfl_xor(mx[r], 1));
    mx[r] = fmaxf(mx[r], __shfl_xor(mx[r], 2));
    mx[r] = fmaxf(mx[r], __shfl_xor(mx[r], 4));
    mx[r] = fmaxf(mx[r], __shfl_xor(mx[r], 8));
  }
  float sum[4] = {0.f, 0.f, 0.f, 0.f};
#pragma unroll
  for (int kt = 0; kt < 4; ++kt)
#pragma unroll
    for (int ni = 0; ni < 2; ++ni)
#pragma unroll
      for (int r = 0; r < 4; ++r) {
        float e = expf(sv[kt][ni][r] - mx[r]);
        sv[kt][ni][r] = e;
        sum[r] += e;
      }
  float inv[4];
#pragma unroll
  for (int r = 0; r < 4; ++r) {
    sum[r] += __shfl_xor(sum[r], 1);
    sum[r] += __shfl_xor(sum[r], 2);
    sum[r] += __shfl_xor(sum[r], 4);
    sum[r] += __shfl_xor(sum[r], 8);
    inv[r] = 1.0f / sum[r];
  }
#pragma unroll
  for (int kt = 0; kt < 4; ++kt)
#pragma unroll
    for (int ni = 0; ni < 2; ++ni)
#pragma unroll
      for (int r = 0; r < 4; ++r) {
        float p = sv[kt][ni][r] * inv[r];
        int row = wv * 16 + quad * 4 + r;
        int col = kt * 32 + ni * 16 + m16;
        f16 ph = (f16)p;
        Ph[row * 136 + col] = ph;
        Pl[row * 136 + col] = (f16)((p - (float)ph) * 2048.f);
      }
  const f16* vbh = vthi + (size_t)(b * NDIM + h * HDIM) * NSC;
  const f16* vbl = vtlo + (size_t)(b * NDIM + h * HDIM) * NSC;
  f32x4 oh_[9], om_[9];
#pragma unroll
  for (int nb = 0; nb < 9; ++nb) { oh_[nb] = zf; om_[nb] = zf; }
#pragma unroll
  for (int ks = 0; ks < 4; ++ks) {
    int po = (wv * 16 + m16) * 136 + ks * 32 + quad * 8;
    f16x8 pah = *(const f16x8*)&Ph[po];
    f16x8 pal = *(const f16x8*)&Pl[po];
#pragma unroll
    for (int nb = 0; nb < 9; ++nb) {
      size_t vo = (size_t)(nb * 16 + m16) * NSC + ks * 32 + quad * 8;
      f16x8 bvh = *(const f16x8*)&vbh[vo];
      f16x8 bvl = *(const f16x8*)&vbl[vo];
      oh_[nb] = MFMA16(pah, bvh, oh_[nb]);
      om_[nb] = MFMA16(pah, bvl, om_[nb]);
      om_[nb] = MFMA16(pal, bvh, om_[nb]);
    }
  }
#pragma unroll
  for (int nb = 0; nb < 9; ++nb)
#pragma unroll
    for (int r = 0; r < 4; ++r) {
      int row = mt * 64 + wv * 16 + quad * 4 + r;
      int col = h * HDIM + nb * 16 + m16;
      float v = oh_[nb][r] + om_[nb][r] * (1.f / 2048.f);
      size_t idx = (size_t)(b * NS + row) * NDIM + col;
      f16 hv = (f16)v;
      ohi[idx] = hv;
      olo[idx] = (f16)((v - (float)hv) * 2048.f);
    }
}

// ---------------- routing + hosted weight cvt (slots 0-3) ----------------
__global__ __launch_bounds__(1024) void k_route(
    const float* __restrict__ cl, const float* __restrict__ al,
    const float* __restrict__ g1, const float* __restrict__ g2,
    const float* __restrict__ g3, const float* __restrict__ tl,
    float* __restrict__ cmv, float* __restrict__ amv,
    int* __restrict__ lists, int* __restrict__ counts, float* __restrict__ out_loss,
    const float* __restrict__ w0, const float* __restrict__ w1,
    const float* __restrict__ w2, const float* __restrict__ w3,
    f16* __restrict__ wf16) {
  int t = threadIdx.x;
  if (blockIdx.x >= 1) {
    size_t c0 = (size_t)(blockIdx.x - 1) * 8192;
    int slot = (int)(c0 / WSZ);               // block-uniform
    size_t base = (c0 % WSZ) + (size_t)t * 8;
    const float* s = ((slot == 0) ? w0 : (slot == 1) ? w1 : (slot == 2) ? w2 : w3) + base;
    float4 v0 = *(const float4*)(s);
    float4 v1 = *(const float4*)(s + 4);
    f16x8 h;
    h[0] = (f16)v0.x; h[1] = (f16)v0.y; h[2] = (f16)v0.z; h[3] = (f16)v0.w;
    h[4] = (f16)v1.x; h[5] = (f16)v1.y; h[6] = (f16)v1.z; h[7] = (f16)v1.w;
    *(f16x8*)(wf16 + (size_t)slot * WSZ + base) = h;
    return;
  }
  __shared__ int lcnt[8];
  __shared__ float bins[8];
  __shared__ float ssum[2];
  if (t < 8) { lcnt[t] = 0; bins[t] = 0.f; }
  if (t < 2) ssum[t] = 0.f;
  __syncthreads();
  for (int n = t; n < NTOK; n += 1024) {
    float lc[NEXP];
#pragma unroll
    for (int e = 0; e < NEXP; ++e) lc[e] = cl[n * NEXP + e] + g2[n * 4 + e];
    int ec = 0; float bv = lc[0];
#pragma unroll
    for (int e = 1; e < NEXP; ++e) if (lc[e] > bv) { bv = lc[e]; ec = e; }
    float la[NEXP];
#pragma unroll
    for (int e = 0; e < NEXP; ++e) la[e] = al[n * NEXP + e] + g3[n * 4 + e];
    int ea = 0; float bva = la[0];
#pragma unroll
    for (int e = 1; e < NEXP; ++e) if (la[e] > bva) { bva = la[e]; ea = e; }
    int b = n >> 10;
    float a0 = tl[b * 2 + 0] + g1[n * 2 + 0];
    float a1 = tl[b * 2 + 1] + g1[n * 2 + 1];
    float mx = fmaxf(a0, a1);
    float e0 = expf(a0 - mx), e1 = expf(a1 - mx);
    float cm = e0 / (e0 + e1), am = e1 / (e0 + e1);
    cmv[n] = cm; amv[n] = am;
    int p0 = atomicAdd(&lcnt[ec], 1);
    lists[ec * NTOK + p0] = n;
    int p1 = atomicAdd(&lcnt[4 + ea], 1);
    lists[(4 + ea) * NTOK + p1] = n;
    atomicAdd(&bins[ec], cm);
    atomicAdd(&bins[4 + ea], am);
    atomicAdd(&ssum[0], cm);
    atomicAdd(&ssum[1], am);
  }
  __syncthreads();
  if (t < 8) counts[t] = lcnt[t];
  if (t == 0) {
    float denom = 4.f * (ssum[0] + ssum[1]) + 1e-10f;
    float acc = 0.f;
    for (int j = 0; j < 8; ++j) {
      float u = bins[j] / denom;
      acc += u * logf(u + 1e-10f);
    }
    out_loss[0] = acc / 8.f;
  }
}

// ---------------- GEMM1 (MoE pass): M64, f16 weights, XCD remap, 2-phase --------------
__global__ __launch_bounds__(256) void k_gemm1(
    const f16* __restrict__ x16, f16* wf,
    const int* __restrict__ lists, const int* __restrict__ counts,
    f16* __restrict__ tbuf,
    const float* __restrict__ w4, const float* __restrict__ w5,
    const float* __restrict__ w6, const float* __restrict__ w7,
    const float* __restrict__ w8) {
  int bid = blockIdx.x;
  if (bid >= 3072) {
    int cvtid = bid - 3072;  // [0,594)
    int t = threadIdx.x;
    if (cvtid < 432) {
      int slot = cvtid / 216;
      size_t base = (size_t)(cvtid % 216) * 16384;
      const float* s = (slot ? w7 : w6) + base;
      f16* dst = wf + (slot ? OFF_AW2 : OFF_CW2) + base;
#pragma unroll
      for (int i = 0; i < 8; ++i) {
        size_t off = (size_t)(t + i * 256) * 8;
        float4 v0 = *(const float4*)(s + off);
        float4 v1 = *(const float4*)(s + off + 4);
        f16x8 h;
        h[0] = (f16)v0.x; h[1] = (f16)v0.y; h[2] = (f16)v0.z; h[3] = (f16)v0.w;
        h[4] = (f16)v1.x; h[5] = (f16)v1.y; h[6] = (f16)v1.z; h[7] = (f16)v1.w;
        *(f16x8*)(dst + off) = h;
      }
    } else {
      int fid = cvtid - 432;            // [0,162)
      int which = fid / 54;             // 0: fr_w1, 1: fr_w3, 2: fr_w2 (block-uniform)
      int base = (fid % 54) * 16384;
      const float* s = (which == 0) ? w4 : (which == 1) ? w5 : w8;
      f16* dst = wf + ((which == 0) ? OFF_FR1 : (which == 1) ? OFF_FR3 : OFF_FR2);
#pragma unroll
      for (int i = 0; i < 8; ++i) {
        int i0 = base + i * 2048 + t * 8;
        int e = i0 / 221184;
        int rem = i0 - e * 221184;
        size_t si;
        if (which < 2) {
          int hh = rem / 288, j = rem - (rem / 288) * 288;
          si = (size_t)e * 884736 + (size_t)hh * 1152 + e * 288 + j;
        } else {
          int rr = rem / 768, c = rem - (rem / 768) * 768;
          si = (size_t)e * 884736 + (size_t)(e * 288 + rr) * 768 + c;
        }
        float4 v0 = *(const float4*)(s + si);
        float4 v1 = *(const float4*)(s + si + 4);
        f16x8 h;
        h[0] = (f16)v0.x; h[1] = (f16)v0.y; h[2] = (f16)v0.z; h[3] = (f16)v0.w;
        h[4] = (f16)v1.x; h[5] = (f16)v1.y; h[6] = (f16)v1.z; h[7] = (f16)v1.w;
        *(f16x8*)(dst + i0) = h;
      }
    }
    return;
  }
  int xcd = bid & 7;
  int local = bid >> 3;
  int pair = xcd * 12 + (local >> 5);   // MT = 32
  int mt = local & 31;
  int g = pair / 12;
  int nt = pair % 12;
  int e = g & 3;
  int cnt = counts[g];
  if (mt * 64 >= cnt) return;
  const int* list = lists + g * NTOK;
  const f16* B1 = wf + (size_t)((g < 4) ? 0 : 2) * WSZ + (size_t)e * NHID * NDIM;
  const f16* B3 = wf + (size_t)((g < 4) ? 1 : 3) * WSZ + (size_t)e * NHID * NDIM;
  f16* tout = tbuf + (size_t)g * NTOK * NHID;
  int t = threadIdx.x;
  int wv = t >> 6, lane = t & 63, m16 = lane & 15, quad = lane >> 4;
  int r0 = t >> 3, ak = (t & 7) * 8;
  int m0 = mt * 64 + r0, m1 = m0 + 32;
  int tok0 = list[min(m0, cnt - 1)], tok1 = list[min(m1, cnt - 1)];
  const f16* ar0 = x16 + (size_t)tok0 * NDIM;
  const f16* ar1 = x16 + (size_t)tok1 * NDIM;
  const f16* b1r0 = B1 + (size_t)(nt * 64 + r0) * NDIM;
  const f16* b1r1 = B1 + (size_t)(nt * 64 + r0 + 32) * NDIM;
  const f16* b3r0 = B3 + (size_t)(nt * 64 + r0) * NDIM;
  const f16* b3r1 = B3 + (size_t)(nt * 64 + r0 + 32) * NDIM;
  __shared__ f16 As[64 * 72];
  __shared__ f16 Bs1[64 * 72];
  __shared__ f16 Bs2[64 * 72];
  f32x4 zf = {0.f, 0.f, 0.f, 0.f};
  f32x4 ac1[2][2] = {{zf, zf}, {zf, zf}};
  f32x4 ac2[2][2] = {{zf, zf}, {zf, zf}};
  uint4 ra0, ra1, rb10, rb11, rb30, rb31;
  ra0  = *(const uint4*)(ar0 + ak);
  ra1  = *(const uint4*)(ar1 + ak);
  rb10 = *(const uint4*)(b1r0 + ak);
  rb11 = *(const uint4*)(b1r1 + ak);
  rb30 = *(const uint4*)(b3r0 + ak);
  rb31 = *(const uint4*)(b3r1 + ak);
  for (int kc = 0; kc < NDIM; kc += 64) {
    __syncthreads();
    *(uint4*)&As[r0 * 72 + ak] = ra0;
    *(uint4*)&As[(r0 + 32) * 72 + ak] = ra1;
    *(uint4*)&Bs1[r0 * 72 + ak] = rb10;
    *(uint4*)&Bs1[(r0 + 32) * 72 + ak] = rb11;
    *(uint4*)&Bs2[r0 * 72 + ak] = rb30;
    *(uint4*)&Bs2[(r0 + 32) * 72 + ak] = rb31;
    __syncthreads();
    int kn = kc + 64;
    if (kn < NDIM) {
      ra0  = *(const uint4*)(ar0 + kn + ak);
      ra1  = *(const uint4*)(ar1 + kn + ak);
      rb10 = *(const uint4*)(b1r0 + kn + ak);
      rb11 = *(const uint4*)(b1r1 + kn + ak);
      rb30 = *(const uint4*)(b3r0 + kn + ak);
      rb31 = *(const uint4*)(b3r1 + kn + ak);
    }
#pragma unroll
    for (int ks = 0; ks < 2; ++ks) {
      int aoff = ((wv & 1) * 32 + m16) * 72 + ks * 32 + quad * 8;
      int boff = ((wv >> 1) * 32 + m16) * 72 + ks * 32 + quad * 8;
      f16x8 a0 = *(const f16x8*)&As[aoff];
      f16x8 a1 = *(const f16x8*)&As[aoff + 16 * 72];
      f16x8 b10 = *(const f16x8*)&Bs1[boff];
      f16x8 b11 = *(const f16x8*)&Bs1[boff + 16 * 72];
      f16x8 b30 = *(const f16x8*)&Bs2[boff];
      f16x8 b31 = *(const f16x8*)&Bs2[boff + 16 * 72];
      ac1[0][0] = MFMA16(a0, b10, ac1[0][0]);
      ac1[0][1] = MFMA16(a0, b11, ac1[0][1]);
      ac1[1][0] = MFMA16(a1, b10, ac1[1][0]);
      ac1[1][1] = MFMA16(a1, b11, ac1[1][1]);
      ac2[0][0] = MFMA16(a0, b30, ac2[0][0]);
      ac2[0][1] = MFMA16(a0, b31, ac2[0][1]);
      ac2[1][0] = MFMA16(a1, b30, ac2[1][0]);
      ac2[1][1] = MFMA16(a1, b31, ac2[1][1]);
    }
  }
#pragma unroll
  for (int mi = 0; mi < 2; ++mi)
#pragma unroll
    for (int ni = 0; ni < 2; ++ni)
#pragma unroll
      for (int r = 0; r < 4; ++r) {
        int row = mt * 64 + (wv & 1) * 32 + mi * 16 + quad * 4 + r;
        int col = nt * 64 + (wv >> 1) * 32 + ni * 16 + m16;
        float h1 = ac1[mi][ni][r];
        float h3 = ac2[mi][ni][r];
        float sl = h1 / (1.0f + expf(-h1));
        tout[(size_t)row * NHID + col] = (f16)(sl * h3);
      }
}

// ---------------- GEMM1 (fr pass): A = f16(ybc+yba) slice, B = compact fr1c/fr3c ------
__global__ __launch_bounds__(256) void k_gemm1_fr(
    const float* __restrict__ ybc, const float* __restrict__ yba,
    const f16* __restrict__ wf, f16* __restrict__ tbuf) {
  int e = blockIdx.z, mt = blockIdx.y, nt = blockIdx.x;
  const int K = 288;
  int koff = e * 288;
  const f16* B1 = wf + OFF_FR1 + (size_t)e * 768 * 288;
  const f16* B3 = wf + OFF_FR3 + (size_t)e * 768 * 288;
  f16* tout = tbuf + (size_t)e * NTOK * NHID;
  int t = threadIdx.x;
  int wv = t >> 6, lane = t & 63, m16 = lane & 15, quad = lane >> 4;
  int r0 = t >> 3, ak = (t & 7) * 8;
  const float* c0 = ybc + (size_t)(mt * 64 + r0) * NDIM + koff;
  const float* c1 = ybc + (size_t)(mt * 64 + r0 + 32) * NDIM + koff;
  const float* d0 = yba + (size_t)(mt * 64 + r0) * NDIM + koff;
  const float* d1 = yba + (size_t)(mt * 64 + r0 + 32) * NDIM + koff;
  const f16* b1r0 = B1 + (size_t)(nt * 64 + r0) * 288;
  const f16* b1r1 = B1 + (size_t)(nt * 64 + r0 + 32) * 288;
  const f16* b3r0 = B3 + (size_t)(nt * 64 + r0) * 288;
  const f16* b3r1 = B3 + (size_t)(nt * 64 + r0 + 32) * 288;
  __shared__ f16 As[64 * 72];
  __shared__ f16 Bs1[64 * 72];
  __shared__ f16 Bs2[64 * 72];
  f32x4 zf = {0.f, 0.f, 0.f, 0.f};
  f32x4 ac1[2][2] = {{zf, zf}, {zf, zf}};
  f32x4 ac2[2][2] = {{zf, zf}, {zf, zf}};
  uint4 rb10, rb11, rb30, rb31;
  rb10 = *(const uint4*)(b1r0 + ak);
  rb11 = *(const uint4*)(b1r1 + ak);
  rb30 = *(const uint4*)(b3r0 + ak);
  rb31 = *(const uint4*)(b3r1 + ak);
  for (int kc = 0; kc < K; kc += 64) {
    __syncthreads();
    {
      f16x8 h0, h1;
      int cb = kc + ak;
      if (cb < K) {
        float4 p0 = *(const float4*)(c0 + cb);
        float4 p1 = *(const float4*)(c0 + cb + 4);
        float4 q0 = *(const float4*)(d0 + cb);
        float4 q1 = *(const float4*)(d0 + cb + 4);
        h0[0] = (f16)(p0.x + q0.x); h0[1] = (f16)(p0.y + q0.y);
        h0[2] = (f16)(p0.z + q0.z); h0[3] = (f16)(p0.w + q0.w);
        h0[4] = (f16)(p1.x + q1.x); h0[5] = (f16)(p1.y + q1.y);
        h0[6] = (f16)(p1.z + q1.z); h0[7] = (f16)(p1.w + q1.w);
        p0 = *(const float4*)(c1 + cb);
        p1 = *(const float4*)(c1 + cb + 4);
        q0 = *(const float4*)(d1 + cb);
        q1 = *(const float4*)(d1 + cb + 4);
        h1[0] = (f16)(p0.x + q0.x); h1[1] = (f16)(p0.y + q0.y);
        h1[2] = (f16)(p0.z + q0.z); h1[3] = (f16)(p0.w + q0.w);
        h1[4] = (f16)(p1.x + q1.x); h1[5] = (f16)(p1.y + q1.y);
        h1[6] = (f16)(p1.z + q1.z); h1[7] = (f16)(p1.w + q1.w);
      } else {
#pragma unroll
        for (int j = 0; j < 8; ++j) { h0[j] = (f16)0.f; h1[j] = (f16)0.f; }
      }
      *(f16x8*)&As[r0 * 72 + ak] = h0;
      *(f16x8*)&As[(r0 + 32) * 72 + ak] = h1;
    }
    *(uint4*)&Bs1[r0 * 72 + ak] = rb10;
    *(uint4*)&Bs1[(r0 + 32) * 72 + ak] = rb11;
    *(uint4*)&Bs2[r0 * 72 + ak] = rb30;
    *(uint4*)&Bs2[(r0 + 32) * 72 + ak] = rb31;
    __syncthreads();
    int kn = kc + 64;
    if (kn < K) {
      bool v = (kn + ak < K);
      uint4 z4u = make_uint4(0u, 0u, 0u, 0u);
      rb10 = v ? *(const uint4*)(b1r0 + kn + ak) : z4u;
      rb11 = v ? *(const uint4*)(b1r1 + kn + ak) : z4u;
      rb30 = v ? *(const uint4*)(b3r0 + kn + ak) : z4u;
      rb31 = v ? *(const uint4*)(b3r1 + kn + ak) : z4u;
    }
#pragma unroll
    for (int ks = 0; ks < 2; ++ks) {
      int aoff = ((wv & 1) * 32 + m16) * 72 + ks * 32 + quad * 8;
      int boff = ((wv >> 1) * 32 + m16) * 72 + ks * 32 + quad * 8;
      f16x8 a0 = *(const f16x8*)&As[aoff];
      f16x8 a1 = *(const f16x8*)&As[aoff + 16 * 72];
      f16x8 b10 = *(const f16x8*)&Bs1[boff];
      f16x8 b11 = *(const f16x8*)&Bs1[boff + 16 * 72];
      f16x8 b30 = *(const f16x8*)&Bs2[boff];
      f16x8 b31 = *(const f16x8*)&Bs2[boff + 16 * 72];
      ac1[0][0] = MFMA16(a0, b10, ac1[0][0]);
      ac1[0][1] = MFMA16(a0, b11, ac1[0][1]);
      ac1[1][0] = MFMA16(a1, b10, ac1[1][0]);
      ac1[1][1] = MFMA16(a1, b11, ac1[1][1]);
      ac2[0][0] = MFMA16(a0, b30, ac2[0][0]);
      ac2[0][1] = MFMA16(a0, b31, ac2[0][1]);
      ac2[1][0] = MFMA16(a1, b30, ac2[1][0]);
      ac2[1][1] = MFMA16(a1, b31, ac2[1][1]);
    }
  }
#pragma unroll
  for (int mi = 0; mi < 2; ++mi)
#pragma unroll
    for (int ni = 0; ni < 2; ++ni)
#pragma unroll
      for (int r = 0; r < 4; ++r) {
        int row = mt * 64 + (wv & 1) * 32 + mi * 16 + quad * 4 + r;
        int col = nt * 64 + (wv >> 1) * 32 + ni * 16 + m16;
        float h1v = ac1[mi][ni][r];
        float h3v = ac2[mi][ni][r];
        float sl = h1v / (1.0f + expf(-h1v));
        tout[(size_t)row * NHID + col] = (f16)(sl * h3v);
      }
}

// ---------------- GEMM2 (MoE): f16 weights, XCD-grouped remap, 2-phase ----------------
__global__ __launch_bounds__(256) void k_gemm2(
    const f16* __restrict__ tbuf, const f16* __restrict__ wf,
    const int* __restrict__ lists, const int* __restrict__ counts,
    const float* __restrict__ cmv, const float* __restrict__ amv,
    float* __restrict__ yc, float* __restrict__ ya) {
  int bid = blockIdx.x;
  int xcd = bid & 7;
  int local = bid >> 3;
  int pair = xcd * 18 + (local >> 5);
  int mt = local & 31;
  int g = pair / 18;
  int nt = pair % 18;
  int e = g & 3;
  int cnt = counts[g];
  if (mt * 64 >= cnt) return;
  const int* list = lists + g * NTOK;
  const f16* A = tbuf + (size_t)g * NTOK * NHID;
  const f16* Bw = wf + ((g < 4) ? OFF_CW2 : OFF_AW2) + (size_t)e * NDIM * NHID;
  const float* sc = (g < 4) ? cmv : amv;
  float* y = (g < 4) ? yc : ya;
  int t = threadIdx.x;
  int wv = t >> 6, lane = t & 63, m16 = lane & 15, quad = lane >> 4;
  int r0 = t >> 3, ak = (t & 7) * 8;
  const f16* ar0 = A + (size_t)(mt * 64 + r0) * NHID;
  const f16* ar1 = A + (size_t)(mt * 64 + r0 + 32) * NHID;
  const f16* br0 = Bw + (size_t)(nt * 64 + r0) * NHID;
  const f16* br1 = Bw + (size_t)(nt * 64 + r0 + 32) * NHID;
  __shared__ f16 As[64 * 72];
  __shared__ f16 Bs[64 * 72];
  f32x4 zf = {0.f, 0.f, 0.f, 0.f};
  f32x4 acc[2][2] = {{zf, zf}, {zf, zf}};
  uint4 ra0, ra1, rb0, rb1;
  ra0 = *(const uint4*)(ar0 + ak);
  ra1 = *(const uint4*)(ar1 + ak);
  rb0 = *(const uint4*)(br0 + ak);
  rb1 = *(const uint4*)(br1 + ak);
  for (int kc = 0; kc < NHID; kc += 64) {
    __syncthreads();
    *(uint4*)&As[r0 * 72 + ak] = ra0;
    *(uint4*)&As[(r0 + 32) * 72 + ak] = ra1;
    *(uint4*)&Bs[r0 * 72 + ak] = rb0;
    *(uint4*)&Bs[(r0 + 32) * 72 + ak] = rb1;
    __syncthreads();
    int kn = kc + 64;
    if (kn < NHID) {
      ra0 = *(const uint4*)(ar0 + kn + ak);
      ra1 = *(const uint4*)(ar1 + kn + ak);
      rb0 = *(const uint4*)(br0 + kn + ak);
      rb1 = *(const uint4*)(br1 + kn + ak);
    }
#pragma unroll
    for (int ks = 0; ks < 2; ++ks) {
      int aoff = ((wv & 1) * 32 + m16) * 72 + ks * 32 + quad * 8;
      int boff = ((wv >> 1) * 32 + m16) * 72 + ks * 32 + quad * 8;
      f16x8 a0 = *(const f16x8*)&As[aoff];
      f16x8 a1 = *(const f16x8*)&As[aoff + 16 * 72];
      f16x8 b0 = *(const f16x8*)&Bs[boff];
      f16x8 b1 = *(const f16x8*)&Bs[boff + 16 * 72];
      acc[0][0] = MFMA16(a0, b0, acc[0][0]);
      acc[0][1] = MFMA16(a0, b1, acc[0][1]);
      acc[1][0] = MFMA16(a1, b0, acc[1][0]);
      acc[1][1] = MFMA16(a1, b1, acc[1][1]);
    }
  }
#pragma unroll
  for (int mi = 0; mi < 2; ++mi)
#pragma unroll
    for (int ni = 0; ni < 2; ++ni)
#pragma unroll
      for (int r = 0; r < 4; ++r) {
        int mg = mt * 64 + (wv & 1) * 32 + mi * 16 + quad * 4 + r;
        if (mg < cnt) {
          int tok = list[mg];
          int col = nt * 64 + (wv >> 1) * 32 + ni * 16 + m16;
          float v = acc[mi][ni][r] * sc[tok];
          y[(size_t)tok * NDIM + col] = v;
        }
      }
}

// ---------------- GEMM2 (fr): compact fr2c, t16 @ slice -> z, 2-phase -----------------
__global__ __launch_bounds__(256) void k_gemm2_fr(
    const f16* __restrict__ tbuf, const f16* __restrict__ wf, float* __restrict__ zz) {
  int e = blockIdx.z;
  int mt = blockIdx.y, nt = blockIdx.x;
  const f16* A = tbuf + (size_t)e * NTOK * NHID;
  const f16* Bw = wf + OFF_FR2 + (size_t)e * 288 * NHID;
  int t = threadIdx.x;
  int wv = t >> 6, lane = t & 63, m16 = lane & 15, quad = lane >> 4;
  int r0 = t >> 3, ak = (t & 7) * 8;
  const f16* ar0 = A + (size_t)(mt * 64 + r0) * NHID;
  const f16* ar1 = A + (size_t)(mt * 64 + r0 + 32) * NHID;
  int ne0 = min(nt * 64 + r0, 287), ne1 = min(nt * 64 + r0 + 32, 287);
  const f16* br0 = Bw + (size_t)ne0 * NHID;
  const f16* br1 = Bw + (size_t)ne1 * NHID;
  __shared__ f16 As[64 * 72];
  __shared__ f16 Bs[64 * 72];
  f32x4 zf = {0.f, 0.f, 0.f, 0.f};
  f32x4 acc[2][2] = {{zf, zf}, {zf, zf}};
  uint4 ra0, ra1, rb0, rb1;
  ra0 = *(const uint4*)(ar0 + ak);
  ra1 = *(const uint4*)(ar1 + ak);
  rb0 = *(const uint4*)(br0 + ak);
  rb1 = *(const uint4*)(br1 + ak);
  for (int kc = 0; kc < NHID; kc += 64) {
    __syncthreads();
    *(uint4*)&As[r0 * 72 + ak] = ra0;
    *(uint4*)&As[(r0 + 32) * 72 + ak] = ra1;
    *(uint4*)&Bs[r0 * 72 + ak] = rb0;
    *(uint4*)&Bs[(r0 + 32) * 72 + ak] = rb1;
    __syncthreads();
    int kn = kc + 64;
    if (kn < NHID) {
      ra0 = *(const uint4*)(ar0 + kn + ak);
      ra1 = *(const uint4*)(ar1 + kn + ak);
      rb0 = *(const uint4*)(br0 + kn + ak);
      rb1 = *(const uint4*)(br1 + kn + ak);
    }
#pragma unroll
    for (int ks = 0; ks < 2; ++ks) {
      int aoff = ((wv & 1) * 32 + m16) * 72 + ks * 32 + quad * 8;
      int boff = ((wv >> 1) * 32 + m16) * 72 + ks * 32 + quad * 8;
      f16x8 a0 = *(const f16x8*)&As[aoff];
      f16x8 a1 = *(const f16x8*)&As[aoff + 16 * 72];
      f16x8 b0 = *(const f16x8*)&Bs[boff];
      f16x8 b1 = *(const f16x8*)&Bs[boff + 16 * 72];
      acc[0][0] = MFMA16(a0, b0, acc[0][0]);
      acc[0][1] = MFMA16(a0, b1, acc[0][1]);
      acc[1][0] = MFMA16(a1, b0, acc[1][0]);
      acc[1][1] = MFMA16(a1, b1, acc[1][1]);
    }
  }
#pragma unroll
  for (int mi = 0; mi < 2; ++mi)
#pragma unroll
    for (int ni = 0; ni < 2; ++ni)
#pragma unroll
      for (int r = 0; r < 4; ++r) {
        int cg = nt * 64 + (wv >> 1) * 32 + ni * 16 + m16;
        if (cg < 288) {
          int row = mt * 64 + (wv & 1) * 32 + mi * 16 + quad * 4 + r;
          zz[(size_t)row * NDIM + e * 288 + cg] = acc[mi][ni][r];
        }
      }
}

// ---------------- host ----------------
extern "C" void kernel_launch(void* const* d_in, const int* in_sizes, int n_in,
                              void* d_out, int out_size, void* d_ws, size_t ws_size,
                              hipStream_t stream) {
  const float* x          = (const float*)d_in[0];
  const float* timep      = (const float*)d_in[1];
  const float* caption    = (const float*)d_in[2];
  const float* acoustic   = (const float*)d_in[3];
  const float* attn_in_w  = (const float*)d_in[4];
  const float* attn_in_b  = (const float*)d_in[5];
  const float* attn_out_w = (const float*)d_in[6];
  const float* attn_out_b = (const float*)d_in[7];
  const float* hl_w       = (const float*)d_in[8];
  const float* hl_b       = (const float*)d_in[9];
  const float* cap_gate_w = (const float*)d_in[10];
  const float* cap_gate_b = (const float*)d_in[11];
  const float* ac_gate_w  = (const float*)d_in[12];
  const float* ac_gate_b  = (const float*)d_in[13];
  const float* cap_w1     = (const float*)d_in[14];
  const float* cap_w2     = (const float*)d_in[15];
  const float* cap_w3     = (const float*)d_in[16];
  const float* ac_w1      = (const float*)d_in[17];
  const float* ac_w2      = (const float*)d_in[18];
  const float* ac_w3      = (const float*)d_in[19];
  const float* fr_w1      = (const float*)d_in[20];
  const float* fr_w2      = (const float*)d_in[21];
  const float* fr_w3      = (const float*)d_in[22];
  (void)in_sizes; (void)n_in; (void)out_size; (void)ws_size;

  float* zout = (float*)d_out;
  float* loss = zout + (size_t)NTOK * NDIM;

  char* wsb = (char*)d_ws;
  size_t off = 0;
  auto alloc = [&](size_t bytes) -> void* {
    void* p = wsb + off;
    off = (off + bytes + 255) & ~(size_t)255;
    return p;
  };
  // persistent small + xhi + converted weights
  float* g1     = (float*)alloc(4096 * 4);
  float* g2     = (float*)alloc(8192 * 4);
  float* g3     = (float*)alloc(8192 * 4);
  float* tl     = (float*)alloc(4 * 4);
  float* al     = (float*)alloc((size_t)NTOK * NEXP * 4);
  float* cl     = (float*)alloc((size_t)NTOK * NEXP * 4);
  float* cmv    = (float*)alloc((size_t)NTOK * 4);
  float* amv    = (float*)alloc((size_t)NTOK * 4);
  int*   lists  = (int*)alloc((size_t)8 * NTOK * 4);
  int*   counts = (int*)alloc(8 * 4);
  float* wp     = (float*)alloc((size_t)NEXP * NDIM * 4);
  float* bp     = (float*)alloc(NEXP * 4);
  f16*   xhi    = (f16*)alloc((size_t)NTOK * NDIM * 2);
  f16*   wf16   = (f16*)alloc((size_t)(6 * WSZ + 3 * WQ) * 2);
  size_t region = off;
  // phase 1 (attention / routing inputs)
  f16*   xlo    = (f16*)alloc((size_t)NTOK * NDIM * 2);
  f16*   caphi  = (f16*)alloc((size_t)NCAP * NDIM * 2);
  f16*   caplo  = (f16*)alloc((size_t)NCAP * NDIM * 2);
  f16*   qhi    = (f16*)alloc((size_t)NTOK * NDIM * 2);
  f16*   qlo    = (f16*)alloc((size_t)NTOK * NDIM * 2);
  f16*   khi    = (f16*)alloc((size_t)NCAP * NDIM * 2);
  f16*   klo    = (f16*)alloc((size_t)NCAP * NDIM * 2);
  f16*   vthi   = (f16*)alloc((size_t)NB * NDIM * NSC * 2);
  f16*   vtlo   = (f16*)alloc((size_t)NB * NDIM * NSC * 2);
  f16*   ohi    = (f16*)alloc((size_t)NTOK * NDIM * 2);
  f16*   olo    = (f16*)alloc((size_t)NTOK * NDIM * 2);
  f16*   inwhi  = (f16*)alloc((size_t)3 * NDIM * NDIM * 2);
  f16*   inwlo  = (f16*)alloc((size_t)3 * NDIM * NDIM * 2);
  // phase 2 (MoE / fr) — reuses phase-1 region (all phase-1 buffers dead)
  off = region;
  f16*   tbuf   = (f16*)alloc((size_t)8 * NTOK * NHID * 2);
  float* ybc    = (float*)alloc((size_t)NTOK * NDIM * 4);
  float* yba    = (float*)alloc((size_t)NTOK * NDIM * 4);

  // single merged preprocessing launch (gumbels parallelized across 20 blocks)
  k_pre<<<dim3(PRE_NB), dim3(256), 0, stream>>>(
      x, caption, attn_in_w, timep, hl_w, hl_b,
      acoustic, ac_gate_w, ac_gate_b,
      attn_out_w, attn_out_b, cap_gate_w, cap_gate_b,
      xhi, xlo, caphi, caplo, inwhi, inwlo,
      g1, g2, g3, tl, al, wp, bp);
  // pure f16 QKV projection
  k_gemm_qkv<<<dim3(18, 32, 3), dim3(256), 0, stream>>>(
      xhi, xlo, caphi, caplo, inwhi, inwlo, attn_in_b,
      qhi, qlo, khi, klo, vthi, vtlo);
  k_attn<<<dim3(16, 16), dim3(256), 0, stream>>>(qhi, qlo, khi, klo, vthi, vtlo, ohi, olo);
  k_o_logits<<<dim3(512), dim3(256), 0, stream>>>(ohi, olo, wp, bp, cl);
  // routing + hosted cvt of slots 0-3 on otherwise-idle CUs
  k_route<<<dim3(1 + 1728), dim3(1024), 0, stream>>>(cl, al, g1, g2, g3, tl,
                                                     cmv, amv, lists, counts, loss,
                                                     cap_w1, cap_w3, ac_w1, ac_w3, wf16);
  // gemm1 MoE pass (8 groups) + tail cvt blocks (cap_w2/ac_w2 full + fr compacts)
  k_gemm1<<<dim3(3666), dim3(256), 0, stream>>>(xhi, wf16, lists, counts, tbuf,
                                                fr_w1, fr_w3, cap_w2, ac_w2, fr_w2);
  k_gemm2<<<dim3(4608), dim3(256), 0, stream>>>(tbuf, wf16, lists, counts,
                                                cmv, amv, ybc, yba);
  k_gemm1_fr<<<dim3(12, 32, 4), dim3(256), 0, stream>>>(ybc, yba, wf16, tbuf);
  k_gemm2_fr<<<dim3(5, 32, 4), dim3(256), 0, stream>>>(tbuf, wf16, zout);
}